// Round 9
// baseline (516.023 us; speedup 1.0000x reference)
//
#include <hip/hip_runtime.h>
#include <hip/hip_bf16.h>

#define NN 50000
#define NE 800000
#define NG 128
#define EB ((NE + 255)/256)
#define MB1 ((NN + 15)/16)

typedef unsigned short u16;

__device__ __forceinline__ float lrelu(float x){ return x > 0.f ? x : 0.2f*x; }
__device__ __forceinline__ u16 f2bf(float f){
    __hip_bfloat16 h = __float2bfloat16(f);
    return *(u16*)&h;
}
// unpack 8 bf16 (as uint4) -> 8 floats
__device__ __forceinline__ void unpack8(uint4 t, float* f){
    f[0]=__uint_as_float(t.x<<16); f[1]=__uint_as_float(t.x&0xffff0000u);
    f[2]=__uint_as_float(t.y<<16); f[3]=__uint_as_float(t.y&0xffff0000u);
    f[4]=__uint_as_float(t.z<<16); f[5]=__uint_as_float(t.z&0xffff0000u);
    f[6]=__uint_as_float(t.w<<16); f[7]=__uint_as_float(t.w&0xffff0000u);
}

// ---------------- fused: edge count (atomics) + mm1 (x@W1 -> h1) ----------------
__global__ void k_cm(const int* __restrict__ dstE, int* __restrict__ degi,
                     const float* __restrict__ x, const float* __restrict__ W1,
                     float* __restrict__ h1){
    if (blockIdx.x < EB){
        int e = blockIdx.x*256 + threadIdx.x;
        if (e < NE) atomicAdd(&degi[dstE[e]], 1);
        return;
    }
    // mm<128,16>: 16 nodes per block
    __shared__ float wl[128*16];
    for (int i = threadIdx.x; i < 128*16; i += 256) wl[i] = W1[i];
    __syncthreads();
    int m  = threadIdx.x & 15;
    int nl = threadIdx.x >> 4;
    int node = (blockIdx.x - EB) * 16 + nl;
    if (node >= NN) return;
    const float* row = x + (size_t)node * 128;
    float acc = 0.f;
#pragma unroll 8
    for (int k = 0; k < 128; k++) acc += row[k] * wl[k*16 + m];
    h1[(size_t)node*16 + m] = acc;
}

// scan stage A + dinv: per-block local exclusive scan (1024 elems/block)
__global__ void k_scan_a(const int* __restrict__ deg, int* __restrict__ rowptr,
                         float* __restrict__ dinv, int* __restrict__ bsum, int n){
    __shared__ int lds[256];
    int base = blockIdx.x*1024 + threadIdx.x*4;
    int v[4]; int s = 0;
#pragma unroll
    for (int k=0;k<4;k++){ v[k] = (base+k < n) ? deg[base+k] : 0; s += v[k]; }
    lds[threadIdx.x] = s;
    __syncthreads();
    for (int off=1; off<256; off<<=1){
        int t = (threadIdx.x>=off) ? lds[threadIdx.x-off] : 0;
        __syncthreads(); lds[threadIdx.x] += t; __syncthreads();
    }
    int run = lds[threadIdx.x] - s;
#pragma unroll
    for (int k=0;k<4;k++){
        if (base+k < n){
            rowptr[base+k] = run;
            dinv[base+k] = rsqrtf((float)(v[k] + 1));   // +1 = self loop
        }
        run += v[k];
    }
    if (threadIdx.x == 255) bsum[blockIdx.x] = lds[255];
}

__global__ void k_scan_b(int* __restrict__ bsum, int* __restrict__ rowptr, int nb, int n){
    __shared__ int lds[64];
    int s = (threadIdx.x < nb) ? bsum[threadIdx.x] : 0;
    lds[threadIdx.x] = s;
    __syncthreads();
    for (int off=1; off<64; off<<=1){
        int t = (threadIdx.x>=off) ? lds[threadIdx.x-off] : 0;
        __syncthreads(); lds[threadIdx.x] += t; __syncthreads();
    }
    if (threadIdx.x < nb) bsum[threadIdx.x] = lds[threadIdx.x] - s;
    if (threadIdx.x == 63) rowptr[n] = lds[63];
}

__global__ void k_scan_c(int* __restrict__ rowptr, const int* __restrict__ bsum, int n){
    int i = blockIdx.x*256 + threadIdx.x;
    int idx = i*4;
    int o = bsum[blockIdx.x];
#pragma unroll
    for (int k=0;k<4;k++) if (idx+k < n) rowptr[idx+k] += o;
}

__global__ void k_scatter(const int* __restrict__ src, const int* __restrict__ dst,
                          const int* __restrict__ rowptr, int* __restrict__ cursor,
                          int* __restrict__ csr_src, int E){
    int e = blockIdx.x*blockDim.x + threadIdx.x;
    if (e < E){
        int d = dst[e];
        int pos = rowptr[d] + atomicAdd(&cursor[d], 1);
        csr_src[pos] = src[e];
    }
}

// ---------------- small matmul (fp32 out) ----------------
template<int K, int M>
__global__ void k_mm(const float* __restrict__ in, int istride,
                     const float* __restrict__ W, float* __restrict__ out, int n){
    __shared__ float wl[K*M];
    for (int i = threadIdx.x; i < K*M; i += blockDim.x) wl[i] = W[i];
    __syncthreads();
    constexpr int NPB = 256 / M;
    int m  = threadIdx.x % M;
    int nl = threadIdx.x / M;
    int node = blockIdx.x * NPB + nl;
    if (node >= n) return;
    const float* row = in + (size_t)node * istride;
    float acc = 0.f;
#pragma unroll 8
    for (int k = 0; k < K; k++) acc += row[k] * wl[k*M + m];
    out[(size_t)node*M + m] = acc;
}

// mm3 + fused att epilogue: out bf16 [N,128], a_src/a_dst [N,4] from fp32 acc
__global__ void k_mm_bf_att(const float* __restrict__ in, int istride,
                            const float* __restrict__ W,
                            const float* __restrict__ as, const float* __restrict__ adt,
                            u16* __restrict__ out, float* __restrict__ asrc,
                            float* __restrict__ adst, int n){
    constexpr int K = 32, M = 128;
    __shared__ float wl[K*M];
    for (int i = threadIdx.x; i < K*M; i += 256) wl[i] = W[i];
    __syncthreads();
    int m  = threadIdx.x % M;
    int nl = threadIdx.x / M;   // 2 nodes per block
    int node = blockIdx.x * 2 + nl;
    if (node >= n) return;
    const float* row = in + (size_t)node * istride;
    float acc = 0.f;
#pragma unroll 8
    for (int k = 0; k < K; k++) acc += row[k] * wl[k*M + m];
    out[(size_t)node*M + m] = f2bf(acc);
    float psv = acc * as[m];
    float pdv = acc * adt[m];
#pragma unroll
    for (int mm = 1; mm <= 16; mm <<= 1){
        psv += __shfl_xor(psv, mm, 64);
        pdv += __shfl_xor(pdv, mm, 64);
    }
    if ((m & 31) == 0){
        int hh = m >> 5;
        asrc[(size_t)node*4 + hh] = psv;
        adst[(size_t)node*4 + hh] = pdv;
    }
}

// ---------------- mm4: [N,128] @ [128,256] -> bf16 h + fused att logits ----------------
__global__ void k_mm4(const float* __restrict__ in, int istride,
                      const float* __restrict__ W,
                      const float* __restrict__ as, const float* __restrict__ adt,
                      u16* __restrict__ hb, float* __restrict__ asrc,
                      float* __restrict__ adst, int n){
    __shared__ __align__(16) float xs[64][68];
    __shared__ __align__(16) float ws[64][68];
    int tid = threadIdx.x;
    int tx = tid & 15;
    int ty = tid >> 4;
    int nbase = blockIdx.y * 64;
    int cbase = blockIdx.x * 64;
    float acc[4][4] = {};
    for (int kb = 0; kb < 128; kb += 64){
#pragma unroll
        for (int p = 0; p < 4; p++){
            int r = p*16 + ty;
            int nn = nbase + r;
            float4 v = make_float4(0.f,0.f,0.f,0.f);
            if (nn < n) v = *(const float4*)(in + (size_t)nn*istride + kb + tx*4);
            *(float4*)&xs[r][tx*4] = v;
            float4 wv = *(const float4*)(W + (size_t)(kb + r)*256 + cbase + tx*4);
            *(float4*)&ws[r][tx*4] = wv;
        }
        __syncthreads();
#pragma unroll 16
        for (int k = 0; k < 64; k++){
            float4 wv = *(const float4*)&ws[k][tx*4];
#pragma unroll
            for (int i2 = 0; i2 < 4; i2++){
                float a = xs[ty*4 + i2][k];
                acc[i2][0] += a*wv.x; acc[i2][1] += a*wv.y;
                acc[i2][2] += a*wv.z; acc[i2][3] += a*wv.w;
            }
        }
        __syncthreads();
    }
    int ht = (cbase >> 5) + (tx >> 3);
    int co = (tx & 7) * 4;
    float s0 = as[ht*32+co+0], s1 = as[ht*32+co+1], s2 = as[ht*32+co+2], s3 = as[ht*32+co+3];
    float d0 = adt[ht*32+co+0], d1 = adt[ht*32+co+1], d2 = adt[ht*32+co+2], d3 = adt[ht*32+co+3];
    float ps[4], pd[4];
#pragma unroll
    for (int i2 = 0; i2 < 4; i2++){
        ps[i2] = acc[i2][0]*s0 + acc[i2][1]*s1 + acc[i2][2]*s2 + acc[i2][3]*s3;
        pd[i2] = acc[i2][0]*d0 + acc[i2][1]*d1 + acc[i2][2]*d2 + acc[i2][3]*d3;
    }
#pragma unroll
    for (int mm = 1; mm <= 4; mm <<= 1){
#pragma unroll
        for (int i2 = 0; i2 < 4; i2++){
            ps[i2] += __shfl_xor(ps[i2], mm, 64);
            pd[i2] += __shfl_xor(pd[i2], mm, 64);
        }
    }
#pragma unroll
    for (int i2 = 0; i2 < 4; i2++){
        int nn = nbase + ty*4 + i2;
        if (nn < n){
            ushort4 v;
            v.x = f2bf(acc[i2][0]); v.y = f2bf(acc[i2][1]);
            v.z = f2bf(acc[i2][2]); v.w = f2bf(acc[i2][3]);
            *(ushort4*)(hb + (size_t)nn*256 + cbase + tx*4) = v;
            if ((tx & 7) == 0){
                asrc[(size_t)nn*8 + ht] = ps[i2];
                adst[(size_t)nn*8 + ht] = pd[i2];
            }
        }
    }
}

// ---------------- GCN aggregation: 16 lanes/node, edge loop unrolled x4 ----------------
template<int C>
__global__ void k_gcn_agg(const float* __restrict__ h, const float* __restrict__ dinv,
                          const int* __restrict__ rowptr, const int* __restrict__ csr_src,
                          const float* __restrict__ b, float* __restrict__ out,
                          int ostride, int n){
    constexpr int CL = C/4;
    constexpr int S  = 16/CL;
    int lin = threadIdx.x & 15;
    int i = blockIdx.x*16 + (threadIdx.x >> 4);
    if (i >= n) return;
    int ll = lin % CL, slot = lin / CL;
    float di = dinv[i];
    float acc[4] = {0.f,0.f,0.f,0.f};
    if (slot == 0){
        float4 t = ((const float4*)(h + (size_t)i*C))[ll];
        acc[0]=di*t.x; acc[1]=di*t.y; acc[2]=di*t.z; acc[3]=di*t.w;
    }
    int e0 = rowptr[i], e1 = rowptr[i+1];
    int e = e0 + slot;
    for (; e + 3*S < e1; e += 4*S){
        int j0 = csr_src[e], j1 = csr_src[e+S], j2 = csr_src[e+2*S], j3 = csr_src[e+3*S];
        float d0 = dinv[j0], d1 = dinv[j1], d2 = dinv[j2], d3 = dinv[j3];
        float4 t0 = ((const float4*)(h + (size_t)j0*C))[ll];
        float4 t1 = ((const float4*)(h + (size_t)j1*C))[ll];
        float4 t2 = ((const float4*)(h + (size_t)j2*C))[ll];
        float4 t3 = ((const float4*)(h + (size_t)j3*C))[ll];
        acc[0]+=d0*t0.x+d1*t1.x+d2*t2.x+d3*t3.x;
        acc[1]+=d0*t0.y+d1*t1.y+d2*t2.y+d3*t3.y;
        acc[2]+=d0*t0.z+d1*t1.z+d2*t2.z+d3*t3.z;
        acc[3]+=d0*t0.w+d1*t1.w+d2*t2.w+d3*t3.w;
    }
    for (; e < e1; e += S){
        int j = csr_src[e];
        float dj = dinv[j];
        float4 t = ((const float4*)(h + (size_t)j*C))[ll];
        acc[0]+=dj*t.x; acc[1]+=dj*t.y; acc[2]+=dj*t.z; acc[3]+=dj*t.w;
    }
#pragma unroll
    for (int m = CL; m < 16; m <<= 1){
#pragma unroll
        for (int k=0;k<4;k++) acc[k] += __shfl_xor(acc[k], m, 64);
    }
    if (slot == 0){
        float4 o;
        o.x = fmaxf(di*acc[0] + b[ll*4+0], 0.f);
        o.y = fmaxf(di*acc[1] + b[ll*4+1], 0.f);
        o.z = fmaxf(di*acc[2] + b[ll*4+2], 0.f);
        o.w = fmaxf(di*acc[3] + b[ll*4+3], 0.f);
        *(float4*)(out + (size_t)i*ostride + ll*4) = o;
    }
}

// ---------------- GAT agg layer 3 (bf16 h, H=4): node split across 2 waves ----------------
// each wave: 64 chans (8 chan-lanes x 8 edge slots), unroll x2
__global__ void k_gat_agg3(const u16* __restrict__ h, const float* __restrict__ asrc,
                           const float* __restrict__ adst, const int* __restrict__ rowptr,
                           const int* __restrict__ csr_src, const float* __restrict__ b,
                           float* __restrict__ out, int ostride, int n){
    constexpr int HC = 128, CL = 8, S = 8;
    int lane = threadIdx.x & 63;
    int wid  = threadIdx.x >> 6;
    int i    = blockIdx.x*2 + (wid >> 1);
    int half = wid & 1;
    if (i >= n) return;
    int ll   = lane % CL;
    int slot = lane / CL;
    int c0   = half*64 + ll*8;
    int head = c0 >> 5;
    float ad = adst[(size_t)i*4 + head];
    float acc[8] = {0.f,0.f,0.f,0.f,0.f,0.f,0.f,0.f};
    float s = 0.f;
    if (slot == 0){
        float wself = __expf(lrelu(asrc[(size_t)i*4 + head] + ad));
        uint4 t = *(const uint4*)(h + (size_t)i*HC + c0);
        float f[8]; unpack8(t, f);
#pragma unroll
        for (int k=0;k<8;k++) acc[k] = wself*f[k];
        s = wself;
    }
    int e0 = rowptr[i], e1 = rowptr[i+1];
    int e = e0 + slot;
    for (; e + S < e1; e += 2*S){
        int j0 = csr_src[e], j1 = csr_src[e+S];
        float w0 = __expf(lrelu(asrc[(size_t)j0*4 + head] + ad));
        float w1 = __expf(lrelu(asrc[(size_t)j1*4 + head] + ad));
        uint4 t0 = *(const uint4*)(h + (size_t)j0*HC + c0);
        uint4 t1 = *(const uint4*)(h + (size_t)j1*HC + c0);
        float f0[8], f1[8]; unpack8(t0, f0); unpack8(t1, f1);
#pragma unroll
        for (int k=0;k<8;k++) acc[k] += w0*f0[k] + w1*f1[k];
        s += w0 + w1;
    }
    if (e < e1){
        int j = csr_src[e];
        float w = __expf(lrelu(asrc[(size_t)j*4 + head] + ad));
        uint4 t = *(const uint4*)(h + (size_t)j*HC + c0);
        float f[8]; unpack8(t, f);
#pragma unroll
        for (int k=0;k<8;k++) acc[k] += w*f[k];
        s += w;
    }
#pragma unroll
    for (int m = CL; m < 64; m <<= 1){
        s += __shfl_xor(s, m, 64);
#pragma unroll
        for (int k=0;k<8;k++) acc[k] += __shfl_xor(acc[k], m, 64);
    }
    if (slot == 0){
        float inv = 1.f / s;
        float o[8];
#pragma unroll
        for (int k=0;k<8;k++) o[k] = fmaxf(acc[k]*inv + b[c0+k], 0.f);
        float4* dst0 = (float4*)(out + (size_t)i*ostride + c0);
        dst0[0] = make_float4(o[0],o[1],o[2],o[3]);
        dst0[1] = make_float4(o[4],o[5],o[6],o[7]);
    }
}

// ---------------- GAT agg layer 4 (bf16 h, H=8): node split across 2 waves ----------------
// each wave: 128 chans (16 chan-lanes x 4 edge slots), unroll x4
__global__ void k_gat_agg4(const u16* __restrict__ h, const float* __restrict__ asrc,
                           const float* __restrict__ adst, const int* __restrict__ rowptr,
                           const int* __restrict__ csr_src, const float* __restrict__ b,
                           float* __restrict__ out, int ostride, int n){
    constexpr int HC = 256, CL = 16, S = 4;
    int lane = threadIdx.x & 63;
    int wid  = threadIdx.x >> 6;
    int i    = blockIdx.x*2 + (wid >> 1);
    int half = wid & 1;
    if (i >= n) return;
    int ll   = lane % CL;
    int slot = lane / CL;
    int c0   = half*128 + ll*8;
    int head = c0 >> 5;
    float ad = adst[(size_t)i*8 + head];
    float acc[8] = {0.f,0.f,0.f,0.f,0.f,0.f,0.f,0.f};
    float s = 0.f;
    if (slot == 0){
        float wself = __expf(lrelu(asrc[(size_t)i*8 + head] + ad));
        uint4 t = *(const uint4*)(h + (size_t)i*HC + c0);
        float f[8]; unpack8(t, f);
#pragma unroll
        for (int k=0;k<8;k++) acc[k] = wself*f[k];
        s = wself;
    }
    int e0 = rowptr[i], e1 = rowptr[i+1];
    int e = e0 + slot;
    for (; e + 3*S < e1; e += 4*S){
        int j0 = csr_src[e], j1 = csr_src[e+S], j2 = csr_src[e+2*S], j3 = csr_src[e+3*S];
        float w0 = __expf(lrelu(asrc[(size_t)j0*8 + head] + ad));
        float w1 = __expf(lrelu(asrc[(size_t)j1*8 + head] + ad));
        float w2 = __expf(lrelu(asrc[(size_t)j2*8 + head] + ad));
        float w3 = __expf(lrelu(asrc[(size_t)j3*8 + head] + ad));
        uint4 t0 = *(const uint4*)(h + (size_t)j0*HC + c0);
        uint4 t1 = *(const uint4*)(h + (size_t)j1*HC + c0);
        uint4 t2 = *(const uint4*)(h + (size_t)j2*HC + c0);
        uint4 t3 = *(const uint4*)(h + (size_t)j3*HC + c0);
        float f0[8], f1[8], f2[8], f3[8];
        unpack8(t0, f0); unpack8(t1, f1); unpack8(t2, f2); unpack8(t3, f3);
#pragma unroll
        for (int k=0;k<8;k++) acc[k] += w0*f0[k] + w1*f1[k] + w2*f2[k] + w3*f3[k];
        s += w0 + w1 + w2 + w3;
    }
    for (; e < e1; e += S){
        int j = csr_src[e];
        float w = __expf(lrelu(asrc[(size_t)j*8 + head] + ad));
        uint4 t = *(const uint4*)(h + (size_t)j*HC + c0);
        float f[8]; unpack8(t, f);
#pragma unroll
        for (int k=0;k<8;k++) acc[k] += w*f[k];
        s += w;
    }
#pragma unroll
    for (int m = CL; m < 64; m <<= 1){
        s += __shfl_xor(s, m, 64);
#pragma unroll
        for (int k=0;k<8;k++) acc[k] += __shfl_xor(acc[k], m, 64);
    }
    if (slot == 0){
        float inv = 1.f / s;
        float o[8];
#pragma unroll
        for (int k=0;k<8;k++) o[k] = fmaxf(acc[k]*inv + b[c0+k], 0.f);
        float4* dst0 = (float4*)(out + (size_t)i*ostride + c0);
        dst0[0] = make_float4(o[0],o[1],o[2],o[3]);
        dst0[1] = make_float4(o[4],o[5],o[6],o[7]);
    }
}

// ---------------- pooling + fused FC ----------------
__global__ void k_pool_sum(const float* __restrict__ xj, const int* __restrict__ batch,
                           float* __restrict__ pool){
    int nb = blockIdx.x * 32;
    int ne = min(nb + 32, NN);
    if (nb >= NN) return;
    int cq = threadIdx.x;
    if (cq >= 108) return;
    float4 a = make_float4(0.f,0.f,0.f,0.f);
    int curg = batch[nb];
    for (int nn = nb; nn < ne; nn++){
        int g = batch[nn];
        if (g != curg){
            float* p = &pool[curg*432 + cq*4];
            atomicAdd(p+0, a.x); atomicAdd(p+1, a.y);
            atomicAdd(p+2, a.z); atomicAdd(p+3, a.w);
            a = make_float4(0.f,0.f,0.f,0.f); curg = g;
        }
        float4 v = *(const float4*)(xj + (size_t)nn*432 + cq*4);
        a.x += v.x; a.y += v.y; a.z += v.z; a.w += v.w;
    }
    float* p = &pool[curg*432 + cq*4];
    atomicAdd(p+0, a.x); atomicAdd(p+1, a.y);
    atomicAdd(p+2, a.z); atomicAdd(p+3, a.w);
}

// fused fc1 + fc2 (+ graph-size via binary search): one block per graph
__global__ void k_fc(const float* __restrict__ pool, const int* __restrict__ batch,
                     const float* __restrict__ Wf1, const float* __restrict__ bf1,
                     const float* __restrict__ Wf2, const float* __restrict__ bf2,
                     float* __restrict__ out){
    int g = blockIdx.x, j = threadIdx.x;   // 128 threads
    int lo = 0, hi = NN;
    while (lo < hi){ int mid = (lo+hi) >> 1; if (batch[mid] < g) lo = mid+1; else hi = mid; }
    int s0 = lo;
    lo = 0; hi = NN;
    while (lo < hi){ int mid = (lo+hi) >> 1; if (batch[mid] < g+1) lo = mid+1; else hi = mid; }
    int cnt = lo - s0;
    float invc = 1.f / (float)max(cnt, 1);
    float acc = 0.f;
    for (int k = 0; k < 432; k++) acc += pool[g*432 + k] * Wf1[k*128 + j];
    float hv = fmaxf(acc * invc + bf1[j], 0.f);
    float p = hv * Wf2[j];
    for (int off = 32; off > 0; off >>= 1) p += __shfl_down(p, off, 64);
    __shared__ float part[2];
    if ((j & 63) == 0) part[j >> 6] = p;
    __syncthreads();
    if (j == 0) out[g] = part[0] + part[1] + bf2[0];
}

extern "C" void kernel_launch(void* const* d_in, const int* in_sizes, int n_in,
                              void* d_out, int out_size, void* d_ws, size_t ws_size,
                              hipStream_t stream){
    const float* x     = (const float*)d_in[0];
    const int*   ei    = (const int*)  d_in[1];
    const int*   batch = (const int*)  d_in[2];
    const float* W1 = (const float*)d_in[3];  const float* b1 = (const float*)d_in[4];
    const float* W2 = (const float*)d_in[5];  const float* b2 = (const float*)d_in[6];
    const float* W3 = (const float*)d_in[7];
    const float* as3 = (const float*)d_in[8]; const float* ad3 = (const float*)d_in[9];
    const float* b3 = (const float*)d_in[10];
    const float* W4 = (const float*)d_in[11];
    const float* as4 = (const float*)d_in[12]; const float* ad4 = (const float*)d_in[13];
    const float* b4 = (const float*)d_in[14];
    const float* Wf1 = (const float*)d_in[15]; const float* bf1 = (const float*)d_in[16];
    const float* Wf2 = (const float*)d_in[17]; const float* bf2 = (const float*)d_in[18];
    float* out = (float*)d_out;

    const int* srcE = ei;
    const int* dstE = ei + NE;

    char* base = (char*)d_ws; size_t off = 0;
    auto alloc = [&](size_t bytes)->void*{
        void* p = base + off;
        off += (bytes + 255) & ~(size_t)255;
        return p;
    };
    int*   degi    = (int*)  alloc((size_t)NN*4);
    int*   cursor  = (int*)  alloc((size_t)NN*4);
    float* dinv    = (float*)alloc((size_t)NN*4);
    int*   rowptr  = (int*)  alloc((size_t)(NN+1)*4);
    int*   bsum    = (int*)  alloc(64*4);
    int*   csr_src = (int*)  alloc((size_t)NE*4);
    float* h_buf   = (float*)alloc((size_t)NN*128*4);   // fp32 h for GCN layers
    u16*   hb3     = (u16*)  alloc((size_t)NN*128*2);   // bf16 h3
    u16*   hb4     = (u16*)  alloc((size_t)NN*256*2);   // bf16 h4
    float* xj      = (float*)alloc((size_t)NN*432*4);   // jump concat [x1|x2|x3|x4]
    float* a_src   = (float*)alloc((size_t)NN*8*4);
    float* a_dst   = (float*)alloc((size_t)NN*8*4);
    float* pool    = (float*)alloc((size_t)NG*432*4);

    hipMemsetAsync(degi, 0, (size_t)NN*4, stream);
    hipMemsetAsync(cursor, 0, (size_t)NN*4, stream);
    hipMemsetAsync(pool, 0, (size_t)NG*432*4, stream);

    const int SB = (NN + 1023)/1024;

    // fused: edge-count atomics + mm1
    k_cm     <<<EB + MB1, 256, 0, stream>>>(dstE, degi, x, W1, h_buf);
    k_scan_a <<<SB, 256, 0, stream>>>(degi, rowptr, dinv, bsum, NN);
    k_scan_b <<<1, 64, 0, stream>>>(bsum, rowptr, SB, NN);
    k_scan_c <<<SB, 256, 0, stream>>>(rowptr, bsum, NN);
    k_scatter<<<EB, 256, 0, stream>>>(srcE, dstE, rowptr, cursor, csr_src, NE);

    // GCN layer 1 aggregation
    k_gcn_agg<16><<<(NN+15)/16, 256, 0, stream>>>(h_buf, dinv, rowptr, csr_src, b1, xj + 0, 432, NN);

    // GCN layer 2
    k_mm<16,32>  <<<(NN+7)/8, 256, 0, stream>>>(xj + 0, 432, W2, h_buf, NN);
    k_gcn_agg<32><<<(NN+15)/16, 256, 0, stream>>>(h_buf, dinv, rowptr, csr_src, b2, xj + 16, 432, NN);

    // GAT layer 3 (4 heads x 32): mm + fused att logits, bf16 h
    k_mm_bf_att<<<(NN+1)/2, 256, 0, stream>>>(xj + 16, 432, W3, as3, ad3, hb3, a_src, a_dst, NN);
    k_gat_agg3<<<(NN+1)/2, 256, 0, stream>>>(hb3, a_src, a_dst, rowptr, csr_src, b3, xj + 48, 432, NN);

    // GAT layer 4 (8 heads x 32): mm4 + fused att logits, bf16 h
    {
        dim3 grid(4, (NN + 63)/64);
        k_mm4<<<grid, 256, 0, stream>>>(xj + 48, 432, W4, as4, ad4, hb4, a_src, a_dst, NN);
    }
    k_gat_agg4<<<(NN+1)/2, 256, 0, stream>>>(hb4, a_src, a_dst, rowptr, csr_src, b4, xj + 176, 432, NN);

    // pooling + fused FC
    k_pool_sum<<<(NN+31)/32, 128, 0, stream>>>(xj, batch, pool);
    k_fc<<<NG, 128, 0, stream>>>(pool, batch, Wf1, bf1, Wf2, bf2, out);
}

// Round 10
// 508.149 us; speedup vs baseline: 1.0155x; 1.0155x over previous
//
#include <hip/hip_runtime.h>
#include <hip/hip_bf16.h>

#define NN 50000
#define NE 800000
#define NG 128
#define EB ((NE + 255)/256)
#define MB1 ((NN + 15)/16)

typedef unsigned short u16;

__device__ __forceinline__ float lrelu(float x){ return x > 0.f ? x : 0.2f*x; }
__device__ __forceinline__ u16 f2bf(float f){
    __hip_bfloat16 h = __float2bfloat16(f);
    return *(u16*)&h;
}
// unpack 8 bf16 (as uint4) -> 8 floats
__device__ __forceinline__ void unpack8(uint4 t, float* f){
    f[0]=__uint_as_float(t.x<<16); f[1]=__uint_as_float(t.x&0xffff0000u);
    f[2]=__uint_as_float(t.y<<16); f[3]=__uint_as_float(t.y&0xffff0000u);
    f[4]=__uint_as_float(t.z<<16); f[5]=__uint_as_float(t.z&0xffff0000u);
    f[6]=__uint_as_float(t.w<<16); f[7]=__uint_as_float(t.w&0xffff0000u);
}

// ---------------- fused: edge count (atomics) + mm1 (x@W1 -> h1) ----------------
__global__ void k_cm(const int* __restrict__ dstE, int* __restrict__ degi,
                     const float* __restrict__ x, const float* __restrict__ W1,
                     float* __restrict__ h1){
    if (blockIdx.x < EB){
        int e = blockIdx.x*256 + threadIdx.x;
        if (e < NE) atomicAdd(&degi[dstE[e]], 1);
        return;
    }
    __shared__ float wl[128*16];
    for (int i = threadIdx.x; i < 128*16; i += 256) wl[i] = W1[i];
    __syncthreads();
    int m  = threadIdx.x & 15;
    int nl = threadIdx.x >> 4;
    int node = (blockIdx.x - EB) * 16 + nl;
    if (node >= NN) return;
    const float* row = x + (size_t)node * 128;
    float acc = 0.f;
#pragma unroll 8
    for (int k = 0; k < 128; k++) acc += row[k] * wl[k*16 + m];
    h1[(size_t)node*16 + m] = acc;
}

// scan stage A + dinv
__global__ void k_scan_a(const int* __restrict__ deg, int* __restrict__ rowptr,
                         float* __restrict__ dinv, int* __restrict__ bsum, int n){
    __shared__ int lds[256];
    int base = blockIdx.x*1024 + threadIdx.x*4;
    int v[4]; int s = 0;
#pragma unroll
    for (int k=0;k<4;k++){ v[k] = (base+k < n) ? deg[base+k] : 0; s += v[k]; }
    lds[threadIdx.x] = s;
    __syncthreads();
    for (int off=1; off<256; off<<=1){
        int t = (threadIdx.x>=off) ? lds[threadIdx.x-off] : 0;
        __syncthreads(); lds[threadIdx.x] += t; __syncthreads();
    }
    int run = lds[threadIdx.x] - s;
#pragma unroll
    for (int k=0;k<4;k++){
        if (base+k < n){
            rowptr[base+k] = run;
            dinv[base+k] = rsqrtf((float)(v[k] + 1));   // +1 = self loop
        }
        run += v[k];
    }
    if (threadIdx.x == 255) bsum[blockIdx.x] = lds[255];
}

__global__ void k_scan_b(int* __restrict__ bsum, int* __restrict__ rowptr, int nb, int n){
    __shared__ int lds[64];
    int s = (threadIdx.x < nb) ? bsum[threadIdx.x] : 0;
    lds[threadIdx.x] = s;
    __syncthreads();
    for (int off=1; off<64; off<<=1){
        int t = (threadIdx.x>=off) ? lds[threadIdx.x-off] : 0;
        __syncthreads(); lds[threadIdx.x] += t; __syncthreads();
    }
    if (threadIdx.x < nb) bsum[threadIdx.x] = lds[threadIdx.x] - s;
    if (threadIdx.x == 63) rowptr[n] = lds[63];
}

__global__ void k_scan_c(int* __restrict__ rowptr, const int* __restrict__ bsum, int n){
    int i = blockIdx.x*256 + threadIdx.x;
    int idx = i*4;
    int o = bsum[blockIdx.x];
#pragma unroll
    for (int k=0;k<4;k++) if (idx+k < n) rowptr[idx+k] += o;
}

__global__ void k_scatter(const int* __restrict__ src, const int* __restrict__ dst,
                          const int* __restrict__ rowptr, int* __restrict__ cursor,
                          int* __restrict__ csr_src, int E){
    int e = blockIdx.x*blockDim.x + threadIdx.x;
    if (e < E){
        int d = dst[e];
        int pos = rowptr[d] + atomicAdd(&cursor[d], 1);
        csr_src[pos] = src[e];
    }
}

// ---------------- small matmul (fp32 out) ----------------
template<int K, int M>
__global__ void k_mm(const float* __restrict__ in, int istride,
                     const float* __restrict__ W, float* __restrict__ out, int n){
    __shared__ float wl[K*M];
    for (int i = threadIdx.x; i < K*M; i += blockDim.x) wl[i] = W[i];
    __syncthreads();
    constexpr int NPB = 256 / M;
    int m  = threadIdx.x % M;
    int nl = threadIdx.x / M;
    int node = blockIdx.x * NPB + nl;
    if (node >= n) return;
    const float* row = in + (size_t)node * istride;
    float acc = 0.f;
#pragma unroll 8
    for (int k = 0; k < K; k++) acc += row[k] * wl[k*M + m];
    out[(size_t)node*M + m] = acc;
}

// mm3 + fused att epilogue
__global__ void k_mm_bf_att(const float* __restrict__ in, int istride,
                            const float* __restrict__ W,
                            const float* __restrict__ as, const float* __restrict__ adt,
                            u16* __restrict__ out, float* __restrict__ asrc,
                            float* __restrict__ adst, int n){
    constexpr int K = 32, M = 128;
    __shared__ float wl[K*M];
    for (int i = threadIdx.x; i < K*M; i += 256) wl[i] = W[i];
    __syncthreads();
    int m  = threadIdx.x % M;
    int nl = threadIdx.x / M;
    int node = blockIdx.x * 2 + nl;
    if (node >= n) return;
    const float* row = in + (size_t)node * istride;
    float acc = 0.f;
#pragma unroll 8
    for (int k = 0; k < K; k++) acc += row[k] * wl[k*M + m];
    out[(size_t)node*M + m] = f2bf(acc);
    float psv = acc * as[m];
    float pdv = acc * adt[m];
#pragma unroll
    for (int mm = 1; mm <= 16; mm <<= 1){
        psv += __shfl_xor(psv, mm, 64);
        pdv += __shfl_xor(pdv, mm, 64);
    }
    if ((m & 31) == 0){
        int hh = m >> 5;
        asrc[(size_t)node*4 + hh] = psv;
        adst[(size_t)node*4 + hh] = pdv;
    }
}

// ---------------- mm4 -> bf16 h + fused att logits ----------------
__global__ void k_mm4(const float* __restrict__ in, int istride,
                      const float* __restrict__ W,
                      const float* __restrict__ as, const float* __restrict__ adt,
                      u16* __restrict__ hb, float* __restrict__ asrc,
                      float* __restrict__ adst, int n){
    __shared__ __align__(16) float xs[64][68];
    __shared__ __align__(16) float ws[64][68];
    int tid = threadIdx.x;
    int tx = tid & 15;
    int ty = tid >> 4;
    int nbase = blockIdx.y * 64;
    int cbase = blockIdx.x * 64;
    float acc[4][4] = {};
    for (int kb = 0; kb < 128; kb += 64){
#pragma unroll
        for (int p = 0; p < 4; p++){
            int r = p*16 + ty;
            int nn = nbase + r;
            float4 v = make_float4(0.f,0.f,0.f,0.f);
            if (nn < n) v = *(const float4*)(in + (size_t)nn*istride + kb + tx*4);
            *(float4*)&xs[r][tx*4] = v;
            float4 wv = *(const float4*)(W + (size_t)(kb + r)*256 + cbase + tx*4);
            *(float4*)&ws[r][tx*4] = wv;
        }
        __syncthreads();
#pragma unroll 16
        for (int k = 0; k < 64; k++){
            float4 wv = *(const float4*)&ws[k][tx*4];
#pragma unroll
            for (int i2 = 0; i2 < 4; i2++){
                float a = xs[ty*4 + i2][k];
                acc[i2][0] += a*wv.x; acc[i2][1] += a*wv.y;
                acc[i2][2] += a*wv.z; acc[i2][3] += a*wv.w;
            }
        }
        __syncthreads();
    }
    int ht = (cbase >> 5) + (tx >> 3);
    int co = (tx & 7) * 4;
    float s0 = as[ht*32+co+0], s1 = as[ht*32+co+1], s2 = as[ht*32+co+2], s3 = as[ht*32+co+3];
    float d0 = adt[ht*32+co+0], d1 = adt[ht*32+co+1], d2 = adt[ht*32+co+2], d3 = adt[ht*32+co+3];
    float ps[4], pd[4];
#pragma unroll
    for (int i2 = 0; i2 < 4; i2++){
        ps[i2] = acc[i2][0]*s0 + acc[i2][1]*s1 + acc[i2][2]*s2 + acc[i2][3]*s3;
        pd[i2] = acc[i2][0]*d0 + acc[i2][1]*d1 + acc[i2][2]*d2 + acc[i2][3]*d3;
    }
#pragma unroll
    for (int mm = 1; mm <= 4; mm <<= 1){
#pragma unroll
        for (int i2 = 0; i2 < 4; i2++){
            ps[i2] += __shfl_xor(ps[i2], mm, 64);
            pd[i2] += __shfl_xor(pd[i2], mm, 64);
        }
    }
#pragma unroll
    for (int i2 = 0; i2 < 4; i2++){
        int nn = nbase + ty*4 + i2;
        if (nn < n){
            ushort4 v;
            v.x = f2bf(acc[i2][0]); v.y = f2bf(acc[i2][1]);
            v.z = f2bf(acc[i2][2]); v.w = f2bf(acc[i2][3]);
            *(ushort4*)(hb + (size_t)nn*256 + cbase + tx*4) = v;
            if ((tx & 7) == 0){
                asrc[(size_t)nn*8 + ht] = ps[i2];
                adst[(size_t)nn*8 + ht] = pd[i2];
            }
        }
    }
}

// ---------------- GCN aggregation: 16 lanes/node, edge loop unrolled x4 ----------------
template<int C>
__global__ void k_gcn_agg(const float* __restrict__ h, const float* __restrict__ dinv,
                          const int* __restrict__ rowptr, const int* __restrict__ csr_src,
                          const float* __restrict__ b, float* __restrict__ out,
                          int ostride, int n){
    constexpr int CL = C/4;
    constexpr int S  = 16/CL;
    int lin = threadIdx.x & 15;
    int i = blockIdx.x*16 + (threadIdx.x >> 4);
    if (i >= n) return;
    int ll = lin % CL, slot = lin / CL;
    float di = dinv[i];
    float acc[4] = {0.f,0.f,0.f,0.f};
    if (slot == 0){
        float4 t = ((const float4*)(h + (size_t)i*C))[ll];
        acc[0]=di*t.x; acc[1]=di*t.y; acc[2]=di*t.z; acc[3]=di*t.w;
    }
    int e0 = rowptr[i], e1 = rowptr[i+1];
    int e = e0 + slot;
    for (; e + 3*S < e1; e += 4*S){
        int j0 = csr_src[e], j1 = csr_src[e+S], j2 = csr_src[e+2*S], j3 = csr_src[e+3*S];
        float d0 = dinv[j0], d1 = dinv[j1], d2 = dinv[j2], d3 = dinv[j3];
        float4 t0 = ((const float4*)(h + (size_t)j0*C))[ll];
        float4 t1 = ((const float4*)(h + (size_t)j1*C))[ll];
        float4 t2 = ((const float4*)(h + (size_t)j2*C))[ll];
        float4 t3 = ((const float4*)(h + (size_t)j3*C))[ll];
        acc[0]+=d0*t0.x+d1*t1.x+d2*t2.x+d3*t3.x;
        acc[1]+=d0*t0.y+d1*t1.y+d2*t2.y+d3*t3.y;
        acc[2]+=d0*t0.z+d1*t1.z+d2*t2.z+d3*t3.z;
        acc[3]+=d0*t0.w+d1*t1.w+d2*t2.w+d3*t3.w;
    }
    for (; e < e1; e += S){
        int j = csr_src[e];
        float dj = dinv[j];
        float4 t = ((const float4*)(h + (size_t)j*C))[ll];
        acc[0]+=dj*t.x; acc[1]+=dj*t.y; acc[2]+=dj*t.z; acc[3]+=dj*t.w;
    }
#pragma unroll
    for (int m = CL; m < 16; m <<= 1){
#pragma unroll
        for (int k=0;k<4;k++) acc[k] += __shfl_xor(acc[k], m, 64);
    }
    if (slot == 0){
        float4 o;
        o.x = fmaxf(di*acc[0] + b[ll*4+0], 0.f);
        o.y = fmaxf(di*acc[1] + b[ll*4+1], 0.f);
        o.z = fmaxf(di*acc[2] + b[ll*4+2], 0.f);
        o.w = fmaxf(di*acc[3] + b[ll*4+3], 0.f);
        *(float4*)(out + (size_t)i*ostride + ll*4) = o;
    }
}

// ---------------- GAT agg layer 3 (bf16 h, H=4, C=32): wave/node, unroll x4 (R8 config) ----------------
__global__ void k_gat_agg3(const u16* __restrict__ h, const float* __restrict__ asrc,
                           const float* __restrict__ adst, const int* __restrict__ rowptr,
                           const int* __restrict__ csr_src, const float* __restrict__ b,
                           float* __restrict__ out, int ostride, int n){
    constexpr int HC = 128, CL = 16, S = 4;
    int lane = threadIdx.x & 63;
    int wid  = threadIdx.x >> 6;
    int i = blockIdx.x*4 + wid;
    if (i >= n) return;
    int ll   = lane % CL;
    int slot = lane / CL;
    int head = (ll*8)/32;
    float ad = adst[(size_t)i*4 + head];
    float acc[8] = {0.f,0.f,0.f,0.f,0.f,0.f,0.f,0.f};
    float s = 0.f;
    if (slot == 0){
        float wself = __expf(lrelu(asrc[(size_t)i*4 + head] + ad));
        uint4 t = ((const uint4*)(h + (size_t)i*HC))[ll];
        float f[8]; unpack8(t, f);
#pragma unroll
        for (int k=0;k<8;k++) acc[k] = wself*f[k];
        s = wself;
    }
    int e0 = rowptr[i], e1 = rowptr[i+1];
    int e = e0 + slot;
    for (; e + 3*S < e1; e += 4*S){
        int j0 = csr_src[e], j1 = csr_src[e+S], j2 = csr_src[e+2*S], j3 = csr_src[e+3*S];
        float w0 = __expf(lrelu(asrc[(size_t)j0*4 + head] + ad));
        float w1 = __expf(lrelu(asrc[(size_t)j1*4 + head] + ad));
        float w2 = __expf(lrelu(asrc[(size_t)j2*4 + head] + ad));
        float w3 = __expf(lrelu(asrc[(size_t)j3*4 + head] + ad));
        uint4 t0 = ((const uint4*)(h + (size_t)j0*HC))[ll];
        uint4 t1 = ((const uint4*)(h + (size_t)j1*HC))[ll];
        uint4 t2 = ((const uint4*)(h + (size_t)j2*HC))[ll];
        uint4 t3 = ((const uint4*)(h + (size_t)j3*HC))[ll];
        float f0[8], f1[8], f2[8], f3[8];
        unpack8(t0, f0); unpack8(t1, f1); unpack8(t2, f2); unpack8(t3, f3);
#pragma unroll
        for (int k=0;k<8;k++) acc[k] += w0*f0[k] + w1*f1[k] + w2*f2[k] + w3*f3[k];
        s += w0 + w1 + w2 + w3;
    }
    for (; e < e1; e += S){
        int j = csr_src[e];
        float w = __expf(lrelu(asrc[(size_t)j*4 + head] + ad));
        uint4 t = ((const uint4*)(h + (size_t)j*HC))[ll];
        float f[8]; unpack8(t, f);
#pragma unroll
        for (int k=0;k<8;k++) acc[k] += w*f[k];
        s += w;
    }
#pragma unroll
    for (int m = CL; m < 64; m <<= 1){
        s += __shfl_xor(s, m, 64);
#pragma unroll
        for (int k=0;k<8;k++) acc[k] += __shfl_xor(acc[k], m, 64);
    }
    if (slot == 0){
        float inv = 1.f / s;
        float o[8];
#pragma unroll
        for (int k=0;k<8;k++) o[k] = fmaxf(acc[k]*inv + b[ll*8+k], 0.f);
        float4* dst0 = (float4*)(out + (size_t)i*ostride + ll*8);
        dst0[0] = make_float4(o[0],o[1],o[2],o[3]);
        dst0[1] = make_float4(o[4],o[5],o[6],o[7]);
    }
}

// ---------------- GAT agg layer 4 (bf16 h, H=8, C=32): wave/node, unroll x4 (R8 config) ----------------
__global__ void k_gat_agg4(const u16* __restrict__ h, const float* __restrict__ asrc,
                           const float* __restrict__ adst, const int* __restrict__ rowptr,
                           const int* __restrict__ csr_src, const float* __restrict__ b,
                           float* __restrict__ out, int ostride, int n){
    constexpr int HC = 256, CL = 32, S = 2;
    int lane = threadIdx.x & 63;
    int wid  = threadIdx.x >> 6;
    int i = blockIdx.x*4 + wid;
    if (i >= n) return;
    int ll   = lane % CL;
    int slot = lane / CL;
    int head = ll >> 2;
    float ad = adst[(size_t)i*8 + head];
    float acc[8] = {0.f,0.f,0.f,0.f,0.f,0.f,0.f,0.f};
    float s = 0.f;
    if (slot == 0){
        float wself = __expf(lrelu(asrc[(size_t)i*8 + head] + ad));
        uint4 t = ((const uint4*)(h + (size_t)i*HC))[ll];
        float f[8]; unpack8(t, f);
#pragma unroll
        for (int k=0;k<8;k++) acc[k] = wself*f[k];
        s = wself;
    }
    int e0 = rowptr[i], e1 = rowptr[i+1];
    int e = e0 + slot;
    for (; e + 3*S < e1; e += 4*S){
        int j0 = csr_src[e], j1 = csr_src[e+S], j2 = csr_src[e+2*S], j3 = csr_src[e+3*S];
        float w0 = __expf(lrelu(asrc[(size_t)j0*8 + head] + ad));
        float w1 = __expf(lrelu(asrc[(size_t)j1*8 + head] + ad));
        float w2 = __expf(lrelu(asrc[(size_t)j2*8 + head] + ad));
        float w3 = __expf(lrelu(asrc[(size_t)j3*8 + head] + ad));
        uint4 t0 = ((const uint4*)(h + (size_t)j0*HC))[ll];
        uint4 t1 = ((const uint4*)(h + (size_t)j1*HC))[ll];
        uint4 t2 = ((const uint4*)(h + (size_t)j2*HC))[ll];
        uint4 t3 = ((const uint4*)(h + (size_t)j3*HC))[ll];
        float f0[8], f1[8], f2[8], f3[8];
        unpack8(t0, f0); unpack8(t1, f1); unpack8(t2, f2); unpack8(t3, f3);
#pragma unroll
        for (int k=0;k<8;k++) acc[k] += w0*f0[k] + w1*f1[k] + w2*f2[k] + w3*f3[k];
        s += w0 + w1 + w2 + w3;
    }
    for (; e < e1; e += S){
        int j = csr_src[e];
        float w = __expf(lrelu(asrc[(size_t)j*8 + head] + ad));
        uint4 t = ((const uint4*)(h + (size_t)j*HC))[ll];
        float f[8]; unpack8(t, f);
#pragma unroll
        for (int k=0;k<8;k++) acc[k] += w*f[k];
        s += w;
    }
    s += __shfl_xor(s, 32, 64);
#pragma unroll
    for (int k=0;k<8;k++) acc[k] += __shfl_xor(acc[k], 32, 64);
    if (slot == 0){
        float inv = 1.f / s;
        float o[8];
#pragma unroll
        for (int k=0;k<8;k++) o[k] = fmaxf(acc[k]*inv + b[ll*8+k], 0.f);
        float4* dst0 = (float4*)(out + (size_t)i*ostride + ll*8);
        dst0[0] = make_float4(o[0],o[1],o[2],o[3]);
        dst0[1] = make_float4(o[4],o[5],o[6],o[7]);
    }
}

// ---------------- pooling + fused FC ----------------
__global__ void k_pool_sum(const float* __restrict__ xj, const int* __restrict__ batch,
                           float* __restrict__ pool){
    int nb = blockIdx.x * 32;
    int ne = min(nb + 32, NN);
    if (nb >= NN) return;
    int cq = threadIdx.x;
    if (cq >= 108) return;
    float4 a = make_float4(0.f,0.f,0.f,0.f);
    int curg = batch[nb];
    for (int nn = nb; nn < ne; nn++){
        int g = batch[nn];
        if (g != curg){
            float* p = &pool[curg*432 + cq*4];
            atomicAdd(p+0, a.x); atomicAdd(p+1, a.y);
            atomicAdd(p+2, a.z); atomicAdd(p+3, a.w);
            a = make_float4(0.f,0.f,0.f,0.f); curg = g;
        }
        float4 v = *(const float4*)(xj + (size_t)nn*432 + cq*4);
        a.x += v.x; a.y += v.y; a.z += v.z; a.w += v.w;
    }
    float* p = &pool[curg*432 + cq*4];
    atomicAdd(p+0, a.x); atomicAdd(p+1, a.y);
    atomicAdd(p+2, a.z); atomicAdd(p+3, a.w);
}

// fused fc1 + fc2
__global__ void k_fc(const float* __restrict__ pool, const int* __restrict__ batch,
                     const float* __restrict__ Wf1, const float* __restrict__ bf1,
                     const float* __restrict__ Wf2, const float* __restrict__ bf2,
                     float* __restrict__ out){
    int g = blockIdx.x, j = threadIdx.x;
    int lo = 0, hi = NN;
    while (lo < hi){ int mid = (lo+hi) >> 1; if (batch[mid] < g) lo = mid+1; else hi = mid; }
    int s0 = lo;
    lo = 0; hi = NN;
    while (lo < hi){ int mid = (lo+hi) >> 1; if (batch[mid] < g+1) lo = mid+1; else hi = mid; }
    int cnt = lo - s0;
    float invc = 1.f / (float)max(cnt, 1);
    float acc = 0.f;
    for (int k = 0; k < 432; k++) acc += pool[g*432 + k] * Wf1[k*128 + j];
    float hv = fmaxf(acc * invc + bf1[j], 0.f);
    float p = hv * Wf2[j];
    for (int off = 32; off > 0; off >>= 1) p += __shfl_down(p, off, 64);
    __shared__ float part[2];
    if ((j & 63) == 0) part[j >> 6] = p;
    __syncthreads();
    if (j == 0) out[g] = part[0] + part[1] + bf2[0];
}

extern "C" void kernel_launch(void* const* d_in, const int* in_sizes, int n_in,
                              void* d_out, int out_size, void* d_ws, size_t ws_size,
                              hipStream_t stream){
    const float* x     = (const float*)d_in[0];
    const int*   ei    = (const int*)  d_in[1];
    const int*   batch = (const int*)  d_in[2];
    const float* W1 = (const float*)d_in[3];  const float* b1 = (const float*)d_in[4];
    const float* W2 = (const float*)d_in[5];  const float* b2 = (const float*)d_in[6];
    const float* W3 = (const float*)d_in[7];
    const float* as3 = (const float*)d_in[8]; const float* ad3 = (const float*)d_in[9];
    const float* b3 = (const float*)d_in[10];
    const float* W4 = (const float*)d_in[11];
    const float* as4 = (const float*)d_in[12]; const float* ad4 = (const float*)d_in[13];
    const float* b4 = (const float*)d_in[14];
    const float* Wf1 = (const float*)d_in[15]; const float* bf1 = (const float*)d_in[16];
    const float* Wf2 = (const float*)d_in[17]; const float* bf2 = (const float*)d_in[18];
    float* out = (float*)d_out;

    const int* srcE = ei;
    const int* dstE = ei + NE;

    char* base = (char*)d_ws; size_t off = 0;
    auto alloc = [&](size_t bytes)->void*{
        void* p = base + off;
        off += (bytes + 255) & ~(size_t)255;
        return p;
    };
    int*   degi    = (int*)  alloc((size_t)NN*4);
    int*   cursor  = (int*)  alloc((size_t)NN*4);
    float* dinv    = (float*)alloc((size_t)NN*4);
    int*   rowptr  = (int*)  alloc((size_t)(NN+1)*4);
    int*   bsum    = (int*)  alloc(64*4);
    int*   csr_src = (int*)  alloc((size_t)NE*4);
    float* h_buf   = (float*)alloc((size_t)NN*128*4);
    u16*   hb3     = (u16*)  alloc((size_t)NN*128*2);
    u16*   hb4     = (u16*)  alloc((size_t)NN*256*2);
    float* xj      = (float*)alloc((size_t)NN*432*4);
    float* a_src   = (float*)alloc((size_t)NN*8*4);
    float* a_dst   = (float*)alloc((size_t)NN*8*4);
    float* pool    = (float*)alloc((size_t)NG*432*4);

    hipMemsetAsync(degi, 0, (size_t)NN*4, stream);
    hipMemsetAsync(cursor, 0, (size_t)NN*4, stream);
    hipMemsetAsync(pool, 0, (size_t)NG*432*4, stream);

    const int SB = (NN + 1023)/1024;

    k_cm     <<<EB + MB1, 256, 0, stream>>>(dstE, degi, x, W1, h_buf);
    k_scan_a <<<SB, 256, 0, stream>>>(degi, rowptr, dinv, bsum, NN);
    k_scan_b <<<1, 64, 0, stream>>>(bsum, rowptr, SB, NN);
    k_scan_c <<<SB, 256, 0, stream>>>(rowptr, bsum, NN);
    k_scatter<<<EB, 256, 0, stream>>>(srcE, dstE, rowptr, cursor, csr_src, NE);

    // GCN layer 1 aggregation
    k_gcn_agg<16><<<(NN+15)/16, 256, 0, stream>>>(h_buf, dinv, rowptr, csr_src, b1, xj + 0, 432, NN);

    // GCN layer 2
    k_mm<16,32>  <<<(NN+7)/8, 256, 0, stream>>>(xj + 0, 432, W2, h_buf, NN);
    k_gcn_agg<32><<<(NN+15)/16, 256, 0, stream>>>(h_buf, dinv, rowptr, csr_src, b2, xj + 16, 432, NN);

    // GAT layer 3
    k_mm_bf_att<<<(NN+1)/2, 256, 0, stream>>>(xj + 16, 432, W3, as3, ad3, hb3, a_src, a_dst, NN);
    k_gat_agg3<<<(NN+3)/4, 256, 0, stream>>>(hb3, a_src, a_dst, rowptr, csr_src, b3, xj + 48, 432, NN);

    // GAT layer 4
    {
        dim3 grid(4, (NN + 63)/64);
        k_mm4<<<grid, 256, 0, stream>>>(xj + 48, 432, W4, as4, ad4, hb4, a_src, a_dst, NN);
    }
    k_gat_agg4<<<(NN+3)/4, 256, 0, stream>>>(hb4, a_src, a_dst, rowptr, csr_src, b4, xj + 176, 432, NN);

    // pooling + fused FC
    k_pool_sum<<<(NN+31)/32, 128, 0, stream>>>(xj, batch, pool);
    k_fc<<<NG, 128, 0, stream>>>(pool, batch, Wf1, bf1, Wf2, bf2, out);
}

// Round 11
// 488.646 us; speedup vs baseline: 1.0560x; 1.0399x over previous
//
#include <hip/hip_runtime.h>
#include <hip/hip_bf16.h>

#define NN 50000
#define NE 800000
#define NG 128
#define EB ((NE + 255)/256)
#define MB1 ((NN + 15)/16)
#define PB 54   // pool-zero blocks: 128*432/1024

typedef unsigned short u16;
typedef unsigned int u32;

__device__ __forceinline__ float lrelu(float x){ return x > 0.f ? x : 0.2f*x; }
__device__ __forceinline__ u16 f2bf(float f){
    __hip_bfloat16 h = __float2bfloat16(f);
    return *(u16*)&h;
}
// unpack 8 bf16 (as uint4) -> 8 floats
__device__ __forceinline__ void unpack8(uint4 t, float* f){
    f[0]=__uint_as_float(t.x<<16); f[1]=__uint_as_float(t.x&0xffff0000u);
    f[2]=__uint_as_float(t.y<<16); f[3]=__uint_as_float(t.y&0xffff0000u);
    f[4]=__uint_as_float(t.z<<16); f[5]=__uint_as_float(t.z&0xffff0000u);
    f[6]=__uint_as_float(t.w<<16); f[7]=__uint_as_float(t.w&0xffff0000u);
}

// ---------------- fused: edge count (atomics) + mm1 (x@W1 -> bf16 h1) + pool zero ----------------
__global__ void k_cm(const int* __restrict__ dstE, int* __restrict__ degi,
                     const float* __restrict__ x, const float* __restrict__ W1,
                     u16* __restrict__ h1, float* __restrict__ pool){
    if (blockIdx.x < EB){
        int e = blockIdx.x*256 + threadIdx.x;
        if (e < NE) atomicAdd(&degi[dstE[e]], 1);
        return;
    }
    if (blockIdx.x >= EB + MB1){
        int idx = (blockIdx.x - EB - MB1)*1024 + threadIdx.x*4;
        if (idx < NG*432) *(float4*)(pool + idx) = make_float4(0.f,0.f,0.f,0.f);
        return;
    }
    __shared__ float wl[128*16];
    for (int i = threadIdx.x; i < 128*16; i += 256) wl[i] = W1[i];
    __syncthreads();
    int m  = threadIdx.x & 15;
    int nl = threadIdx.x >> 4;
    int node = (blockIdx.x - EB) * 16 + nl;
    if (node >= NN) return;
    const float* row = x + (size_t)node * 128;
    float acc = 0.f;
#pragma unroll 8
    for (int k = 0; k < 128; k++) acc += row[k] * wl[k*16 + m];
    h1[(size_t)node*16 + m] = f2bf(acc);
}

// scan stage A + dinv + cursor zero
__global__ void k_scan_a(const int* __restrict__ deg, int* __restrict__ rowptr,
                         float* __restrict__ dinv, int* __restrict__ cursor,
                         int* __restrict__ bsum, int n){
    __shared__ int lds[256];
    int base = blockIdx.x*1024 + threadIdx.x*4;
    int v[4]; int s = 0;
#pragma unroll
    for (int k=0;k<4;k++){ v[k] = (base+k < n) ? deg[base+k] : 0; s += v[k]; }
    lds[threadIdx.x] = s;
    __syncthreads();
    for (int off=1; off<256; off<<=1){
        int t = (threadIdx.x>=off) ? lds[threadIdx.x-off] : 0;
        __syncthreads(); lds[threadIdx.x] += t; __syncthreads();
    }
    int run = lds[threadIdx.x] - s;
#pragma unroll
    for (int k=0;k<4;k++){
        if (base+k < n){
            rowptr[base+k] = run;
            dinv[base+k] = rsqrtf((float)(v[k] + 1));   // +1 = self loop
            cursor[base+k] = 0;
        }
        run += v[k];
    }
    if (threadIdx.x == 255) bsum[blockIdx.x] = lds[255];
}

// scan stage C (absorbs old stage B): each block reduces bsum[0..blockIdx) itself
__global__ void k_scan_c(int* __restrict__ rowptr, const int* __restrict__ bsum,
                         int nb, int n){
    __shared__ int off_s;
    if (threadIdx.x < 64){
        int v = ((int)threadIdx.x < nb && (int)threadIdx.x < (int)blockIdx.x)
                ? bsum[threadIdx.x] : 0;
        for (int m=1; m<64; m<<=1) v += __shfl_xor(v, m, 64);
        if (threadIdx.x == 0) off_s = v;
    }
    __syncthreads();
    int o = off_s;
    int idx = blockIdx.x*1024 + threadIdx.x*4;
#pragma unroll
    for (int k=0;k<4;k++) if (idx+k < n) rowptr[idx+k] += o;
    if ((int)blockIdx.x == nb-1 && threadIdx.x == 0) rowptr[n] = o + bsum[nb-1];
}

__global__ void k_scatter(const int* __restrict__ src, const int* __restrict__ dst,
                          const int* __restrict__ rowptr, int* __restrict__ cursor,
                          int* __restrict__ csr_src, int E){
    int e = blockIdx.x*blockDim.x + threadIdx.x;
    if (e < E){
        int d = dst[e];
        int pos = rowptr[d] + atomicAdd(&cursor[d], 1);
        csr_src[pos] = src[e];
    }
}

// ---------------- fused GCN1 agg (bf16 h1) + relu + mm2 -> bf16 h2 ----------------
// 16 lanes/node: CL=2 chan-lanes (8 bf16 each) x S=8 edge slots, unroll x2
__global__ void k_gcn_agg16_mm2(const u16* __restrict__ h1, const float* __restrict__ dinv,
                                const int* __restrict__ rowptr, const int* __restrict__ csr_src,
                                const float* __restrict__ b1, const float* __restrict__ W2,
                                float* __restrict__ xj, u16* __restrict__ h2, int n){
    __shared__ float w2s[16*32];
    __shared__ float x1s[16][17];
    for (int i = threadIdx.x; i < 512; i += 256) w2s[i] = W2[i];
    int lin = threadIdx.x & 15;
    int nl  = threadIdx.x >> 4;
    int i = blockIdx.x*16 + nl;          // NN % 16 == 0: always valid
    int ll = lin & 1, slot = lin >> 1;
    float di = dinv[i];
    float acc[8] = {0.f,0.f,0.f,0.f,0.f,0.f,0.f,0.f};
    if (slot == 0){
        uint4 t = *(const uint4*)(h1 + (size_t)i*16 + ll*8);
        float f[8]; unpack8(t, f);
#pragma unroll
        for (int k=0;k<8;k++) acc[k] = di*f[k];
    }
    int e0 = rowptr[i], e1 = rowptr[i+1];
    int e = e0 + slot;
    for (; e + 8 < e1; e += 16){
        int j0 = csr_src[e], j1 = csr_src[e+8];
        float d0 = dinv[j0], d1 = dinv[j1];
        uint4 t0 = *(const uint4*)(h1 + (size_t)j0*16 + ll*8);
        uint4 t1 = *(const uint4*)(h1 + (size_t)j1*16 + ll*8);
        float f0[8], f1[8]; unpack8(t0, f0); unpack8(t1, f1);
#pragma unroll
        for (int k=0;k<8;k++) acc[k] += d0*f0[k] + d1*f1[k];
    }
    if (e < e1){
        int j = csr_src[e];
        float dj = dinv[j];
        uint4 t = *(const uint4*)(h1 + (size_t)j*16 + ll*8);
        float f[8]; unpack8(t, f);
#pragma unroll
        for (int k=0;k<8;k++) acc[k] += dj*f[k];
    }
#pragma unroll
    for (int m = 2; m < 16; m <<= 1){
#pragma unroll
        for (int k=0;k<8;k++) acc[k] += __shfl_xor(acc[k], m, 64);
    }
    if (slot == 0){
        float o[8];
#pragma unroll
        for (int k=0;k<8;k++){
            o[k] = fmaxf(di*acc[k] + b1[ll*8+k], 0.f);
            x1s[nl][ll*8+k] = o[k];
        }
        float4* dst0 = (float4*)(xj + (size_t)i*432 + ll*8);
        dst0[0] = make_float4(o[0],o[1],o[2],o[3]);
        dst0[1] = make_float4(o[4],o[5],o[6],o[7]);
    }
    __syncthreads();
    // mm2: 16x32 per node; each lane computes 2 output chans
    float a0 = 0.f, a1 = 0.f;
    int m0 = lin*2;
#pragma unroll
    for (int k=0;k<16;k++){
        float xv = x1s[nl][k];
        a0 += xv * w2s[k*32 + m0];
        a1 += xv * w2s[k*32 + m0 + 1];
    }
    u32 pk = (u32)f2bf(a0) | ((u32)f2bf(a1) << 16);
    *(u32*)(h2 + (size_t)i*32 + m0) = pk;
}

// ---------------- GCN2 aggregation (bf16 h2): CL=4 x S=4, unroll x4 ----------------
__global__ void k_gcn_agg32(const u16* __restrict__ h2, const float* __restrict__ dinv,
                            const int* __restrict__ rowptr, const int* __restrict__ csr_src,
                            const float* __restrict__ b2, float* __restrict__ out,
                            int ostride, int n){
    int lin = threadIdx.x & 15;
    int i = blockIdx.x*16 + (threadIdx.x >> 4);
    if (i >= n) return;
    int ll = lin & 3, slot = lin >> 2;
    float di = dinv[i];
    float acc[8] = {0.f,0.f,0.f,0.f,0.f,0.f,0.f,0.f};
    if (slot == 0){
        uint4 t = *(const uint4*)(h2 + (size_t)i*32 + ll*8);
        float f[8]; unpack8(t, f);
#pragma unroll
        for (int k=0;k<8;k++) acc[k] = di*f[k];
    }
    int e0 = rowptr[i], e1 = rowptr[i+1];
    int e = e0 + slot;
    for (; e + 12 < e1; e += 16){
        int j0 = csr_src[e], j1 = csr_src[e+4], j2 = csr_src[e+8], j3 = csr_src[e+12];
        float d0 = dinv[j0], d1 = dinv[j1], d2 = dinv[j2], d3 = dinv[j3];
        uint4 t0 = *(const uint4*)(h2 + (size_t)j0*32 + ll*8);
        uint4 t1 = *(const uint4*)(h2 + (size_t)j1*32 + ll*8);
        uint4 t2 = *(const uint4*)(h2 + (size_t)j2*32 + ll*8);
        uint4 t3 = *(const uint4*)(h2 + (size_t)j3*32 + ll*8);
        float f0[8], f1[8], f2[8], f3[8];
        unpack8(t0, f0); unpack8(t1, f1); unpack8(t2, f2); unpack8(t3, f3);
#pragma unroll
        for (int k=0;k<8;k++) acc[k] += d0*f0[k] + d1*f1[k] + d2*f2[k] + d3*f3[k];
    }
    for (; e < e1; e += 4){
        int j = csr_src[e];
        float dj = dinv[j];
        uint4 t = *(const uint4*)(h2 + (size_t)j*32 + ll*8);
        float f[8]; unpack8(t, f);
#pragma unroll
        for (int k=0;k<8;k++) acc[k] += dj*f[k];
    }
#pragma unroll
    for (int m = 4; m < 16; m <<= 1){
#pragma unroll
        for (int k=0;k<8;k++) acc[k] += __shfl_xor(acc[k], m, 64);
    }
    if (slot == 0){
        float o[8];
#pragma unroll
        for (int k=0;k<8;k++) o[k] = fmaxf(di*acc[k] + b2[ll*8+k], 0.f);
        float4* dst0 = (float4*)(out + (size_t)i*ostride + ll*8);
        dst0[0] = make_float4(o[0],o[1],o[2],o[3]);
        dst0[1] = make_float4(o[4],o[5],o[6],o[7]);
    }
}

// mm3 + fused att epilogue
__global__ void k_mm_bf_att(const float* __restrict__ in, int istride,
                            const float* __restrict__ W,
                            const float* __restrict__ as, const float* __restrict__ adt,
                            u16* __restrict__ out, float* __restrict__ asrc,
                            float* __restrict__ adst, int n){
    constexpr int K = 32, M = 128;
    __shared__ float wl[K*M];
    for (int i = threadIdx.x; i < K*M; i += 256) wl[i] = W[i];
    __syncthreads();
    int m  = threadIdx.x % M;
    int nl = threadIdx.x / M;
    int node = blockIdx.x * 2 + nl;
    if (node >= n) return;
    const float* row = in + (size_t)node * istride;
    float acc = 0.f;
#pragma unroll 8
    for (int k = 0; k < K; k++) acc += row[k] * wl[k*M + m];
    out[(size_t)node*M + m] = f2bf(acc);
    float psv = acc * as[m];
    float pdv = acc * adt[m];
#pragma unroll
    for (int mm = 1; mm <= 16; mm <<= 1){
        psv += __shfl_xor(psv, mm, 64);
        pdv += __shfl_xor(pdv, mm, 64);
    }
    if ((m & 31) == 0){
        int hh = m >> 5;
        asrc[(size_t)node*4 + hh] = psv;
        adst[(size_t)node*4 + hh] = pdv;
    }
}

// ---------------- mm4 -> bf16 h + fused att logits ----------------
__global__ void k_mm4(const float* __restrict__ in, int istride,
                      const float* __restrict__ W,
                      const float* __restrict__ as, const float* __restrict__ adt,
                      u16* __restrict__ hb, float* __restrict__ asrc,
                      float* __restrict__ adst, int n){
    __shared__ __align__(16) float xs[64][68];
    __shared__ __align__(16) float ws[64][68];
    int tid = threadIdx.x;
    int tx = tid & 15;
    int ty = tid >> 4;
    int nbase = blockIdx.y * 64;
    int cbase = blockIdx.x * 64;
    float acc[4][4] = {};
    for (int kb = 0; kb < 128; kb += 64){
#pragma unroll
        for (int p = 0; p < 4; p++){
            int r = p*16 + ty;
            int nn = nbase + r;
            float4 v = make_float4(0.f,0.f,0.f,0.f);
            if (nn < n) v = *(const float4*)(in + (size_t)nn*istride + kb + tx*4);
            *(float4*)&xs[r][tx*4] = v;
            float4 wv = *(const float4*)(W + (size_t)(kb + r)*256 + cbase + tx*4);
            *(float4*)&ws[r][tx*4] = wv;
        }
        __syncthreads();
#pragma unroll 16
        for (int k = 0; k < 64; k++){
            float4 wv = *(const float4*)&ws[k][tx*4];
#pragma unroll
            for (int i2 = 0; i2 < 4; i2++){
                float a = xs[ty*4 + i2][k];
                acc[i2][0] += a*wv.x; acc[i2][1] += a*wv.y;
                acc[i2][2] += a*wv.z; acc[i2][3] += a*wv.w;
            }
        }
        __syncthreads();
    }
    int ht = (cbase >> 5) + (tx >> 3);
    int co = (tx & 7) * 4;
    float s0 = as[ht*32+co+0], s1 = as[ht*32+co+1], s2 = as[ht*32+co+2], s3 = as[ht*32+co+3];
    float d0 = adt[ht*32+co+0], d1 = adt[ht*32+co+1], d2 = adt[ht*32+co+2], d3 = adt[ht*32+co+3];
    float ps[4], pd[4];
#pragma unroll
    for (int i2 = 0; i2 < 4; i2++){
        ps[i2] = acc[i2][0]*s0 + acc[i2][1]*s1 + acc[i2][2]*s2 + acc[i2][3]*s3;
        pd[i2] = acc[i2][0]*d0 + acc[i2][1]*d1 + acc[i2][2]*d2 + acc[i2][3]*d3;
    }
#pragma unroll
    for (int mm = 1; mm <= 4; mm <<= 1){
#pragma unroll
        for (int i2 = 0; i2 < 4; i2++){
            ps[i2] += __shfl_xor(ps[i2], mm, 64);
            pd[i2] += __shfl_xor(pd[i2], mm, 64);
        }
    }
#pragma unroll
    for (int i2 = 0; i2 < 4; i2++){
        int nn = nbase + ty*4 + i2;
        if (nn < n){
            ushort4 v;
            v.x = f2bf(acc[i2][0]); v.y = f2bf(acc[i2][1]);
            v.z = f2bf(acc[i2][2]); v.w = f2bf(acc[i2][3]);
            *(ushort4*)(hb + (size_t)nn*256 + cbase + tx*4) = v;
            if ((tx & 7) == 0){
                asrc[(size_t)nn*8 + ht] = ps[i2];
                adst[(size_t)nn*8 + ht] = pd[i2];
            }
        }
    }
}

// ---------------- GAT agg layer 3 (bf16 h, H=4): wave/node, CL=16 x S=4, unroll x4 ----------------
__global__ void k_gat_agg3(const u16* __restrict__ h, const float* __restrict__ asrc,
                           const float* __restrict__ adst, const int* __restrict__ rowptr,
                           const int* __restrict__ csr_src, const float* __restrict__ b,
                           float* __restrict__ out, int ostride, int n){
    constexpr int HC = 128, CL = 16, S = 4;
    int lane = threadIdx.x & 63;
    int wid  = threadIdx.x >> 6;
    int i = blockIdx.x*4 + wid;
    if (i >= n) return;
    int ll   = lane % CL;
    int slot = lane / CL;
    int head = (ll*8)/32;
    float ad = adst[(size_t)i*4 + head];
    float acc[8] = {0.f,0.f,0.f,0.f,0.f,0.f,0.f,0.f};
    float s = 0.f;
    if (slot == 0){
        float wself = __expf(lrelu(asrc[(size_t)i*4 + head] + ad));
        uint4 t = ((const uint4*)(h + (size_t)i*HC))[ll];
        float f[8]; unpack8(t, f);
#pragma unroll
        for (int k=0;k<8;k++) acc[k] = wself*f[k];
        s = wself;
    }
    int e0 = rowptr[i], e1 = rowptr[i+1];
    int e = e0 + slot;
    for (; e + 3*S < e1; e += 4*S){
        int j0 = csr_src[e], j1 = csr_src[e+S], j2 = csr_src[e+2*S], j3 = csr_src[e+3*S];
        float w0 = __expf(lrelu(asrc[(size_t)j0*4 + head] + ad));
        float w1 = __expf(lrelu(asrc[(size_t)j1*4 + head] + ad));
        float w2 = __expf(lrelu(asrc[(size_t)j2*4 + head] + ad));
        float w3 = __expf(lrelu(asrc[(size_t)j3*4 + head] + ad));
        uint4 t0 = ((const uint4*)(h + (size_t)j0*HC))[ll];
        uint4 t1 = ((const uint4*)(h + (size_t)j1*HC))[ll];
        uint4 t2 = ((const uint4*)(h + (size_t)j2*HC))[ll];
        uint4 t3 = ((const uint4*)(h + (size_t)j3*HC))[ll];
        float f0[8], f1[8], f2[8], f3[8];
        unpack8(t0, f0); unpack8(t1, f1); unpack8(t2, f2); unpack8(t3, f3);
#pragma unroll
        for (int k=0;k<8;k++) acc[k] += w0*f0[k] + w1*f1[k] + w2*f2[k] + w3*f3[k];
        s += w0 + w1 + w2 + w3;
    }
    for (; e < e1; e += S){
        int j = csr_src[e];
        float w = __expf(lrelu(asrc[(size_t)j*4 + head] + ad));
        uint4 t = ((const uint4*)(h + (size_t)j*HC))[ll];
        float f[8]; unpack8(t, f);
#pragma unroll
        for (int k=0;k<8;k++) acc[k] += w*f[k];
        s += w;
    }
#pragma unroll
    for (int m = CL; m < 64; m <<= 1){
        s += __shfl_xor(s, m, 64);
#pragma unroll
        for (int k=0;k<8;k++) acc[k] += __shfl_xor(acc[k], m, 64);
    }
    if (slot == 0){
        float inv = 1.f / s;
        float o[8];
#pragma unroll
        for (int k=0;k<8;k++) o[k] = fmaxf(acc[k]*inv + b[ll*8+k], 0.f);
        float4* dst0 = (float4*)(out + (size_t)i*ostride + ll*8);
        dst0[0] = make_float4(o[0],o[1],o[2],o[3]);
        dst0[1] = make_float4(o[4],o[5],o[6],o[7]);
    }
}

// ---------------- GAT agg layer 4 (bf16 h, H=8): wave/node, CL=32 x S=2, unroll x4 ----------------
__global__ void k_gat_agg4(const u16* __restrict__ h, const float* __restrict__ asrc,
                           const float* __restrict__ adst, const int* __restrict__ rowptr,
                           const int* __restrict__ csr_src, const float* __restrict__ b,
                           float* __restrict__ out, int ostride, int n){
    constexpr int HC = 256, CL = 32, S = 2;
    int lane = threadIdx.x & 63;
    int wid  = threadIdx.x >> 6;
    int i = blockIdx.x*4 + wid;
    if (i >= n) return;
    int ll   = lane % CL;
    int slot = lane / CL;
    int head = ll >> 2;
    float ad = adst[(size_t)i*8 + head];
    float acc[8] = {0.f,0.f,0.f,0.f,0.f,0.f,0.f,0.f};
    float s = 0.f;
    if (slot == 0){
        float wself = __expf(lrelu(asrc[(size_t)i*8 + head] + ad));
        uint4 t = ((const uint4*)(h + (size_t)i*HC))[ll];
        float f[8]; unpack8(t, f);
#pragma unroll
        for (int k=0;k<8;k++) acc[k] = wself*f[k];
        s = wself;
    }
    int e0 = rowptr[i], e1 = rowptr[i+1];
    int e = e0 + slot;
    for (; e + 3*S < e1; e += 4*S){
        int j0 = csr_src[e], j1 = csr_src[e+S], j2 = csr_src[e+2*S], j3 = csr_src[e+3*S];
        float w0 = __expf(lrelu(asrc[(size_t)j0*8 + head] + ad));
        float w1 = __expf(lrelu(asrc[(size_t)j1*8 + head] + ad));
        float w2 = __expf(lrelu(asrc[(size_t)j2*8 + head] + ad));
        float w3 = __expf(lrelu(asrc[(size_t)j3*8 + head] + ad));
        uint4 t0 = ((const uint4*)(h + (size_t)j0*HC))[ll];
        uint4 t1 = ((const uint4*)(h + (size_t)j1*HC))[ll];
        uint4 t2 = ((const uint4*)(h + (size_t)j2*HC))[ll];
        uint4 t3 = ((const uint4*)(h + (size_t)j3*HC))[ll];
        float f0[8], f1[8], f2[8], f3[8];
        unpack8(t0, f0); unpack8(t1, f1); unpack8(t2, f2); unpack8(t3, f3);
#pragma unroll
        for (int k=0;k<8;k++) acc[k] += w0*f0[k] + w1*f1[k] + w2*f2[k] + w3*f3[k];
        s += w0 + w1 + w2 + w3;
    }
    for (; e < e1; e += S){
        int j = csr_src[e];
        float w = __expf(lrelu(asrc[(size_t)j*8 + head] + ad));
        uint4 t = ((const uint4*)(h + (size_t)j*HC))[ll];
        float f[8]; unpack8(t, f);
#pragma unroll
        for (int k=0;k<8;k++) acc[k] += w*f[k];
        s += w;
    }
    s += __shfl_xor(s, 32, 64);
#pragma unroll
    for (int k=0;k<8;k++) acc[k] += __shfl_xor(acc[k], 32, 64);
    if (slot == 0){
        float inv = 1.f / s;
        float o[8];
#pragma unroll
        for (int k=0;k<8;k++) o[k] = fmaxf(acc[k]*inv + b[ll*8+k], 0.f);
        float4* dst0 = (float4*)(out + (size_t)i*ostride + ll*8);
        dst0[0] = make_float4(o[0],o[1],o[2],o[3]);
        dst0[1] = make_float4(o[4],o[5],o[6],o[7]);
    }
}

// ---------------- pooling + fused FC ----------------
__global__ void k_pool_sum(const float* __restrict__ xj, const int* __restrict__ batch,
                           float* __restrict__ pool){
    int nb = blockIdx.x * 32;
    int ne = min(nb + 32, NN);
    if (nb >= NN) return;
    int cq = threadIdx.x;
    if (cq >= 108) return;
    float4 a = make_float4(0.f,0.f,0.f,0.f);
    int curg = batch[nb];
    for (int nn = nb; nn < ne; nn++){
        int g = batch[nn];
        if (g != curg){
            float* p = &pool[curg*432 + cq*4];
            atomicAdd(p+0, a.x); atomicAdd(p+1, a.y);
            atomicAdd(p+2, a.z); atomicAdd(p+3, a.w);
            a = make_float4(0.f,0.f,0.f,0.f); curg = g;
        }
        float4 v = *(const float4*)(xj + (size_t)nn*432 + cq*4);
        a.x += v.x; a.y += v.y; a.z += v.z; a.w += v.w;
    }
    float* p = &pool[curg*432 + cq*4];
    atomicAdd(p+0, a.x); atomicAdd(p+1, a.y);
    atomicAdd(p+2, a.z); atomicAdd(p+3, a.w);
}

// fused fc1 + fc2
__global__ void k_fc(const float* __restrict__ pool, const int* __restrict__ batch,
                     const float* __restrict__ Wf1, const float* __restrict__ bf1,
                     const float* __restrict__ Wf2, const float* __restrict__ bf2,
                     float* __restrict__ out){
    int g = blockIdx.x, j = threadIdx.x;
    int lo = 0, hi = NN;
    while (lo < hi){ int mid = (lo+hi) >> 1; if (batch[mid] < g) lo = mid+1; else hi = mid; }
    int s0 = lo;
    lo = 0; hi = NN;
    while (lo < hi){ int mid = (lo+hi) >> 1; if (batch[mid] < g+1) lo = mid+1; else hi = mid; }
    int cnt = lo - s0;
    float invc = 1.f / (float)max(cnt, 1);
    float acc = 0.f;
    for (int k = 0; k < 432; k++) acc += pool[g*432 + k] * Wf1[k*128 + j];
    float hv = fmaxf(acc * invc + bf1[j], 0.f);
    float p = hv * Wf2[j];
    for (int off = 32; off > 0; off >>= 1) p += __shfl_down(p, off, 64);
    __shared__ float part[2];
    if ((j & 63) == 0) part[j >> 6] = p;
    __syncthreads();
    if (j == 0) out[g] = part[0] + part[1] + bf2[0];
}

extern "C" void kernel_launch(void* const* d_in, const int* in_sizes, int n_in,
                              void* d_out, int out_size, void* d_ws, size_t ws_size,
                              hipStream_t stream){
    const float* x     = (const float*)d_in[0];
    const int*   ei    = (const int*)  d_in[1];
    const int*   batch = (const int*)  d_in[2];
    const float* W1 = (const float*)d_in[3];  const float* b1 = (const float*)d_in[4];
    const float* W2 = (const float*)d_in[5];  const float* b2 = (const float*)d_in[6];
    const float* W3 = (const float*)d_in[7];
    const float* as3 = (const float*)d_in[8]; const float* ad3 = (const float*)d_in[9];
    const float* b3 = (const float*)d_in[10];
    const float* W4 = (const float*)d_in[11];
    const float* as4 = (const float*)d_in[12]; const float* ad4 = (const float*)d_in[13];
    const float* b4 = (const float*)d_in[14];
    const float* Wf1 = (const float*)d_in[15]; const float* bf1 = (const float*)d_in[16];
    const float* Wf2 = (const float*)d_in[17]; const float* bf2 = (const float*)d_in[18];
    float* out = (float*)d_out;

    const int* srcE = ei;
    const int* dstE = ei + NE;

    char* base = (char*)d_ws; size_t off = 0;
    auto alloc = [&](size_t bytes)->void*{
        void* p = base + off;
        off += (bytes + 255) & ~(size_t)255;
        return p;
    };
    int*   degi    = (int*)  alloc((size_t)NN*4);
    int*   cursor  = (int*)  alloc((size_t)NN*4);
    float* dinv    = (float*)alloc((size_t)NN*4);
    int*   rowptr  = (int*)  alloc((size_t)(NN+1)*4);
    int*   bsum    = (int*)  alloc(64*4);
    int*   csr_src = (int*)  alloc((size_t)NE*4);
    u16*   h1b     = (u16*)  alloc((size_t)NN*16*2);    // bf16 h1
    u16*   h2b     = (u16*)  alloc((size_t)NN*32*2);    // bf16 h2
    u16*   hb3     = (u16*)  alloc((size_t)NN*128*2);   // bf16 h3
    u16*   hb4     = (u16*)  alloc((size_t)NN*256*2);   // bf16 h4
    float* xj      = (float*)alloc((size_t)NN*432*4);
    float* a_src   = (float*)alloc((size_t)NN*8*4);
    float* a_dst   = (float*)alloc((size_t)NN*8*4);
    float* pool    = (float*)alloc((size_t)NG*432*4);

    hipMemsetAsync(degi, 0, (size_t)NN*4, stream);

    const int SB = (NN + 1023)/1024;

    // count atomics + mm1(bf16) + pool zero
    k_cm     <<<EB + MB1 + PB, 256, 0, stream>>>(dstE, degi, x, W1, h1b, pool);
    k_scan_a <<<SB, 256, 0, stream>>>(degi, rowptr, dinv, cursor, bsum, NN);
    k_scan_c <<<SB, 256, 0, stream>>>(rowptr, bsum, SB, NN);
    k_scatter<<<EB, 256, 0, stream>>>(srcE, dstE, rowptr, cursor, csr_src, NE);

    // GCN layer 1 agg + relu + mm2 fused (bf16 h1 -> x1(fp32 in xj) + bf16 h2)
    k_gcn_agg16_mm2<<<(NN+15)/16, 256, 0, stream>>>(h1b, dinv, rowptr, csr_src, b1, W2, xj, h2b, NN);

    // GCN layer 2 agg (bf16 h2 -> x2 fp32 in xj+16)
    k_gcn_agg32<<<(NN+15)/16, 256, 0, stream>>>(h2b, dinv, rowptr, csr_src, b2, xj + 16, 432, NN);

    // GAT layer 3
    k_mm_bf_att<<<(NN+1)/2, 256, 0, stream>>>(xj + 16, 432, W3, as3, ad3, hb3, a_src, a_dst, NN);
    k_gat_agg3<<<(NN+3)/4, 256, 0, stream>>>(hb3, a_src, a_dst, rowptr, csr_src, b3, xj + 48, 432, NN);

    // GAT layer 4
    {
        dim3 grid(4, (NN + 63)/64);
        k_mm4<<<grid, 256, 0, stream>>>(xj + 48, 432, W4, as4, ad4, hb4, a_src, a_dst, NN);
    }
    k_gat_agg4<<<(NN+3)/4, 256, 0, stream>>>(hb4, a_src, a_dst, rowptr, csr_src, b4, xj + 176, 432, NN);

    // pooling + fused FC
    k_pool_sum<<<(NN+31)/32, 128, 0, stream>>>(xj, batch, pool);
    k_fc<<<NG, 128, 0, stream>>>(pool, batch, Wf1, bf1, Wf2, bf2, out);
}

// Round 12
// 452.966 us; speedup vs baseline: 1.1392x; 1.0788x over previous
//
#include <hip/hip_runtime.h>
#include <hip/hip_bf16.h>

#define NN 50000
#define NE 800000
#define NG 128
#define EB ((NE + 255)/256)
#define MB1 ((NN + 15)/16)
#define PB 54   // pool-zero blocks: 128*432/1024

typedef unsigned short u16;
typedef unsigned int u32;
typedef float f32x4 __attribute__((ext_vector_type(4)));
typedef short s16x8 __attribute__((ext_vector_type(8)));

__device__ __forceinline__ float lrelu(float x){ return x > 0.f ? x : 0.2f*x; }
__device__ __forceinline__ u16 f2bf(float f){
    __hip_bfloat16 h = __float2bfloat16(f);
    return *(u16*)&h;
}
// unpack 8 bf16 (as uint4) -> 8 floats
__device__ __forceinline__ void unpack8(uint4 t, float* f){
    f[0]=__uint_as_float(t.x<<16); f[1]=__uint_as_float(t.x&0xffff0000u);
    f[2]=__uint_as_float(t.y<<16); f[3]=__uint_as_float(t.y&0xffff0000u);
    f[4]=__uint_as_float(t.z<<16); f[5]=__uint_as_float(t.z&0xffff0000u);
    f[6]=__uint_as_float(t.w<<16); f[7]=__uint_as_float(t.w&0xffff0000u);
}

// ---------------- fused: edge count (atomics) + mm1 (x@W1 -> bf16 h1) + pool zero ----------------
__global__ void k_cm(const int* __restrict__ dstE, int* __restrict__ degi,
                     const float* __restrict__ x, const float* __restrict__ W1,
                     u16* __restrict__ h1, float* __restrict__ pool){
    if (blockIdx.x < EB){
        int e = blockIdx.x*256 + threadIdx.x;
        if (e < NE) atomicAdd(&degi[dstE[e]], 1);
        return;
    }
    if (blockIdx.x >= EB + MB1){
        int idx = (blockIdx.x - EB - MB1)*1024 + threadIdx.x*4;
        if (idx < NG*432) *(float4*)(pool + idx) = make_float4(0.f,0.f,0.f,0.f);
        return;
    }
    __shared__ float wl[128*16];
    for (int i = threadIdx.x; i < 128*16; i += 256) wl[i] = W1[i];
    __syncthreads();
    int m  = threadIdx.x & 15;
    int nl = threadIdx.x >> 4;
    int node = (blockIdx.x - EB) * 16 + nl;
    if (node >= NN) return;
    const float* row = x + (size_t)node * 128;
    float acc = 0.f;
#pragma unroll 8
    for (int k = 0; k < 128; k++) acc += row[k] * wl[k*16 + m];
    h1[(size_t)node*16 + m] = f2bf(acc);
}

// scan stage A + dinv + cursor zero
__global__ void k_scan_a(const int* __restrict__ deg, int* __restrict__ rowptr,
                         float* __restrict__ dinv, int* __restrict__ cursor,
                         int* __restrict__ bsum, int n){
    __shared__ int lds[256];
    int base = blockIdx.x*1024 + threadIdx.x*4;
    int v[4]; int s = 0;
#pragma unroll
    for (int k=0;k<4;k++){ v[k] = (base+k < n) ? deg[base+k] : 0; s += v[k]; }
    lds[threadIdx.x] = s;
    __syncthreads();
    for (int off=1; off<256; off<<=1){
        int t = (threadIdx.x>=off) ? lds[threadIdx.x-off] : 0;
        __syncthreads(); lds[threadIdx.x] += t; __syncthreads();
    }
    int run = lds[threadIdx.x] - s;
#pragma unroll
    for (int k=0;k<4;k++){
        if (base+k < n){
            rowptr[base+k] = run;
            dinv[base+k] = rsqrtf((float)(v[k] + 1));   // +1 = self loop
            cursor[base+k] = 0;
        }
        run += v[k];
    }
    if (threadIdx.x == 255) bsum[blockIdx.x] = lds[255];
}

// scan stage C: each block reduces bsum prefix itself
__global__ void k_scan_c(int* __restrict__ rowptr, const int* __restrict__ bsum,
                         int nb, int n){
    __shared__ int off_s;
    if (threadIdx.x < 64){
        int v = ((int)threadIdx.x < nb && (int)threadIdx.x < (int)blockIdx.x)
                ? bsum[threadIdx.x] : 0;
        for (int m=1; m<64; m<<=1) v += __shfl_xor(v, m, 64);
        if (threadIdx.x == 0) off_s = v;
    }
    __syncthreads();
    int o = off_s;
    int idx = blockIdx.x*1024 + threadIdx.x*4;
#pragma unroll
    for (int k=0;k<4;k++) if (idx+k < n) rowptr[idx+k] += o;
    if ((int)blockIdx.x == nb-1 && threadIdx.x == 0) rowptr[n] = o + bsum[nb-1];
}

__global__ void k_scatter(const int* __restrict__ src, const int* __restrict__ dst,
                          const int* __restrict__ rowptr, int* __restrict__ cursor,
                          int* __restrict__ csr_src, int E){
    int e = blockIdx.x*blockDim.x + threadIdx.x;
    if (e < E){
        int d = dst[e];
        int pos = rowptr[d] + atomicAdd(&cursor[d], 1);
        csr_src[pos] = src[e];
    }
}

// ---------------- fused GCN1 agg (bf16 h1) + relu + mm2 -> bf16 h2 ----------------
__global__ void k_gcn_agg16_mm2(const u16* __restrict__ h1, const float* __restrict__ dinv,
                                const int* __restrict__ rowptr, const int* __restrict__ csr_src,
                                const float* __restrict__ b1, const float* __restrict__ W2,
                                float* __restrict__ xj, u16* __restrict__ h2, int n){
    __shared__ float w2s[16*32];
    __shared__ float x1s[16][17];
    for (int i = threadIdx.x; i < 512; i += 256) w2s[i] = W2[i];
    int lin = threadIdx.x & 15;
    int nl  = threadIdx.x >> 4;
    int i = blockIdx.x*16 + nl;
    int ll = lin & 1, slot = lin >> 1;
    float di = dinv[i];
    float acc[8] = {0.f,0.f,0.f,0.f,0.f,0.f,0.f,0.f};
    if (slot == 0){
        uint4 t = *(const uint4*)(h1 + (size_t)i*16 + ll*8);
        float f[8]; unpack8(t, f);
#pragma unroll
        for (int k=0;k<8;k++) acc[k] = di*f[k];
    }
    int e0 = rowptr[i], e1 = rowptr[i+1];
    int e = e0 + slot;
    for (; e + 8 < e1; e += 16){
        int j0 = csr_src[e], j1 = csr_src[e+8];
        float d0 = dinv[j0], d1 = dinv[j1];
        uint4 t0 = *(const uint4*)(h1 + (size_t)j0*16 + ll*8);
        uint4 t1 = *(const uint4*)(h1 + (size_t)j1*16 + ll*8);
        float f0[8], f1[8]; unpack8(t0, f0); unpack8(t1, f1);
#pragma unroll
        for (int k=0;k<8;k++) acc[k] += d0*f0[k] + d1*f1[k];
    }
    if (e < e1){
        int j = csr_src[e];
        float dj = dinv[j];
        uint4 t = *(const uint4*)(h1 + (size_t)j*16 + ll*8);
        float f[8]; unpack8(t, f);
#pragma unroll
        for (int k=0;k<8;k++) acc[k] += dj*f[k];
    }
#pragma unroll
    for (int m = 2; m < 16; m <<= 1){
#pragma unroll
        for (int k=0;k<8;k++) acc[k] += __shfl_xor(acc[k], m, 64);
    }
    if (slot == 0){
        float o[8];
#pragma unroll
        for (int k=0;k<8;k++){
            o[k] = fmaxf(di*acc[k] + b1[ll*8+k], 0.f);
            x1s[nl][ll*8+k] = o[k];
        }
        float4* dst0 = (float4*)(xj + (size_t)i*432 + ll*8);
        dst0[0] = make_float4(o[0],o[1],o[2],o[3]);
        dst0[1] = make_float4(o[4],o[5],o[6],o[7]);
    }
    __syncthreads();
    float a0 = 0.f, a1 = 0.f;
    int m0 = lin*2;
#pragma unroll
    for (int k=0;k<16;k++){
        float xv = x1s[nl][k];
        a0 += xv * w2s[k*32 + m0];
        a1 += xv * w2s[k*32 + m0 + 1];
    }
    u32 pk = (u32)f2bf(a0) | ((u32)f2bf(a1) << 16);
    *(u32*)(h2 + (size_t)i*32 + m0) = pk;
}

// ---------------- GCN2 aggregation (bf16 h2) ----------------
__global__ void k_gcn_agg32(const u16* __restrict__ h2, const float* __restrict__ dinv,
                            const int* __restrict__ rowptr, const int* __restrict__ csr_src,
                            const float* __restrict__ b2, float* __restrict__ out,
                            int ostride, int n){
    int lin = threadIdx.x & 15;
    int i = blockIdx.x*16 + (threadIdx.x >> 4);
    if (i >= n) return;
    int ll = lin & 3, slot = lin >> 2;
    float di = dinv[i];
    float acc[8] = {0.f,0.f,0.f,0.f,0.f,0.f,0.f,0.f};
    if (slot == 0){
        uint4 t = *(const uint4*)(h2 + (size_t)i*32 + ll*8);
        float f[8]; unpack8(t, f);
#pragma unroll
        for (int k=0;k<8;k++) acc[k] = di*f[k];
    }
    int e0 = rowptr[i], e1 = rowptr[i+1];
    int e = e0 + slot;
    for (; e + 12 < e1; e += 16){
        int j0 = csr_src[e], j1 = csr_src[e+4], j2 = csr_src[e+8], j3 = csr_src[e+12];
        float d0 = dinv[j0], d1 = dinv[j1], d2 = dinv[j2], d3 = dinv[j3];
        uint4 t0 = *(const uint4*)(h2 + (size_t)j0*32 + ll*8);
        uint4 t1 = *(const uint4*)(h2 + (size_t)j1*32 + ll*8);
        uint4 t2 = *(const uint4*)(h2 + (size_t)j2*32 + ll*8);
        uint4 t3 = *(const uint4*)(h2 + (size_t)j3*32 + ll*8);
        float f0[8], f1[8], f2[8], f3[8];
        unpack8(t0, f0); unpack8(t1, f1); unpack8(t2, f2); unpack8(t3, f3);
#pragma unroll
        for (int k=0;k<8;k++) acc[k] += d0*f0[k] + d1*f1[k] + d2*f2[k] + d3*f3[k];
    }
    for (; e < e1; e += 4){
        int j = csr_src[e];
        float dj = dinv[j];
        uint4 t = *(const uint4*)(h2 + (size_t)j*32 + ll*8);
        float f[8]; unpack8(t, f);
#pragma unroll
        for (int k=0;k<8;k++) acc[k] += dj*f[k];
    }
#pragma unroll
    for (int m = 4; m < 16; m <<= 1){
#pragma unroll
        for (int k=0;k<8;k++) acc[k] += __shfl_xor(acc[k], m, 64);
    }
    if (slot == 0){
        float o[8];
#pragma unroll
        for (int k=0;k<8;k++) o[k] = fmaxf(di*acc[k] + b2[ll*8+k], 0.f);
        float4* dst0 = (float4*)(out + (size_t)i*ostride + ll*8);
        dst0[0] = make_float4(o[0],o[1],o[2],o[3]);
        dst0[1] = make_float4(o[4],o[5],o[6],o[7]);
    }
}

// mm3 + fused att epilogue
__global__ void k_mm_bf_att(const float* __restrict__ in, int istride,
                            const float* __restrict__ W,
                            const float* __restrict__ as, const float* __restrict__ adt,
                            u16* __restrict__ out, float* __restrict__ asrc,
                            float* __restrict__ adst, int n){
    constexpr int K = 32, M = 128;
    __shared__ float wl[K*M];
    for (int i = threadIdx.x; i < K*M; i += 256) wl[i] = W[i];
    __syncthreads();
    int m  = threadIdx.x % M;
    int nl = threadIdx.x / M;
    int node = blockIdx.x * 2 + nl;
    if (node >= n) return;
    const float* row = in + (size_t)node * istride;
    float acc = 0.f;
#pragma unroll 8
    for (int k = 0; k < K; k++) acc += row[k] * wl[k*M + m];
    out[(size_t)node*M + m] = f2bf(acc);
    float psv = acc * as[m];
    float pdv = acc * adt[m];
#pragma unroll
    for (int mm = 1; mm <= 16; mm <<= 1){
        psv += __shfl_xor(psv, mm, 64);
        pdv += __shfl_xor(pdv, mm, 64);
    }
    if ((m & 31) == 0){
        int hh = m >> 5;
        asrc[(size_t)node*4 + hh] = psv;
        adst[(size_t)node*4 + hh] = pdv;
    }
}

// ---------------- mm4 via bf16 MFMA: [N,128]@[128,256] -> bf16 h4 + att logits ----------------
// grid (2, 782): block = 64 nodes x 128 cols; wave = 16 nodes x 8 col-tiles of 16
// A-frag: A[m=lane&15][k=quad*8+j]; B-frag: B[k=quad*8+j][n=lane&15]; D: col=lane&15,row=quad*4+reg
__global__ void k_mm4_mfma(const float* __restrict__ xjin, const float* __restrict__ W4,
                           const float* __restrict__ as, const float* __restrict__ adt,
                           u16* __restrict__ hb, float* __restrict__ asrc,
                           float* __restrict__ adst){
    __shared__ u16 outS[64][136];     // 272B row stride: 16B aligned
    __shared__ float asS[128], adS[128];
    int tid = threadIdx.x;
    int lane = tid & 63, w = tid >> 6;
    int cbase = blockIdx.x * 128;
    int nbase = blockIdx.y * 64;
    if (tid < 128){ asS[tid] = as[cbase + tid]; adS[tid] = adt[cbase + tid]; }
    int q = lane >> 4, r16 = lane & 15;
    int m = nbase + w*16 + r16;       // node this lane supplies for A
    f32x4 acc[8] = {};
    const float* arow = xjin + 48 + (size_t)m*432;
    for (int s = 0; s < 4; s++){
        s16x8 af = (s16x8){0,0,0,0,0,0,0,0};
        if (m < NN){
            const float* ap = arow + s*32 + q*8;
            float4 a0 = *(const float4*)ap;
            float4 a1 = *(const float4*)(ap+4);
            af[0]=(short)f2bf(a0.x); af[1]=(short)f2bf(a0.y);
            af[2]=(short)f2bf(a0.z); af[3]=(short)f2bf(a0.w);
            af[4]=(short)f2bf(a1.x); af[5]=(short)f2bf(a1.y);
            af[6]=(short)f2bf(a1.z); af[7]=(short)f2bf(a1.w);
        }
        int k0 = s*32 + q*8;
#pragma unroll
        for (int t = 0; t < 8; t++){
            const float* bp = W4 + (size_t)k0*256 + cbase + t*16 + r16;
            s16x8 bf;
            bf[0]=(short)f2bf(bp[0]);    bf[1]=(short)f2bf(bp[256]);
            bf[2]=(short)f2bf(bp[512]);  bf[3]=(short)f2bf(bp[768]);
            bf[4]=(short)f2bf(bp[1024]); bf[5]=(short)f2bf(bp[1280]);
            bf[6]=(short)f2bf(bp[1536]); bf[7]=(short)f2bf(bp[1792]);
            acc[t] = __builtin_amdgcn_mfma_f32_16x16x32_bf16(af, bf, acc[t], 0, 0, 0);
        }
    }
    // acc -> LDS (own wave rows)
#pragma unroll
    for (int t = 0; t < 8; t++){
#pragma unroll
        for (int r = 0; r < 4; r++){
            outS[w*16 + q*4 + r][t*16 + r16] = f2bf(acc[t][r]);
        }
    }
    __syncthreads();
    // logits: 16 nodes x 4 head-parts per wave (bf16-sourced, R3-R6-style)
    {
        int row = w*16 + r16;
        int node = nbase + row;
        float ps = 0.f, pd = 0.f;
        const u16* orow = &outS[row][q*32];
#pragma unroll
        for (int c = 0; c < 32; c++){
            float f = __uint_as_float(((u32)orow[c]) << 16);
            ps += f * asS[q*32 + c];
            pd += f * adS[q*32 + c];
        }
        if (node < NN){
            int hg = (cbase >> 5) + q;
            asrc[(size_t)node*8 + hg] = ps;
            adst[(size_t)node*8 + hg] = pd;
        }
    }
    // coalesced h4 store
    for (int idx = tid; idx < 1024; idx += 256){
        int row = idx >> 4, seg = idx & 15;
        int node = nbase + row;
        if (node < NN){
            uint4 v = *(const uint4*)&outS[row][seg*8];
            *(uint4*)(hb + (size_t)node*256 + cbase + seg*8) = v;
        }
    }
}

// ---------------- GAT agg layer 3 (bf16 h, H=4): wave/node, CL=16 x S=4, unroll x4 ----------------
__global__ void k_gat_agg3(const u16* __restrict__ h, const float* __restrict__ asrc,
                           const float* __restrict__ adst, const int* __restrict__ rowptr,
                           const int* __restrict__ csr_src, const float* __restrict__ b,
                           float* __restrict__ out, int ostride, int n){
    constexpr int HC = 128, CL = 16, S = 4;
    int lane = threadIdx.x & 63;
    int wid  = threadIdx.x >> 6;
    int i = blockIdx.x*4 + wid;
    if (i >= n) return;
    int ll   = lane % CL;
    int slot = lane / CL;
    int head = (ll*8)/32;
    float ad = adst[(size_t)i*4 + head];
    float acc[8] = {0.f,0.f,0.f,0.f,0.f,0.f,0.f,0.f};
    float s = 0.f;
    if (slot == 0){
        float wself = __expf(lrelu(asrc[(size_t)i*4 + head] + ad));
        uint4 t = ((const uint4*)(h + (size_t)i*HC))[ll];
        float f[8]; unpack8(t, f);
#pragma unroll
        for (int k=0;k<8;k++) acc[k] = wself*f[k];
        s = wself;
    }
    int e0 = rowptr[i], e1 = rowptr[i+1];
    int e = e0 + slot;
    for (; e + 3*S < e1; e += 4*S){
        int j0 = csr_src[e], j1 = csr_src[e+S], j2 = csr_src[e+2*S], j3 = csr_src[e+3*S];
        float w0 = __expf(lrelu(asrc[(size_t)j0*4 + head] + ad));
        float w1 = __expf(lrelu(asrc[(size_t)j1*4 + head] + ad));
        float w2 = __expf(lrelu(asrc[(size_t)j2*4 + head] + ad));
        float w3 = __expf(lrelu(asrc[(size_t)j3*4 + head] + ad));
        uint4 t0 = ((const uint4*)(h + (size_t)j0*HC))[ll];
        uint4 t1 = ((const uint4*)(h + (size_t)j1*HC))[ll];
        uint4 t2 = ((const uint4*)(h + (size_t)j2*HC))[ll];
        uint4 t3 = ((const uint4*)(h + (size_t)j3*HC))[ll];
        float f0[8], f1[8], f2[8], f3[8];
        unpack8(t0, f0); unpack8(t1, f1); unpack8(t2, f2); unpack8(t3, f3);
#pragma unroll
        for (int k=0;k<8;k++) acc[k] += w0*f0[k] + w1*f1[k] + w2*f2[k] + w3*f3[k];
        s += w0 + w1 + w2 + w3;
    }
    for (; e < e1; e += S){
        int j = csr_src[e];
        float w = __expf(lrelu(asrc[(size_t)j*4 + head] + ad));
        uint4 t = ((const uint4*)(h + (size_t)j*HC))[ll];
        float f[8]; unpack8(t, f);
#pragma unroll
        for (int k=0;k<8;k++) acc[k] += w*f[k];
        s += w;
    }
#pragma unroll
    for (int m = CL; m < 64; m <<= 1){
        s += __shfl_xor(s, m, 64);
#pragma unroll
        for (int k=0;k<8;k++) acc[k] += __shfl_xor(acc[k], m, 64);
    }
    if (slot == 0){
        float inv = 1.f / s;
        float o[8];
#pragma unroll
        for (int k=0;k<8;k++) o[k] = fmaxf(acc[k]*inv + b[ll*8+k], 0.f);
        float4* dst0 = (float4*)(out + (size_t)i*ostride + ll*8);
        dst0[0] = make_float4(o[0],o[1],o[2],o[3]);
        dst0[1] = make_float4(o[4],o[5],o[6],o[7]);
    }
}

// ---------------- GAT agg layer 4 (bf16 h, H=8): wave/node, CL=32 x S=2, unroll x4 ----------------
__global__ void k_gat_agg4(const u16* __restrict__ h, const float* __restrict__ asrc,
                           const float* __restrict__ adst, const int* __restrict__ rowptr,
                           const int* __restrict__ csr_src, const float* __restrict__ b,
                           float* __restrict__ out, int ostride, int n){
    constexpr int HC = 256, CL = 32, S = 2;
    int lane = threadIdx.x & 63;
    int wid  = threadIdx.x >> 6;
    int i = blockIdx.x*4 + wid;
    if (i >= n) return;
    int ll   = lane % CL;
    int slot = lane / CL;
    int head = ll >> 2;
    float ad = adst[(size_t)i*8 + head];
    float acc[8] = {0.f,0.f,0.f,0.f,0.f,0.f,0.f,0.f};
    float s = 0.f;
    if (slot == 0){
        float wself = __expf(lrelu(asrc[(size_t)i*8 + head] + ad));
        uint4 t = ((const uint4*)(h + (size_t)i*HC))[ll];
        float f[8]; unpack8(t, f);
#pragma unroll
        for (int k=0;k<8;k++) acc[k] = wself*f[k];
        s = wself;
    }
    int e0 = rowptr[i], e1 = rowptr[i+1];
    int e = e0 + slot;
    for (; e + 3*S < e1; e += 4*S){
        int j0 = csr_src[e], j1 = csr_src[e+S], j2 = csr_src[e+2*S], j3 = csr_src[e+3*S];
        float w0 = __expf(lrelu(asrc[(size_t)j0*8 + head] + ad));
        float w1 = __expf(lrelu(asrc[(size_t)j1*8 + head] + ad));
        float w2 = __expf(lrelu(asrc[(size_t)j2*8 + head] + ad));
        float w3 = __expf(lrelu(asrc[(size_t)j3*8 + head] + ad));
        uint4 t0 = ((const uint4*)(h + (size_t)j0*HC))[ll];
        uint4 t1 = ((const uint4*)(h + (size_t)j1*HC))[ll];
        uint4 t2 = ((const uint4*)(h + (size_t)j2*HC))[ll];
        uint4 t3 = ((const uint4*)(h + (size_t)j3*HC))[ll];
        float f0[8], f1[8], f2[8], f3[8];
        unpack8(t0, f0); unpack8(t1, f1); unpack8(t2, f2); unpack8(t3, f3);
#pragma unroll
        for (int k=0;k<8;k++) acc[k] += w0*f0[k] + w1*f1[k] + w2*f2[k] + w3*f3[k];
        s += w0 + w1 + w2 + w3;
    }
    for (; e < e1; e += S){
        int j = csr_src[e];
        float w = __expf(lrelu(asrc[(size_t)j*8 + head] + ad));
        uint4 t = ((const uint4*)(h + (size_t)j*HC))[ll];
        float f[8]; unpack8(t, f);
#pragma unroll
        for (int k=0;k<8;k++) acc[k] += w*f[k];
        s += w;
    }
    s += __shfl_xor(s, 32, 64);
#pragma unroll
    for (int k=0;k<8;k++) acc[k] += __shfl_xor(acc[k], 32, 64);
    if (slot == 0){
        float inv = 1.f / s;
        float o[8];
#pragma unroll
        for (int k=0;k<8;k++) o[k] = fmaxf(acc[k]*inv + b[ll*8+k], 0.f);
        float4* dst0 = (float4*)(out + (size_t)i*ostride + ll*8);
        dst0[0] = make_float4(o[0],o[1],o[2],o[3]);
        dst0[1] = make_float4(o[4],o[5],o[6],o[7]);
    }
}

// ---------------- pooling + fused FC ----------------
__global__ void k_pool_sum(const float* __restrict__ xj, const int* __restrict__ batch,
                           float* __restrict__ pool){
    int nb = blockIdx.x * 32;
    int ne = min(nb + 32, NN);
    if (nb >= NN) return;
    int cq = threadIdx.x;
    if (cq >= 108) return;
    float4 a = make_float4(0.f,0.f,0.f,0.f);
    int curg = batch[nb];
    for (int nn = nb; nn < ne; nn++){
        int g = batch[nn];
        if (g != curg){
            float* p = &pool[curg*432 + cq*4];
            atomicAdd(p+0, a.x); atomicAdd(p+1, a.y);
            atomicAdd(p+2, a.z); atomicAdd(p+3, a.w);
            a = make_float4(0.f,0.f,0.f,0.f); curg = g;
        }
        float4 v = *(const float4*)(xj + (size_t)nn*432 + cq*4);
        a.x += v.x; a.y += v.y; a.z += v.z; a.w += v.w;
    }
    float* p = &pool[curg*432 + cq*4];
    atomicAdd(p+0, a.x); atomicAdd(p+1, a.y);
    atomicAdd(p+2, a.z); atomicAdd(p+3, a.w);
}

// fused fc1 + fc2
__global__ void k_fc(const float* __restrict__ pool, const int* __restrict__ batch,
                     const float* __restrict__ Wf1, const float* __restrict__ bf1,
                     const float* __restrict__ Wf2, const float* __restrict__ bf2,
                     float* __restrict__ out){
    int g = blockIdx.x, j = threadIdx.x;
    int lo = 0, hi = NN;
    while (lo < hi){ int mid = (lo+hi) >> 1; if (batch[mid] < g) lo = mid+1; else hi = mid; }
    int s0 = lo;
    lo = 0; hi = NN;
    while (lo < hi){ int mid = (lo+hi) >> 1; if (batch[mid] < g+1) lo = mid+1; else hi = mid; }
    int cnt = lo - s0;
    float invc = 1.f / (float)max(cnt, 1);
    float acc = 0.f;
    for (int k = 0; k < 432; k++) acc += pool[g*432 + k] * Wf1[k*128 + j];
    float hv = fmaxf(acc * invc + bf1[j], 0.f);
    float p = hv * Wf2[j];
    for (int off = 32; off > 0; off >>= 1) p += __shfl_down(p, off, 64);
    __shared__ float part[2];
    if ((j & 63) == 0) part[j >> 6] = p;
    __syncthreads();
    if (j == 0) out[g] = part[0] + part[1] + bf2[0];
}

extern "C" void kernel_launch(void* const* d_in, const int* in_sizes, int n_in,
                              void* d_out, int out_size, void* d_ws, size_t ws_size,
                              hipStream_t stream){
    const float* x     = (const float*)d_in[0];
    const int*   ei    = (const int*)  d_in[1];
    const int*   batch = (const int*)  d_in[2];
    const float* W1 = (const float*)d_in[3];  const float* b1 = (const float*)d_in[4];
    const float* W2 = (const float*)d_in[5];  const float* b2 = (const float*)d_in[6];
    const float* W3 = (const float*)d_in[7];
    const float* as3 = (const float*)d_in[8]; const float* ad3 = (const float*)d_in[9];
    const float* b3 = (const float*)d_in[10];
    const float* W4 = (const float*)d_in[11];
    const float* as4 = (const float*)d_in[12]; const float* ad4 = (const float*)d_in[13];
    const float* b4 = (const float*)d_in[14];
    const float* Wf1 = (const float*)d_in[15]; const float* bf1 = (const float*)d_in[16];
    const float* Wf2 = (const float*)d_in[17]; const float* bf2 = (const float*)d_in[18];
    float* out = (float*)d_out;

    const int* srcE = ei;
    const int* dstE = ei + NE;

    char* base = (char*)d_ws; size_t off = 0;
    auto alloc = [&](size_t bytes)->void*{
        void* p = base + off;
        off += (bytes + 255) & ~(size_t)255;
        return p;
    };
    int*   degi    = (int*)  alloc((size_t)NN*4);
    int*   cursor  = (int*)  alloc((size_t)NN*4);
    float* dinv    = (float*)alloc((size_t)NN*4);
    int*   rowptr  = (int*)  alloc((size_t)(NN+1)*4);
    int*   bsum    = (int*)  alloc(64*4);
    int*   csr_src = (int*)  alloc((size_t)NE*4);
    u16*   h1b     = (u16*)  alloc((size_t)NN*16*2);
    u16*   h2b     = (u16*)  alloc((size_t)NN*32*2);
    u16*   hb3     = (u16*)  alloc((size_t)NN*128*2);
    u16*   hb4     = (u16*)  alloc((size_t)NN*256*2);
    float* xj      = (float*)alloc((size_t)NN*432*4);
    float* a_src   = (float*)alloc((size_t)NN*8*4);
    float* a_dst   = (float*)alloc((size_t)NN*8*4);
    float* pool    = (float*)alloc((size_t)NG*432*4);

    hipMemsetAsync(degi, 0, (size_t)NN*4, stream);

    const int SB = (NN + 1023)/1024;

    k_cm     <<<EB + MB1 + PB, 256, 0, stream>>>(dstE, degi, x, W1, h1b, pool);
    k_scan_a <<<SB, 256, 0, stream>>>(degi, rowptr, dinv, cursor, bsum, NN);
    k_scan_c <<<SB, 256, 0, stream>>>(rowptr, bsum, SB, NN);
    k_scatter<<<EB, 256, 0, stream>>>(srcE, dstE, rowptr, cursor, csr_src, NE);

    // GCN layer 1 agg + relu + mm2 fused
    k_gcn_agg16_mm2<<<(NN+15)/16, 256, 0, stream>>>(h1b, dinv, rowptr, csr_src, b1, W2, xj, h2b, NN);

    // GCN layer 2 agg
    k_gcn_agg32<<<(NN+15)/16, 256, 0, stream>>>(h2b, dinv, rowptr, csr_src, b2, xj + 16, 432, NN);

    // GAT layer 3
    k_mm_bf_att<<<(NN+1)/2, 256, 0, stream>>>(xj + 16, 432, W3, as3, ad3, hb3, a_src, a_dst, NN);
    k_gat_agg3<<<(NN+3)/4, 256, 0, stream>>>(hb3, a_src, a_dst, rowptr, csr_src, b3, xj + 48, 432, NN);

    // GAT layer 4: MFMA mm4 + fused logits
    {
        dim3 grid(2, (NN + 63)/64);
        k_mm4_mfma<<<grid, 256, 0, stream>>>(xj, W4, as4, ad4, hb4, a_src, a_dst);
    }
    k_gat_agg4<<<(NN+3)/4, 256, 0, stream>>>(hb4, a_src, a_dst, rowptr, csr_src, b4, xj + 176, 432, NN);

    // pooling + fused FC
    k_pool_sum<<<(NN+31)/32, 128, 0, stream>>>(xj, batch, pool);
    k_fc<<<NG, 128, 0, stream>>>(pool, batch, Wf1, bf1, Wf2, bf2, out);
}

// Round 13
// 414.616 us; speedup vs baseline: 1.2446x; 1.0925x over previous
//
#include <hip/hip_runtime.h>
#include <hip/hip_bf16.h>

#define NN 50000
#define NE 800000
#define NG 128
#define EB ((NE + 255)/256)
#define MB1 ((NN + 15)/16)
#define PB 54   // pool-zero blocks: 128*432/1024

typedef unsigned short u16;
typedef unsigned int u32;
typedef float f32x4 __attribute__((ext_vector_type(4)));
typedef short s16x8 __attribute__((ext_vector_type(8)));

__device__ __forceinline__ float lrelu(float x){ return x > 0.f ? x : 0.2f*x; }
__device__ __forceinline__ u16 f2bf(float f){
    __hip_bfloat16 h = __float2bfloat16(f);
    return *(u16*)&h;
}
// unpack 8 bf16 (as uint4) -> 8 floats
__device__ __forceinline__ void unpack8(uint4 t, float* f){
    f[0]=__uint_as_float(t.x<<16); f[1]=__uint_as_float(t.x&0xffff0000u);
    f[2]=__uint_as_float(t.y<<16); f[3]=__uint_as_float(t.y&0xffff0000u);
    f[4]=__uint_as_float(t.z<<16); f[5]=__uint_as_float(t.z&0xffff0000u);
    f[6]=__uint_as_float(t.w<<16); f[7]=__uint_as_float(t.w&0xffff0000u);
}

// ---------------- fused: edge count (atomics) + mm1 (x@W1 -> bf16 h1) + pool zero ----------------
__global__ void k_cm(const int* __restrict__ dstE, int* __restrict__ degi,
                     const float* __restrict__ x, const float* __restrict__ W1,
                     u16* __restrict__ h1, float* __restrict__ pool){
    if (blockIdx.x < EB){
        int e = blockIdx.x*256 + threadIdx.x;
        if (e < NE) atomicAdd(&degi[dstE[e]], 1);
        return;
    }
    if (blockIdx.x >= EB + MB1){
        int idx = (blockIdx.x - EB - MB1)*1024 + threadIdx.x*4;
        if (idx < NG*432) *(float4*)(pool + idx) = make_float4(0.f,0.f,0.f,0.f);
        return;
    }
    __shared__ float wl[128*16];
    for (int i = threadIdx.x; i < 128*16; i += 256) wl[i] = W1[i];
    __syncthreads();
    int m  = threadIdx.x & 15;
    int nl = threadIdx.x >> 4;
    int node = (blockIdx.x - EB) * 16 + nl;
    if (node >= NN) return;
    const float* row = x + (size_t)node * 128;
    float acc = 0.f;
#pragma unroll 8
    for (int k = 0; k < 128; k++) acc += row[k] * wl[k*16 + m];
    h1[(size_t)node*16 + m] = f2bf(acc);
}

// scan stage A + dinv + cursor zero
__global__ void k_scan_a(const int* __restrict__ deg, int* __restrict__ rowptr,
                         float* __restrict__ dinv, int* __restrict__ cursor,
                         int* __restrict__ bsum, int n){
    __shared__ int lds[256];
    int base = blockIdx.x*1024 + threadIdx.x*4;
    int v[4]; int s = 0;
#pragma unroll
    for (int k=0;k<4;k++){ v[k] = (base+k < n) ? deg[base+k] : 0; s += v[k]; }
    lds[threadIdx.x] = s;
    __syncthreads();
    for (int off=1; off<256; off<<=1){
        int t = (threadIdx.x>=off) ? lds[threadIdx.x-off] : 0;
        __syncthreads(); lds[threadIdx.x] += t; __syncthreads();
    }
    int run = lds[threadIdx.x] - s;
#pragma unroll
    for (int k=0;k<4;k++){
        if (base+k < n){
            rowptr[base+k] = run;
            dinv[base+k] = rsqrtf((float)(v[k] + 1));   // +1 = self loop
            cursor[base+k] = 0;
        }
        run += v[k];
    }
    if (threadIdx.x == 255) bsum[blockIdx.x] = lds[255];
}

// scan stage C: each block reduces bsum prefix itself
__global__ void k_scan_c(int* __restrict__ rowptr, const int* __restrict__ bsum,
                         int nb, int n){
    __shared__ int off_s;
    if (threadIdx.x < 64){
        int v = ((int)threadIdx.x < nb && (int)threadIdx.x < (int)blockIdx.x)
                ? bsum[threadIdx.x] : 0;
        for (int m=1; m<64; m<<=1) v += __shfl_xor(v, m, 64);
        if (threadIdx.x == 0) off_s = v;
    }
    __syncthreads();
    int o = off_s;
    int idx = blockIdx.x*1024 + threadIdx.x*4;
#pragma unroll
    for (int k=0;k<4;k++) if (idx+k < n) rowptr[idx+k] += o;
    if ((int)blockIdx.x == nb-1 && threadIdx.x == 0) rowptr[n] = o + bsum[nb-1];
}

__global__ void k_scatter(const int* __restrict__ src, const int* __restrict__ dst,
                          const int* __restrict__ rowptr, int* __restrict__ cursor,
                          int* __restrict__ csr_src, int E){
    int e = blockIdx.x*blockDim.x + threadIdx.x;
    if (e < E){
        int d = dst[e];
        int pos = rowptr[d] + atomicAdd(&cursor[d], 1);
        csr_src[pos] = src[e];
    }
}

// ---------------- fused GCN1 agg (bf16 h1) + relu + mm2 -> bf16 h2 ----------------
__global__ void k_gcn_agg16_mm2(const u16* __restrict__ h1, const float* __restrict__ dinv,
                                const int* __restrict__ rowptr, const int* __restrict__ csr_src,
                                const float* __restrict__ b1, const float* __restrict__ W2,
                                float* __restrict__ xj, u16* __restrict__ h2, int n){
    __shared__ float w2s[16*32];
    __shared__ float x1s[16][17];
    for (int i = threadIdx.x; i < 512; i += 256) w2s[i] = W2[i];
    int lin = threadIdx.x & 15;
    int nl  = threadIdx.x >> 4;
    int i = blockIdx.x*16 + nl;
    int ll = lin & 1, slot = lin >> 1;
    float di = dinv[i];
    float acc[8] = {0.f,0.f,0.f,0.f,0.f,0.f,0.f,0.f};
    if (slot == 0){
        uint4 t = *(const uint4*)(h1 + (size_t)i*16 + ll*8);
        float f[8]; unpack8(t, f);
#pragma unroll
        for (int k=0;k<8;k++) acc[k] = di*f[k];
    }
    int e0 = rowptr[i], e1 = rowptr[i+1];
    int e = e0 + slot;
    for (; e + 8 < e1; e += 16){
        int j0 = csr_src[e], j1 = csr_src[e+8];
        float d0 = dinv[j0], d1 = dinv[j1];
        uint4 t0 = *(const uint4*)(h1 + (size_t)j0*16 + ll*8);
        uint4 t1 = *(const uint4*)(h1 + (size_t)j1*16 + ll*8);
        float f0[8], f1[8]; unpack8(t0, f0); unpack8(t1, f1);
#pragma unroll
        for (int k=0;k<8;k++) acc[k] += d0*f0[k] + d1*f1[k];
    }
    if (e < e1){
        int j = csr_src[e];
        float dj = dinv[j];
        uint4 t = *(const uint4*)(h1 + (size_t)j*16 + ll*8);
        float f[8]; unpack8(t, f);
#pragma unroll
        for (int k=0;k<8;k++) acc[k] += dj*f[k];
    }
#pragma unroll
    for (int m = 2; m < 16; m <<= 1){
#pragma unroll
        for (int k=0;k<8;k++) acc[k] += __shfl_xor(acc[k], m, 64);
    }
    if (slot == 0){
        float o[8];
#pragma unroll
        for (int k=0;k<8;k++){
            o[k] = fmaxf(di*acc[k] + b1[ll*8+k], 0.f);
            x1s[nl][ll*8+k] = o[k];
        }
        float4* dst0 = (float4*)(xj + (size_t)i*432 + ll*8);
        dst0[0] = make_float4(o[0],o[1],o[2],o[3]);
        dst0[1] = make_float4(o[4],o[5],o[6],o[7]);
    }
    __syncthreads();
    float a0 = 0.f, a1 = 0.f;
    int m0 = lin*2;
#pragma unroll
    for (int k=0;k<16;k++){
        float xv = x1s[nl][k];
        a0 += xv * w2s[k*32 + m0];
        a1 += xv * w2s[k*32 + m0 + 1];
    }
    u32 pk = (u32)f2bf(a0) | ((u32)f2bf(a1) << 16);
    *(u32*)(h2 + (size_t)i*32 + m0) = pk;
}

// ---------------- GCN2 aggregation (bf16 h2) ----------------
__global__ void k_gcn_agg32(const u16* __restrict__ h2, const float* __restrict__ dinv,
                            const int* __restrict__ rowptr, const int* __restrict__ csr_src,
                            const float* __restrict__ b2, float* __restrict__ out,
                            int ostride, int n){
    int lin = threadIdx.x & 15;
    int i = blockIdx.x*16 + (threadIdx.x >> 4);
    if (i >= n) return;
    int ll = lin & 3, slot = lin >> 2;
    float di = dinv[i];
    float acc[8] = {0.f,0.f,0.f,0.f,0.f,0.f,0.f,0.f};
    if (slot == 0){
        uint4 t = *(const uint4*)(h2 + (size_t)i*32 + ll*8);
        float f[8]; unpack8(t, f);
#pragma unroll
        for (int k=0;k<8;k++) acc[k] = di*f[k];
    }
    int e0 = rowptr[i], e1 = rowptr[i+1];
    int e = e0 + slot;
    for (; e + 12 < e1; e += 16){
        int j0 = csr_src[e], j1 = csr_src[e+4], j2 = csr_src[e+8], j3 = csr_src[e+12];
        float d0 = dinv[j0], d1 = dinv[j1], d2 = dinv[j2], d3 = dinv[j3];
        uint4 t0 = *(const uint4*)(h2 + (size_t)j0*32 + ll*8);
        uint4 t1 = *(const uint4*)(h2 + (size_t)j1*32 + ll*8);
        uint4 t2 = *(const uint4*)(h2 + (size_t)j2*32 + ll*8);
        uint4 t3 = *(const uint4*)(h2 + (size_t)j3*32 + ll*8);
        float f0[8], f1[8], f2[8], f3[8];
        unpack8(t0, f0); unpack8(t1, f1); unpack8(t2, f2); unpack8(t3, f3);
#pragma unroll
        for (int k=0;k<8;k++) acc[k] += d0*f0[k] + d1*f1[k] + d2*f2[k] + d3*f3[k];
    }
    for (; e < e1; e += 4){
        int j = csr_src[e];
        float dj = dinv[j];
        uint4 t = *(const uint4*)(h2 + (size_t)j*32 + ll*8);
        float f[8]; unpack8(t, f);
#pragma unroll
        for (int k=0;k<8;k++) acc[k] += dj*f[k];
    }
#pragma unroll
    for (int m = 4; m < 16; m <<= 1){
#pragma unroll
        for (int k=0;k<8;k++) acc[k] += __shfl_xor(acc[k], m, 64);
    }
    if (slot == 0){
        float o[8];
#pragma unroll
        for (int k=0;k<8;k++) o[k] = fmaxf(di*acc[k] + b2[ll*8+k], 0.f);
        float4* dst0 = (float4*)(out + (size_t)i*ostride + ll*8);
        dst0[0] = make_float4(o[0],o[1],o[2],o[3]);
        dst0[1] = make_float4(o[4],o[5],o[6],o[7]);
    }
}

// ---------------- mm3 via bf16 MFMA: [N,32]@[32,128] -> bf16 h3 + att logits ----------------
// grid 782: block = 64 nodes x 128 cols; wave = 16 nodes x 8 col-tiles; K=32 = one MFMA step
__global__ void k_mm3_mfma(const float* __restrict__ xjin, const float* __restrict__ W3,
                           const float* __restrict__ as, const float* __restrict__ adt,
                           u16* __restrict__ hb, float* __restrict__ asrc,
                           float* __restrict__ adst){
    __shared__ u16 outS[64][136];
    __shared__ float asS[128], adS[128];
    int tid = threadIdx.x;
    int lane = tid & 63, w = tid >> 6;
    int nbase = blockIdx.x * 64;
    if (tid < 128){ asS[tid] = as[tid]; adS[tid] = adt[tid]; }
    int q = lane >> 4, r16 = lane & 15;
    int m = nbase + w*16 + r16;
    f32x4 acc[8] = {};
    // A-frag: A[m][k=q*8+j] from x2 = xj+16
    s16x8 af = (s16x8){0,0,0,0,0,0,0,0};
    if (m < NN){
        const float* ap = xjin + 16 + (size_t)m*432 + q*8;
        float4 a0 = *(const float4*)ap;
        float4 a1 = *(const float4*)(ap+4);
        af[0]=(short)f2bf(a0.x); af[1]=(short)f2bf(a0.y);
        af[2]=(short)f2bf(a0.z); af[3]=(short)f2bf(a0.w);
        af[4]=(short)f2bf(a1.x); af[5]=(short)f2bf(a1.y);
        af[6]=(short)f2bf(a1.z); af[7]=(short)f2bf(a1.w);
    }
#pragma unroll
    for (int t = 0; t < 8; t++){
        const float* bp = W3 + (size_t)(q*8)*128 + t*16 + r16;
        s16x8 bf;
        bf[0]=(short)f2bf(bp[0]);   bf[1]=(short)f2bf(bp[128]);
        bf[2]=(short)f2bf(bp[256]); bf[3]=(short)f2bf(bp[384]);
        bf[4]=(short)f2bf(bp[512]); bf[5]=(short)f2bf(bp[640]);
        bf[6]=(short)f2bf(bp[768]); bf[7]=(short)f2bf(bp[896]);
        acc[t] = __builtin_amdgcn_mfma_f32_16x16x32_bf16(af, bf, acc[t], 0, 0, 0);
    }
#pragma unroll
    for (int t = 0; t < 8; t++){
#pragma unroll
        for (int r = 0; r < 4; r++){
            outS[w*16 + q*4 + r][t*16 + r16] = f2bf(acc[t][r]);
        }
    }
    __syncthreads();
    // logits: 16 nodes x 4 heads per wave (head = q, 32 chans each)
    {
        int row = w*16 + r16;
        int node = nbase + row;
        float ps = 0.f, pd = 0.f;
        const u16* orow = &outS[row][q*32];
#pragma unroll
        for (int c = 0; c < 32; c++){
            float f = __uint_as_float(((u32)orow[c]) << 16);
            ps += f * asS[q*32 + c];
            pd += f * adS[q*32 + c];
        }
        if (node < NN){
            asrc[(size_t)node*4 + q] = ps;
            adst[(size_t)node*4 + q] = pd;
        }
    }
    // coalesced h3 store: 64 rows x 16 segs of 8 u16
    for (int idx = tid; idx < 1024; idx += 256){
        int row = idx >> 4, seg = idx & 15;
        int node = nbase + row;
        if (node < NN){
            uint4 v = *(const uint4*)&outS[row][seg*8];
            *(uint4*)(hb + (size_t)node*128 + seg*8) = v;
        }
    }
}

// ---------------- mm4 via bf16 MFMA: [N,128]@[128,256] -> bf16 h4 + att logits ----------------
__global__ void k_mm4_mfma(const float* __restrict__ xjin, const float* __restrict__ W4,
                           const float* __restrict__ as, const float* __restrict__ adt,
                           u16* __restrict__ hb, float* __restrict__ asrc,
                           float* __restrict__ adst){
    __shared__ u16 outS[64][136];
    __shared__ float asS[128], adS[128];
    int tid = threadIdx.x;
    int lane = tid & 63, w = tid >> 6;
    int cbase = blockIdx.x * 128;
    int nbase = blockIdx.y * 64;
    if (tid < 128){ asS[tid] = as[cbase + tid]; adS[tid] = adt[cbase + tid]; }
    int q = lane >> 4, r16 = lane & 15;
    int m = nbase + w*16 + r16;
    f32x4 acc[8] = {};
    const float* arow = xjin + 48 + (size_t)m*432;
    for (int s = 0; s < 4; s++){
        s16x8 af = (s16x8){0,0,0,0,0,0,0,0};
        if (m < NN){
            const float* ap = arow + s*32 + q*8;
            float4 a0 = *(const float4*)ap;
            float4 a1 = *(const float4*)(ap+4);
            af[0]=(short)f2bf(a0.x); af[1]=(short)f2bf(a0.y);
            af[2]=(short)f2bf(a0.z); af[3]=(short)f2bf(a0.w);
            af[4]=(short)f2bf(a1.x); af[5]=(short)f2bf(a1.y);
            af[6]=(short)f2bf(a1.z); af[7]=(short)f2bf(a1.w);
        }
        int k0 = s*32 + q*8;
#pragma unroll
        for (int t = 0; t < 8; t++){
            const float* bp = W4 + (size_t)k0*256 + cbase + t*16 + r16;
            s16x8 bf;
            bf[0]=(short)f2bf(bp[0]);    bf[1]=(short)f2bf(bp[256]);
            bf[2]=(short)f2bf(bp[512]);  bf[3]=(short)f2bf(bp[768]);
            bf[4]=(short)f2bf(bp[1024]); bf[5]=(short)f2bf(bp[1280]);
            bf[6]=(short)f2bf(bp[1536]); bf[7]=(short)f2bf(bp[1792]);
            acc[t] = __builtin_amdgcn_mfma_f32_16x16x32_bf16(af, bf, acc[t], 0, 0, 0);
        }
    }
#pragma unroll
    for (int t = 0; t < 8; t++){
#pragma unroll
        for (int r = 0; r < 4; r++){
            outS[w*16 + q*4 + r][t*16 + r16] = f2bf(acc[t][r]);
        }
    }
    __syncthreads();
    {
        int row = w*16 + r16;
        int node = nbase + row;
        float ps = 0.f, pd = 0.f;
        const u16* orow = &outS[row][q*32];
#pragma unroll
        for (int c = 0; c < 32; c++){
            float f = __uint_as_float(((u32)orow[c]) << 16);
            ps += f * asS[q*32 + c];
            pd += f * adS[q*32 + c];
        }
        if (node < NN){
            int hg = (cbase >> 5) + q;
            asrc[(size_t)node*8 + hg] = ps;
            adst[(size_t)node*8 + hg] = pd;
        }
    }
    for (int idx = tid; idx < 1024; idx += 256){
        int row = idx >> 4, seg = idx & 15;
        int node = nbase + row;
        if (node < NN){
            uint4 v = *(const uint4*)&outS[row][seg*8];
            *(uint4*)(hb + (size_t)node*256 + cbase + seg*8) = v;
        }
    }
}

// ---------------- GAT agg layer 3 (bf16 h, H=4): wave/node, CL=16 x S=4, unroll x4 ----------------
__global__ void k_gat_agg3(const u16* __restrict__ h, const float* __restrict__ asrc,
                           const float* __restrict__ adst, const int* __restrict__ rowptr,
                           const int* __restrict__ csr_src, const float* __restrict__ b,
                           float* __restrict__ out, int ostride, int n){
    constexpr int HC = 128, CL = 16, S = 4;
    int lane = threadIdx.x & 63;
    int wid  = threadIdx.x >> 6;
    int i = blockIdx.x*4 + wid;
    if (i >= n) return;
    int ll   = lane % CL;
    int slot = lane / CL;
    int head = (ll*8)/32;
    float ad = adst[(size_t)i*4 + head];
    float acc[8] = {0.f,0.f,0.f,0.f,0.f,0.f,0.f,0.f};
    float s = 0.f;
    if (slot == 0){
        float wself = __expf(lrelu(asrc[(size_t)i*4 + head] + ad));
        uint4 t = ((const uint4*)(h + (size_t)i*HC))[ll];
        float f[8]; unpack8(t, f);
#pragma unroll
        for (int k=0;k<8;k++) acc[k] = wself*f[k];
        s = wself;
    }
    int e0 = rowptr[i], e1 = rowptr[i+1];
    int e = e0 + slot;
    for (; e + 3*S < e1; e += 4*S){
        int j0 = csr_src[e], j1 = csr_src[e+S], j2 = csr_src[e+2*S], j3 = csr_src[e+3*S];
        float w0 = __expf(lrelu(asrc[(size_t)j0*4 + head] + ad));
        float w1 = __expf(lrelu(asrc[(size_t)j1*4 + head] + ad));
        float w2 = __expf(lrelu(asrc[(size_t)j2*4 + head] + ad));
        float w3 = __expf(lrelu(asrc[(size_t)j3*4 + head] + ad));
        uint4 t0 = ((const uint4*)(h + (size_t)j0*HC))[ll];
        uint4 t1 = ((const uint4*)(h + (size_t)j1*HC))[ll];
        uint4 t2 = ((const uint4*)(h + (size_t)j2*HC))[ll];
        uint4 t3 = ((const uint4*)(h + (size_t)j3*HC))[ll];
        float f0[8], f1[8], f2[8], f3[8];
        unpack8(t0, f0); unpack8(t1, f1); unpack8(t2, f2); unpack8(t3, f3);
#pragma unroll
        for (int k=0;k<8;k++) acc[k] += w0*f0[k] + w1*f1[k] + w2*f2[k] + w3*f3[k];
        s += w0 + w1 + w2 + w3;
    }
    for (; e < e1; e += S){
        int j = csr_src[e];
        float w = __expf(lrelu(asrc[(size_t)j*4 + head] + ad));
        uint4 t = ((const uint4*)(h + (size_t)j*HC))[ll];
        float f[8]; unpack8(t, f);
#pragma unroll
        for (int k=0;k<8;k++) acc[k] += w*f[k];
        s += w;
    }
#pragma unroll
    for (int m = CL; m < 64; m <<= 1){
        s += __shfl_xor(s, m, 64);
#pragma unroll
        for (int k=0;k<8;k++) acc[k] += __shfl_xor(acc[k], m, 64);
    }
    if (slot == 0){
        float inv = 1.f / s;
        float o[8];
#pragma unroll
        for (int k=0;k<8;k++) o[k] = fmaxf(acc[k]*inv + b[ll*8+k], 0.f);
        float4* dst0 = (float4*)(out + (size_t)i*ostride + ll*8);
        dst0[0] = make_float4(o[0],o[1],o[2],o[3]);
        dst0[1] = make_float4(o[4],o[5],o[6],o[7]);
    }
}

// ---------------- GAT agg layer 4 (bf16 h, H=8): wave/node, CL=32 x S=2, unroll x4 ----------------
__global__ void k_gat_agg4(const u16* __restrict__ h, const float* __restrict__ asrc,
                           const float* __restrict__ adst, const int* __restrict__ rowptr,
                           const int* __restrict__ csr_src, const float* __restrict__ b,
                           float* __restrict__ out, int ostride, int n){
    constexpr int HC = 256, CL = 32, S = 2;
    int lane = threadIdx.x & 63;
    int wid  = threadIdx.x >> 6;
    int i = blockIdx.x*4 + wid;
    if (i >= n) return;
    int ll   = lane % CL;
    int slot = lane / CL;
    int head = ll >> 2;
    float ad = adst[(size_t)i*8 + head];
    float acc[8] = {0.f,0.f,0.f,0.f,0.f,0.f,0.f,0.f};
    float s = 0.f;
    if (slot == 0){
        float wself = __expf(lrelu(asrc[(size_t)i*8 + head] + ad));
        uint4 t = ((const uint4*)(h + (size_t)i*HC))[ll];
        float f[8]; unpack8(t, f);
#pragma unroll
        for (int k=0;k<8;k++) acc[k] = wself*f[k];
        s = wself;
    }
    int e0 = rowptr[i], e1 = rowptr[i+1];
    int e = e0 + slot;
    for (; e + 3*S < e1; e += 4*S){
        int j0 = csr_src[e], j1 = csr_src[e+S], j2 = csr_src[e+2*S], j3 = csr_src[e+3*S];
        float w0 = __expf(lrelu(asrc[(size_t)j0*8 + head] + ad));
        float w1 = __expf(lrelu(asrc[(size_t)j1*8 + head] + ad));
        float w2 = __expf(lrelu(asrc[(size_t)j2*8 + head] + ad));
        float w3 = __expf(lrelu(asrc[(size_t)j3*8 + head] + ad));
        uint4 t0 = ((const uint4*)(h + (size_t)j0*HC))[ll];
        uint4 t1 = ((const uint4*)(h + (size_t)j1*HC))[ll];
        uint4 t2 = ((const uint4*)(h + (size_t)j2*HC))[ll];
        uint4 t3 = ((const uint4*)(h + (size_t)j3*HC))[ll];
        float f0[8], f1[8], f2[8], f3[8];
        unpack8(t0, f0); unpack8(t1, f1); unpack8(t2, f2); unpack8(t3, f3);
#pragma unroll
        for (int k=0;k<8;k++) acc[k] += w0*f0[k] + w1*f1[k] + w2*f2[k] + w3*f3[k];
        s += w0 + w1 + w2 + w3;
    }
    for (; e < e1; e += S){
        int j = csr_src[e];
        float w = __expf(lrelu(asrc[(size_t)j*8 + head] + ad));
        uint4 t = ((const uint4*)(h + (size_t)j*HC))[ll];
        float f[8]; unpack8(t, f);
#pragma unroll
        for (int k=0;k<8;k++) acc[k] += w*f[k];
        s += w;
    }
    s += __shfl_xor(s, 32, 64);
#pragma unroll
    for (int k=0;k<8;k++) acc[k] += __shfl_xor(acc[k], 32, 64);
    if (slot == 0){
        float inv = 1.f / s;
        float o[8];
#pragma unroll
        for (int k=0;k<8;k++) o[k] = fmaxf(acc[k]*inv + b[ll*8+k], 0.f);
        float4* dst0 = (float4*)(out + (size_t)i*ostride + ll*8);
        dst0[0] = make_float4(o[0],o[1],o[2],o[3]);
        dst0[1] = make_float4(o[4],o[5],o[6],o[7]);
    }
}

// ---------------- pooling + fused FC ----------------
__global__ void k_pool_sum(const float* __restrict__ xj, const int* __restrict__ batch,
                           float* __restrict__ pool){
    int nb = blockIdx.x * 32;
    int ne = min(nb + 32, NN);
    if (nb >= NN) return;
    int cq = threadIdx.x;
    if (cq >= 108) return;
    float4 a = make_float4(0.f,0.f,0.f,0.f);
    int curg = batch[nb];
    for (int nn = nb; nn < ne; nn++){
        int g = batch[nn];
        if (g != curg){
            float* p = &pool[curg*432 + cq*4];
            atomicAdd(p+0, a.x); atomicAdd(p+1, a.y);
            atomicAdd(p+2, a.z); atomicAdd(p+3, a.w);
            a = make_float4(0.f,0.f,0.f,0.f); curg = g;
        }
        float4 v = *(const float4*)(xj + (size_t)nn*432 + cq*4);
        a.x += v.x; a.y += v.y; a.z += v.z; a.w += v.w;
    }
    float* p = &pool[curg*432 + cq*4];
    atomicAdd(p+0, a.x); atomicAdd(p+1, a.y);
    atomicAdd(p+2, a.z); atomicAdd(p+3, a.w);
}

// fused fc1 + fc2
__global__ void k_fc(const float* __restrict__ pool, const int* __restrict__ batch,
                     const float* __restrict__ Wf1, const float* __restrict__ bf1,
                     const float* __restrict__ Wf2, const float* __restrict__ bf2,
                     float* __restrict__ out){
    int g = blockIdx.x, j = threadIdx.x;
    int lo = 0, hi = NN;
    while (lo < hi){ int mid = (lo+hi) >> 1; if (batch[mid] < g) lo = mid+1; else hi = mid; }
    int s0 = lo;
    lo = 0; hi = NN;
    while (lo < hi){ int mid = (lo+hi) >> 1; if (batch[mid] < g+1) lo = mid+1; else hi = mid; }
    int cnt = lo - s0;
    float invc = 1.f / (float)max(cnt, 1);
    float acc = 0.f;
    for (int k = 0; k < 432; k++) acc += pool[g*432 + k] * Wf1[k*128 + j];
    float hv = fmaxf(acc * invc + bf1[j], 0.f);
    float p = hv * Wf2[j];
    for (int off = 32; off > 0; off >>= 1) p += __shfl_down(p, off, 64);
    __shared__ float part[2];
    if ((j & 63) == 0) part[j >> 6] = p;
    __syncthreads();
    if (j == 0) out[g] = part[0] + part[1] + bf2[0];
}

extern "C" void kernel_launch(void* const* d_in, const int* in_sizes, int n_in,
                              void* d_out, int out_size, void* d_ws, size_t ws_size,
                              hipStream_t stream){
    const float* x     = (const float*)d_in[0];
    const int*   ei    = (const int*)  d_in[1];
    const int*   batch = (const int*)  d_in[2];
    const float* W1 = (const float*)d_in[3];  const float* b1 = (const float*)d_in[4];
    const float* W2 = (const float*)d_in[5];  const float* b2 = (const float*)d_in[6];
    const float* W3 = (const float*)d_in[7];
    const float* as3 = (const float*)d_in[8]; const float* ad3 = (const float*)d_in[9];
    const float* b3 = (const float*)d_in[10];
    const float* W4 = (const float*)d_in[11];
    const float* as4 = (const float*)d_in[12]; const float* ad4 = (const float*)d_in[13];
    const float* b4 = (const float*)d_in[14];
    const float* Wf1 = (const float*)d_in[15]; const float* bf1 = (const float*)d_in[16];
    const float* Wf2 = (const float*)d_in[17]; const float* bf2 = (const float*)d_in[18];
    float* out = (float*)d_out;

    const int* srcE = ei;
    const int* dstE = ei + NE;

    char* base = (char*)d_ws; size_t off = 0;
    auto alloc = [&](size_t bytes)->void*{
        void* p = base + off;
        off += (bytes + 255) & ~(size_t)255;
        return p;
    };
    int*   degi    = (int*)  alloc((size_t)NN*4);
    int*   cursor  = (int*)  alloc((size_t)NN*4);
    float* dinv    = (float*)alloc((size_t)NN*4);
    int*   rowptr  = (int*)  alloc((size_t)(NN+1)*4);
    int*   bsum    = (int*)  alloc(64*4);
    int*   csr_src = (int*)  alloc((size_t)NE*4);
    u16*   h1b     = (u16*)  alloc((size_t)NN*16*2);
    u16*   h2b     = (u16*)  alloc((size_t)NN*32*2);
    u16*   hb3     = (u16*)  alloc((size_t)NN*128*2);
    u16*   hb4     = (u16*)  alloc((size_t)NN*256*2);
    float* xj      = (float*)alloc((size_t)NN*432*4);
    float* a_src   = (float*)alloc((size_t)NN*8*4);
    float* a_dst   = (float*)alloc((size_t)NN*8*4);
    float* pool    = (float*)alloc((size_t)NG*432*4);

    hipMemsetAsync(degi, 0, (size_t)NN*4, stream);

    const int SB = (NN + 1023)/1024;

    k_cm     <<<EB + MB1 + PB, 256, 0, stream>>>(dstE, degi, x, W1, h1b, pool);
    k_scan_a <<<SB, 256, 0, stream>>>(degi, rowptr, dinv, cursor, bsum, NN);
    k_scan_c <<<SB, 256, 0, stream>>>(rowptr, bsum, SB, NN);
    k_scatter<<<EB, 256, 0, stream>>>(srcE, dstE, rowptr, cursor, csr_src, NE);

    // GCN layer 1 agg + relu + mm2 fused
    k_gcn_agg16_mm2<<<(NN+15)/16, 256, 0, stream>>>(h1b, dinv, rowptr, csr_src, b1, W2, xj, h2b, NN);

    // GCN layer 2 agg
    k_gcn_agg32<<<(NN+15)/16, 256, 0, stream>>>(h2b, dinv, rowptr, csr_src, b2, xj + 16, 432, NN);

    // GAT layer 3: MFMA mm3 + fused logits
    k_mm3_mfma<<<(NN+63)/64, 256, 0, stream>>>(xj, W3, as3, ad3, hb3, a_src, a_dst);
    k_gat_agg3<<<(NN+3)/4, 256, 0, stream>>>(hb3, a_src, a_dst, rowptr, csr_src, b3, xj + 48, 432, NN);

    // GAT layer 4: MFMA mm4 + fused logits
    {
        dim3 grid(2, (NN + 63)/64);
        k_mm4_mfma<<<grid, 256, 0, stream>>>(xj, W4, as4, ad4, hb4, a_src, a_dst);
    }
    k_gat_agg4<<<(NN+3)/4, 256, 0, stream>>>(hb4, a_src, a_dst, rowptr, csr_src, b4, xj + 176, 432, NN);

    // pooling + fused FC
    k_pool_sum<<<(NN+31)/32, 128, 0, stream>>>(xj, batch, pool);
    k_fc<<<NG, 128, 0, stream>>>(pool, batch, Wf1, bf1, Wf2, bf2, out);
}

// Round 14
// 406.992 us; speedup vs baseline: 1.2679x; 1.0187x over previous
//
#include <hip/hip_runtime.h>
#include <hip/hip_bf16.h>

#define NN 50000
#define NE 800000
#define NG 128
#define EB ((NE + 255)/256)
#define MB1 ((NN + 15)/16)
#define PB 54    // pool-zero blocks: 128*432/1024
#define WB4 128  // W4 pack blocks: 32768/256
#define WB3 16   // W3 pack blocks: 4096/256

typedef unsigned short u16;
typedef unsigned int u32;
typedef float f32x4 __attribute__((ext_vector_type(4)));
typedef short s16x8 __attribute__((ext_vector_type(8)));

__device__ __forceinline__ float lrelu(float x){ return x > 0.f ? x : 0.2f*x; }
__device__ __forceinline__ u16 f2bf(float f){
    __hip_bfloat16 h = __float2bfloat16(f);
    return *(u16*)&h;
}
// unpack 8 bf16 (as uint4) -> 8 floats
__device__ __forceinline__ void unpack8(uint4 t, float* f){
    f[0]=__uint_as_float(t.x<<16); f[1]=__uint_as_float(t.x&0xffff0000u);
    f[2]=__uint_as_float(t.y<<16); f[3]=__uint_as_float(t.y&0xffff0000u);
    f[4]=__uint_as_float(t.z<<16); f[5]=__uint_as_float(t.z&0xffff0000u);
    f[6]=__uint_as_float(t.w<<16); f[7]=__uint_as_float(t.w&0xffff0000u);
}

// ---- fused: edge count + mm1 (x@W1 -> bf16 h1) + pool zero + W4/W3 bf16 pack ----
__global__ void k_cm(const int* __restrict__ dstE, int* __restrict__ degi,
                     const float* __restrict__ x, const float* __restrict__ W1,
                     const float* __restrict__ W3, const float* __restrict__ W4,
                     u16* __restrict__ h1, float* __restrict__ pool,
                     u16* __restrict__ W3p, u16* __restrict__ W4p){
    if (blockIdx.x < EB){
        int e = blockIdx.x*256 + threadIdx.x;
        if (e < NE) atomicAdd(&degi[dstE[e]], 1);
        return;
    }
    if (blockIdx.x >= EB + MB1){
        int b2 = blockIdx.x - EB - MB1;
        if (b2 < PB){
            int idx = b2*1024 + threadIdx.x*4;
            if (idx < NG*432) *(float4*)(pool + idx) = make_float4(0.f,0.f,0.f,0.f);
        } else if (b2 < PB + WB4){
            int e = (b2 - PB)*256 + threadIdx.x;     // e = k*256 + n
            int k = e >> 8, n = e & 255;
            W4p[(k>>3)*2048 + n*8 + (k&7)] = f2bf(W4[e]);
        } else {
            int e = (b2 - PB - WB4)*256 + threadIdx.x; // e = k*128 + n
            if (e < 4096){
                int k = e >> 7, n = e & 127;
                W3p[(k>>3)*1024 + n*8 + (k&7)] = f2bf(W3[e]);
            }
        }
        return;
    }
    __shared__ float wl[128*16];
    for (int i = threadIdx.x; i < 128*16; i += 256) wl[i] = W1[i];
    __syncthreads();
    int m  = threadIdx.x & 15;
    int nl = threadIdx.x >> 4;
    int node = (blockIdx.x - EB) * 16 + nl;
    if (node >= NN) return;
    const float* row = x + (size_t)node * 128;
    float acc = 0.f;
#pragma unroll 8
    for (int k = 0; k < 128; k++) acc += row[k] * wl[k*16 + m];
    h1[(size_t)node*16 + m] = f2bf(acc);
}

// scan stage A + dinv + cursor zero
__global__ void k_scan_a(const int* __restrict__ deg, int* __restrict__ rowptr,
                         float* __restrict__ dinv, int* __restrict__ cursor,
                         int* __restrict__ bsum, int n){
    __shared__ int lds[256];
    int base = blockIdx.x*1024 + threadIdx.x*4;
    int v[4]; int s = 0;
#pragma unroll
    for (int k=0;k<4;k++){ v[k] = (base+k < n) ? deg[base+k] : 0; s += v[k]; }
    lds[threadIdx.x] = s;
    __syncthreads();
    for (int off=1; off<256; off<<=1){
        int t = (threadIdx.x>=off) ? lds[threadIdx.x-off] : 0;
        __syncthreads(); lds[threadIdx.x] += t; __syncthreads();
    }
    int run = lds[threadIdx.x] - s;
#pragma unroll
    for (int k=0;k<4;k++){
        if (base+k < n){
            rowptr[base+k] = run;
            dinv[base+k] = rsqrtf((float)(v[k] + 1));
            cursor[base+k] = 0;
        }
        run += v[k];
    }
    if (threadIdx.x == 255) bsum[blockIdx.x] = lds[255];
}

__global__ void k_scan_c(int* __restrict__ rowptr, const int* __restrict__ bsum,
                         int nb, int n){
    __shared__ int off_s;
    if (threadIdx.x < 64){
        int v = ((int)threadIdx.x < nb && (int)threadIdx.x < (int)blockIdx.x)
                ? bsum[threadIdx.x] : 0;
        for (int m=1; m<64; m<<=1) v += __shfl_xor(v, m, 64);
        if (threadIdx.x == 0) off_s = v;
    }
    __syncthreads();
    int o = off_s;
    int idx = blockIdx.x*1024 + threadIdx.x*4;
#pragma unroll
    for (int k=0;k<4;k++) if (idx+k < n) rowptr[idx+k] += o;
    if ((int)blockIdx.x == nb-1 && threadIdx.x == 0) rowptr[n] = o + bsum[nb-1];
}

__global__ void k_scatter(const int* __restrict__ src, const int* __restrict__ dst,
                          const int* __restrict__ rowptr, int* __restrict__ cursor,
                          int* __restrict__ csr_src, int E){
    int e = blockIdx.x*blockDim.x + threadIdx.x;
    if (e < E){
        int d = dst[e];
        int pos = rowptr[d] + atomicAdd(&cursor[d], 1);
        csr_src[pos] = src[e];
    }
}

// ---- fused GCN1 agg (bf16 h1) + relu + mm2 -> bf16 h2 ----
__global__ void k_gcn_agg16_mm2(const u16* __restrict__ h1, const float* __restrict__ dinv,
                                const int* __restrict__ rowptr, const int* __restrict__ csr_src,
                                const float* __restrict__ b1, const float* __restrict__ W2,
                                float* __restrict__ xj, u16* __restrict__ h2, int n){
    __shared__ float w2s[16*32];
    __shared__ float x1s[16][17];
    for (int i = threadIdx.x; i < 512; i += 256) w2s[i] = W2[i];
    int lin = threadIdx.x & 15;
    int nl  = threadIdx.x >> 4;
    int i = blockIdx.x*16 + nl;
    int ll = lin & 1, slot = lin >> 1;
    float di = dinv[i];
    float acc[8] = {0.f,0.f,0.f,0.f,0.f,0.f,0.f,0.f};
    if (slot == 0){
        uint4 t = *(const uint4*)(h1 + (size_t)i*16 + ll*8);
        float f[8]; unpack8(t, f);
#pragma unroll
        for (int k=0;k<8;k++) acc[k] = di*f[k];
    }
    int e0 = rowptr[i], e1 = rowptr[i+1];
    int e = e0 + slot;
    for (; e + 8 < e1; e += 16){
        int j0 = csr_src[e], j1 = csr_src[e+8];
        float d0 = dinv[j0], d1 = dinv[j1];
        uint4 t0 = *(const uint4*)(h1 + (size_t)j0*16 + ll*8);
        uint4 t1 = *(const uint4*)(h1 + (size_t)j1*16 + ll*8);
        float f0[8], f1[8]; unpack8(t0, f0); unpack8(t1, f1);
#pragma unroll
        for (int k=0;k<8;k++) acc[k] += d0*f0[k] + d1*f1[k];
    }
    if (e < e1){
        int j = csr_src[e];
        float dj = dinv[j];
        uint4 t = *(const uint4*)(h1 + (size_t)j*16 + ll*8);
        float f[8]; unpack8(t, f);
#pragma unroll
        for (int k=0;k<8;k++) acc[k] += dj*f[k];
    }
#pragma unroll
    for (int m = 2; m < 16; m <<= 1){
#pragma unroll
        for (int k=0;k<8;k++) acc[k] += __shfl_xor(acc[k], m, 64);
    }
    if (slot == 0){
        float o[8];
#pragma unroll
        for (int k=0;k<8;k++){
            o[k] = fmaxf(di*acc[k] + b1[ll*8+k], 0.f);
            x1s[nl][ll*8+k] = o[k];
        }
        float4* dst0 = (float4*)(xj + (size_t)i*432 + ll*8);
        dst0[0] = make_float4(o[0],o[1],o[2],o[3]);
        dst0[1] = make_float4(o[4],o[5],o[6],o[7]);
    }
    __syncthreads();
    float a0 = 0.f, a1 = 0.f;
    int m0 = lin*2;
#pragma unroll
    for (int k=0;k<16;k++){
        float xv = x1s[nl][k];
        a0 += xv * w2s[k*32 + m0];
        a1 += xv * w2s[k*32 + m0 + 1];
    }
    u32 pk = (u32)f2bf(a0) | ((u32)f2bf(a1) << 16);
    *(u32*)(h2 + (size_t)i*32 + m0) = pk;
}

// ---- GCN2 agg (bf16 h2) -> x2 fp32 (xj+16) + x2 bf16 copy ----
__global__ void k_gcn_agg32(const u16* __restrict__ h2, const float* __restrict__ dinv,
                            const int* __restrict__ rowptr, const int* __restrict__ csr_src,
                            const float* __restrict__ b2, float* __restrict__ out,
                            u16* __restrict__ x2b, int ostride, int n){
    int lin = threadIdx.x & 15;
    int i = blockIdx.x*16 + (threadIdx.x >> 4);
    if (i >= n) return;
    int ll = lin & 3, slot = lin >> 2;
    float di = dinv[i];
    float acc[8] = {0.f,0.f,0.f,0.f,0.f,0.f,0.f,0.f};
    if (slot == 0){
        uint4 t = *(const uint4*)(h2 + (size_t)i*32 + ll*8);
        float f[8]; unpack8(t, f);
#pragma unroll
        for (int k=0;k<8;k++) acc[k] = di*f[k];
    }
    int e0 = rowptr[i], e1 = rowptr[i+1];
    int e = e0 + slot;
    for (; e + 12 < e1; e += 16){
        int j0 = csr_src[e], j1 = csr_src[e+4], j2 = csr_src[e+8], j3 = csr_src[e+12];
        float d0 = dinv[j0], d1 = dinv[j1], d2 = dinv[j2], d3 = dinv[j3];
        uint4 t0 = *(const uint4*)(h2 + (size_t)j0*32 + ll*8);
        uint4 t1 = *(const uint4*)(h2 + (size_t)j1*32 + ll*8);
        uint4 t2 = *(const uint4*)(h2 + (size_t)j2*32 + ll*8);
        uint4 t3 = *(const uint4*)(h2 + (size_t)j3*32 + ll*8);
        float f0[8], f1[8], f2[8], f3[8];
        unpack8(t0, f0); unpack8(t1, f1); unpack8(t2, f2); unpack8(t3, f3);
#pragma unroll
        for (int k=0;k<8;k++) acc[k] += d0*f0[k] + d1*f1[k] + d2*f2[k] + d3*f3[k];
    }
    for (; e < e1; e += 4){
        int j = csr_src[e];
        float dj = dinv[j];
        uint4 t = *(const uint4*)(h2 + (size_t)j*32 + ll*8);
        float f[8]; unpack8(t, f);
#pragma unroll
        for (int k=0;k<8;k++) acc[k] += dj*f[k];
    }
#pragma unroll
    for (int m = 4; m < 16; m <<= 1){
#pragma unroll
        for (int k=0;k<8;k++) acc[k] += __shfl_xor(acc[k], m, 64);
    }
    if (slot == 0){
        float o[8];
#pragma unroll
        for (int k=0;k<8;k++) o[k] = fmaxf(di*acc[k] + b2[ll*8+k], 0.f);
        float4* dst0 = (float4*)(out + (size_t)i*ostride + ll*8);
        dst0[0] = make_float4(o[0],o[1],o[2],o[3]);
        dst0[1] = make_float4(o[4],o[5],o[6],o[7]);
        uint4 pk;
        pk.x = (u32)f2bf(o[0]) | ((u32)f2bf(o[1])<<16);
        pk.y = (u32)f2bf(o[2]) | ((u32)f2bf(o[3])<<16);
        pk.z = (u32)f2bf(o[4]) | ((u32)f2bf(o[5])<<16);
        pk.w = (u32)f2bf(o[6]) | ((u32)f2bf(o[7])<<16);
        *(uint4*)(x2b + (size_t)i*32 + ll*8) = pk;
    }
}

// ---- mm3 via bf16 MFMA (bf16 A from x2b, packed bf16 B) ----
__global__ void k_mm3_mfma(const u16* __restrict__ x2b, const u16* __restrict__ W3p,
                           const float* __restrict__ as, const float* __restrict__ adt,
                           u16* __restrict__ hb, float* __restrict__ asrc,
                           float* __restrict__ adst){
    __shared__ u16 outS[64][136];
    __shared__ float asS[128], adS[128];
    int tid = threadIdx.x;
    int lane = tid & 63, w = tid >> 6;
    int nbase = blockIdx.x * 64;
    if (tid < 128){ asS[tid] = as[tid]; adS[tid] = adt[tid]; }
    int q = lane >> 4, r16 = lane & 15;
    int m = nbase + w*16 + r16;
    f32x4 acc[8] = {};
    s16x8 af = (s16x8){0,0,0,0,0,0,0,0};
    if (m < NN) af = *(const s16x8*)(x2b + (size_t)m*32 + q*8);
#pragma unroll
    for (int t = 0; t < 8; t++){
        s16x8 bf = *(const s16x8*)(W3p + q*1024 + (t*16 + r16)*8);
        acc[t] = __builtin_amdgcn_mfma_f32_16x16x32_bf16(af, bf, acc[t], 0, 0, 0);
    }
#pragma unroll
    for (int t = 0; t < 8; t++){
#pragma unroll
        for (int r = 0; r < 4; r++){
            outS[w*16 + q*4 + r][t*16 + r16] = f2bf(acc[t][r]);
        }
    }
    __syncthreads();
    {
        int row = w*16 + r16;
        int node = nbase + row;
        float ps = 0.f, pd = 0.f;
        const u16* orow = &outS[row][q*32];
#pragma unroll
        for (int c = 0; c < 32; c++){
            float f = __uint_as_float(((u32)orow[c]) << 16);
            ps += f * asS[q*32 + c];
            pd += f * adS[q*32 + c];
        }
        if (node < NN){
            asrc[(size_t)node*4 + q] = ps;
            adst[(size_t)node*4 + q] = pd;
        }
    }
    for (int idx = tid; idx < 1024; idx += 256){
        int row = idx >> 4, seg = idx & 15;
        int node = nbase + row;
        if (node < NN){
            uint4 v = *(const uint4*)&outS[row][seg*8];
            *(uint4*)(hb + (size_t)node*128 + seg*8) = v;
        }
    }
}

// ---- mm4 via bf16 MFMA (bf16 A from x3b, packed bf16 B) ----
__global__ void k_mm4_mfma(const u16* __restrict__ x3b, const u16* __restrict__ W4p,
                           const float* __restrict__ as, const float* __restrict__ adt,
                           u16* __restrict__ hb, float* __restrict__ asrc,
                           float* __restrict__ adst){
    __shared__ u16 outS[64][136];
    __shared__ float asS[128], adS[128];
    int tid = threadIdx.x;
    int lane = tid & 63, w = tid >> 6;
    int cbase = blockIdx.x * 128;
    int nbase = blockIdx.y * 64;
    if (tid < 128){ asS[tid] = as[cbase + tid]; adS[tid] = adt[cbase + tid]; }
    int q = lane >> 4, r16 = lane & 15;
    int m = nbase + w*16 + r16;
    f32x4 acc[8] = {};
    for (int s = 0; s < 4; s++){
        s16x8 af = (s16x8){0,0,0,0,0,0,0,0};
        if (m < NN) af = *(const s16x8*)(x3b + (size_t)m*128 + s*32 + q*8);
        int kb = s*4 + q;   // (k0>>3)
#pragma unroll
        for (int t = 0; t < 8; t++){
            s16x8 bf = *(const s16x8*)(W4p + (size_t)kb*2048 + (cbase + t*16 + r16)*8);
            acc[t] = __builtin_amdgcn_mfma_f32_16x16x32_bf16(af, bf, acc[t], 0, 0, 0);
        }
    }
#pragma unroll
    for (int t = 0; t < 8; t++){
#pragma unroll
        for (int r = 0; r < 4; r++){
            outS[w*16 + q*4 + r][t*16 + r16] = f2bf(acc[t][r]);
        }
    }
    __syncthreads();
    {
        int row = w*16 + r16;
        int node = nbase + row;
        float ps = 0.f, pd = 0.f;
        const u16* orow = &outS[row][q*32];
#pragma unroll
        for (int c = 0; c < 32; c++){
            float f = __uint_as_float(((u32)orow[c]) << 16);
            ps += f * asS[q*32 + c];
            pd += f * adS[q*32 + c];
        }
        if (node < NN){
            int hg = (cbase >> 5) + q;
            asrc[(size_t)node*8 + hg] = ps;
            adst[(size_t)node*8 + hg] = pd;
        }
    }
    for (int idx = tid; idx < 1024; idx += 256){
        int row = idx >> 4, seg = idx & 15;
        int node = nbase + row;
        if (node < NN){
            uint4 v = *(const uint4*)&outS[row][seg*8];
            *(uint4*)(hb + (size_t)node*256 + cbase + seg*8) = v;
        }
    }
}

// ---- GAT agg layer 3 -> x3 fp32 (xj+48, for pool) + x3 bf16 copy (for mm4) ----
__global__ void k_gat_agg3(const u16* __restrict__ h, const float* __restrict__ asrc,
                           const float* __restrict__ adst, const int* __restrict__ rowptr,
                           const int* __restrict__ csr_src, const float* __restrict__ b,
                           float* __restrict__ out, u16* __restrict__ x3b,
                           int ostride, int n){
    constexpr int HC = 128, CL = 16, S = 4;
    int lane = threadIdx.x & 63;
    int wid  = threadIdx.x >> 6;
    int i = blockIdx.x*4 + wid;
    if (i >= n) return;
    int ll   = lane % CL;
    int slot = lane / CL;
    int head = (ll*8)/32;
    float ad = adst[(size_t)i*4 + head];
    float acc[8] = {0.f,0.f,0.f,0.f,0.f,0.f,0.f,0.f};
    float s = 0.f;
    if (slot == 0){
        float wself = __expf(lrelu(asrc[(size_t)i*4 + head] + ad));
        uint4 t = ((const uint4*)(h + (size_t)i*HC))[ll];
        float f[8]; unpack8(t, f);
#pragma unroll
        for (int k=0;k<8;k++) acc[k] = wself*f[k];
        s = wself;
    }
    int e0 = rowptr[i], e1 = rowptr[i+1];
    int e = e0 + slot;
    for (; e + 3*S < e1; e += 4*S){
        int j0 = csr_src[e], j1 = csr_src[e+S], j2 = csr_src[e+2*S], j3 = csr_src[e+3*S];
        float w0 = __expf(lrelu(asrc[(size_t)j0*4 + head] + ad));
        float w1 = __expf(lrelu(asrc[(size_t)j1*4 + head] + ad));
        float w2 = __expf(lrelu(asrc[(size_t)j2*4 + head] + ad));
        float w3 = __expf(lrelu(asrc[(size_t)j3*4 + head] + ad));
        uint4 t0 = ((const uint4*)(h + (size_t)j0*HC))[ll];
        uint4 t1 = ((const uint4*)(h + (size_t)j1*HC))[ll];
        uint4 t2 = ((const uint4*)(h + (size_t)j2*HC))[ll];
        uint4 t3 = ((const uint4*)(h + (size_t)j3*HC))[ll];
        float f0[8], f1[8], f2[8], f3[8];
        unpack8(t0, f0); unpack8(t1, f1); unpack8(t2, f2); unpack8(t3, f3);
#pragma unroll
        for (int k=0;k<8;k++) acc[k] += w0*f0[k] + w1*f1[k] + w2*f2[k] + w3*f3[k];
        s += w0 + w1 + w2 + w3;
    }
    for (; e < e1; e += S){
        int j = csr_src[e];
        float w = __expf(lrelu(asrc[(size_t)j*4 + head] + ad));
        uint4 t = ((const uint4*)(h + (size_t)j*HC))[ll];
        float f[8]; unpack8(t, f);
#pragma unroll
        for (int k=0;k<8;k++) acc[k] += w*f[k];
        s += w;
    }
#pragma unroll
    for (int m = CL; m < 64; m <<= 1){
        s += __shfl_xor(s, m, 64);
#pragma unroll
        for (int k=0;k<8;k++) acc[k] += __shfl_xor(acc[k], m, 64);
    }
    if (slot == 0){
        float inv = 1.f / s;
        float o[8];
#pragma unroll
        for (int k=0;k<8;k++) o[k] = fmaxf(acc[k]*inv + b[ll*8+k], 0.f);
        float4* dst0 = (float4*)(out + (size_t)i*ostride + ll*8);
        dst0[0] = make_float4(o[0],o[1],o[2],o[3]);
        dst0[1] = make_float4(o[4],o[5],o[6],o[7]);
        uint4 pk;
        pk.x = (u32)f2bf(o[0]) | ((u32)f2bf(o[1])<<16);
        pk.y = (u32)f2bf(o[2]) | ((u32)f2bf(o[3])<<16);
        pk.z = (u32)f2bf(o[4]) | ((u32)f2bf(o[5])<<16);
        pk.w = (u32)f2bf(o[6]) | ((u32)f2bf(o[7])<<16);
        *(uint4*)(x3b + (size_t)i*128 + ll*8) = pk;
    }
}

// ---- GAT agg layer 4: fused pooling of x4 (no x4 store; atomic adds into pool) ----
// block = 4 nodes (NN%4==0); grid exactly NN/4 -> no early returns (barrier safety)
__global__ void k_gat_agg4(const u16* __restrict__ h, const float* __restrict__ asrc,
                           const float* __restrict__ adst, const int* __restrict__ rowptr,
                           const int* __restrict__ csr_src, const float* __restrict__ b,
                           const int* __restrict__ batch, float* __restrict__ pool){
    constexpr int HC = 256, CL = 32, S = 2;
    __shared__ float x4buf[4][256];
    __shared__ int gbuf[4];
    int lane = threadIdx.x & 63;
    int wid  = threadIdx.x >> 6;
    int i = blockIdx.x*4 + wid;
    int ll   = lane % CL;
    int slot = lane / CL;
    int head = ll >> 2;
    float ad = adst[(size_t)i*8 + head];
    float acc[8] = {0.f,0.f,0.f,0.f,0.f,0.f,0.f,0.f};
    float s = 0.f;
    if (slot == 0){
        float wself = __expf(lrelu(asrc[(size_t)i*8 + head] + ad));
        uint4 t = ((const uint4*)(h + (size_t)i*HC))[ll];
        float f[8]; unpack8(t, f);
#pragma unroll
        for (int k=0;k<8;k++) acc[k] = wself*f[k];
        s = wself;
    }
    int e0 = rowptr[i], e1 = rowptr[i+1];
    int e = e0 + slot;
    for (; e + 3*S < e1; e += 4*S){
        int j0 = csr_src[e], j1 = csr_src[e+S], j2 = csr_src[e+2*S], j3 = csr_src[e+3*S];
        float w0 = __expf(lrelu(asrc[(size_t)j0*8 + head] + ad));
        float w1 = __expf(lrelu(asrc[(size_t)j1*8 + head] + ad));
        float w2 = __expf(lrelu(asrc[(size_t)j2*8 + head] + ad));
        float w3 = __expf(lrelu(asrc[(size_t)j3*8 + head] + ad));
        uint4 t0 = ((const uint4*)(h + (size_t)j0*HC))[ll];
        uint4 t1 = ((const uint4*)(h + (size_t)j1*HC))[ll];
        uint4 t2 = ((const uint4*)(h + (size_t)j2*HC))[ll];
        uint4 t3 = ((const uint4*)(h + (size_t)j3*HC))[ll];
        float f0[8], f1[8], f2[8], f3[8];
        unpack8(t0, f0); unpack8(t1, f1); unpack8(t2, f2); unpack8(t3, f3);
#pragma unroll
        for (int k=0;k<8;k++) acc[k] += w0*f0[k] + w1*f1[k] + w2*f2[k] + w3*f3[k];
        s += w0 + w1 + w2 + w3;
    }
    for (; e < e1; e += S){
        int j = csr_src[e];
        float w = __expf(lrelu(asrc[(size_t)j*8 + head] + ad));
        uint4 t = ((const uint4*)(h + (size_t)j*HC))[ll];
        float f[8]; unpack8(t, f);
#pragma unroll
        for (int k=0;k<8;k++) acc[k] += w*f[k];
        s += w;
    }
    s += __shfl_xor(s, 32, 64);
#pragma unroll
    for (int k=0;k<8;k++) acc[k] += __shfl_xor(acc[k], 32, 64);
    if (slot == 0){
        float inv = 1.f / s;
#pragma unroll
        for (int k=0;k<8;k++)
            x4buf[wid][ll*8+k] = fmaxf(acc[k]*inv + b[ll*8+k], 0.f);
        if (ll == 0) gbuf[wid] = batch[i];
    }
    __syncthreads();
    {
        int c = threadIdx.x;      // 0..255
        int g0 = gbuf[0];
        float sum = 0.f;
#pragma unroll
        for (int wd = 0; wd < 4; wd++){
            float v = x4buf[wd][c];
            int gw = gbuf[wd];
            if (gw == g0) sum += v;
            else atomicAdd(&pool[gw*432 + 176 + c], v);
        }
        atomicAdd(&pool[g0*432 + 176 + c], sum);
    }
}

// ---- pooling over chans 0..175 only (x4 pooled inside agg4) ----
__global__ void k_pool_sum(const float* __restrict__ xj, const int* __restrict__ batch,
                           float* __restrict__ pool){
    int nb = blockIdx.x * 32;
    int ne = min(nb + 32, NN);
    if (nb >= NN) return;
    int cq = threadIdx.x;
    if (cq >= 44) return;       // 44 quads = 176 chans
    float4 a = make_float4(0.f,0.f,0.f,0.f);
    int curg = batch[nb];
    for (int nn = nb; nn < ne; nn++){
        int g = batch[nn];
        if (g != curg){
            float* p = &pool[curg*432 + cq*4];
            atomicAdd(p+0, a.x); atomicAdd(p+1, a.y);
            atomicAdd(p+2, a.z); atomicAdd(p+3, a.w);
            a = make_float4(0.f,0.f,0.f,0.f); curg = g;
        }
        float4 v = *(const float4*)(xj + (size_t)nn*432 + cq*4);
        a.x += v.x; a.y += v.y; a.z += v.z; a.w += v.w;
    }
    float* p = &pool[curg*432 + cq*4];
    atomicAdd(p+0, a.x); atomicAdd(p+1, a.y);
    atomicAdd(p+2, a.z); atomicAdd(p+3, a.w);
}

// fused fc1 + fc2
__global__ void k_fc(const float* __restrict__ pool, const int* __restrict__ batch,
                     const float* __restrict__ Wf1, const float* __restrict__ bf1,
                     const float* __restrict__ Wf2, const float* __restrict__ bf2,
                     float* __restrict__ out){
    int g = blockIdx.x, j = threadIdx.x;
    int lo = 0, hi = NN;
    while (lo < hi){ int mid = (lo+hi) >> 1; if (batch[mid] < g) lo = mid+1; else hi = mid; }
    int s0 = lo;
    lo = 0; hi = NN;
    while (lo < hi){ int mid = (lo+hi) >> 1; if (batch[mid] < g+1) lo = mid+1; else hi = mid; }
    int cnt = lo - s0;
    float invc = 1.f / (float)max(cnt, 1);
    float acc = 0.f;
    for (int k = 0; k < 432; k++) acc += pool[g*432 + k] * Wf1[k*128 + j];
    float hv = fmaxf(acc * invc + bf1[j], 0.f);
    float p = hv * Wf2[j];
    for (int off = 32; off > 0; off >>= 1) p += __shfl_down(p, off, 64);
    __shared__ float part[2];
    if ((j & 63) == 0) part[j >> 6] = p;
    __syncthreads();
    if (j == 0) out[g] = part[0] + part[1] + bf2[0];
}

extern "C" void kernel_launch(void* const* d_in, const int* in_sizes, int n_in,
                              void* d_out, int out_size, void* d_ws, size_t ws_size,
                              hipStream_t stream){
    const float* x     = (const float*)d_in[0];
    const int*   ei    = (const int*)  d_in[1];
    const int*   batch = (const int*)  d_in[2];
    const float* W1 = (const float*)d_in[3];  const float* b1 = (const float*)d_in[4];
    const float* W2 = (const float*)d_in[5];  const float* b2 = (const float*)d_in[6];
    const float* W3 = (const float*)d_in[7];
    const float* as3 = (const float*)d_in[8]; const float* ad3 = (const float*)d_in[9];
    const float* b3 = (const float*)d_in[10];
    const float* W4 = (const float*)d_in[11];
    const float* as4 = (const float*)d_in[12]; const float* ad4 = (const float*)d_in[13];
    const float* b4 = (const float*)d_in[14];
    const float* Wf1 = (const float*)d_in[15]; const float* bf1 = (const float*)d_in[16];
    const float* Wf2 = (const float*)d_in[17]; const float* bf2 = (const float*)d_in[18];
    float* out = (float*)d_out;

    const int* srcE = ei;
    const int* dstE = ei + NE;

    char* base = (char*)d_ws; size_t off = 0;
    auto alloc = [&](size_t bytes)->void*{
        void* p = base + off;
        off += (bytes + 255) & ~(size_t)255;
        return p;
    };
    int*   degi    = (int*)  alloc((size_t)NN*4);
    int*   cursor  = (int*)  alloc((size_t)NN*4);
    float* dinv    = (float*)alloc((size_t)NN*4);
    int*   rowptr  = (int*)  alloc((size_t)(NN+1)*4);
    int*   bsum    = (int*)  alloc(64*4);
    int*   csr_src = (int*)  alloc((size_t)NE*4);
    u16*   h1b     = (u16*)  alloc((size_t)NN*16*2);
    u16*   h2b     = (u16*)  alloc((size_t)NN*32*2);
    u16*   hb3     = (u16*)  alloc((size_t)NN*128*2);
    u16*   hb4     = (u16*)  alloc((size_t)NN*256*2);
    u16*   x2b     = (u16*)  alloc((size_t)NN*32*2);
    u16*   x3b     = (u16*)  alloc((size_t)NN*128*2);
    u16*   W3p     = (u16*)  alloc((size_t)4096*2);
    u16*   W4p     = (u16*)  alloc((size_t)32768*2);
    float* xj      = (float*)alloc((size_t)NN*432*4);
    float* a_src   = (float*)alloc((size_t)NN*8*4);
    float* a_dst   = (float*)alloc((size_t)NN*8*4);
    float* pool    = (float*)alloc((size_t)NG*432*4);

    hipMemsetAsync(degi, 0, (size_t)NN*4, stream);

    const int SB = (NN + 1023)/1024;

    k_cm     <<<EB + MB1 + PB + WB4 + WB3, 256, 0, stream>>>(dstE, degi, x, W1, W3, W4,
                                                             h1b, pool, W3p, W4p);
    k_scan_a <<<SB, 256, 0, stream>>>(degi, rowptr, dinv, cursor, bsum, NN);
    k_scan_c <<<SB, 256, 0, stream>>>(rowptr, bsum, SB, NN);
    k_scatter<<<EB, 256, 0, stream>>>(srcE, dstE, rowptr, cursor, csr_src, NE);

    // GCN layer 1 agg + relu + mm2 fused
    k_gcn_agg16_mm2<<<(NN+15)/16, 256, 0, stream>>>(h1b, dinv, rowptr, csr_src, b1, W2, xj, h2b, NN);

    // GCN layer 2 agg -> x2 fp32 + bf16
    k_gcn_agg32<<<(NN+15)/16, 256, 0, stream>>>(h2b, dinv, rowptr, csr_src, b2, xj + 16, x2b, 432, NN);

    // GAT layer 3: MFMA mm3 + fused logits
    k_mm3_mfma<<<(NN+63)/64, 256, 0, stream>>>(x2b, W3p, as3, ad3, hb3, a_src, a_dst);
    k_gat_agg3<<<(NN+3)/4, 256, 0, stream>>>(hb3, a_src, a_dst, rowptr, csr_src, b3, xj + 48, x3b, 432, NN);

    // GAT layer 4: MFMA mm4 + fused logits; agg4 pools x4 directly
    {
        dim3 grid(2, (NN + 63)/64);
        k_mm4_mfma<<<grid, 256, 0, stream>>>(x3b, W4p, as4, ad4, hb4, a_src, a_dst);
    }
    k_gat_agg4<<<NN/4, 256, 0, stream>>>(hb4, a_src, a_dst, rowptr, csr_src, b4, batch, pool);

    // pooling (chans 0..175) + fused FC
    k_pool_sum<<<(NN+31)/32, 128, 0, stream>>>(xj, batch, pool);
    k_fc<<<NG, 128, 0, stream>>>(pool, batch, Wf1, bf1, Wf2, bf2, out);
}

// Round 15
// 395.027 us; speedup vs baseline: 1.3063x; 1.0303x over previous
//
#include <hip/hip_runtime.h>
#include <hip/hip_bf16.h>

#define NN 50000
#define NE 800000
#define NG 128
#define EB ((NE + 255)/256)
#define MB1 ((NN + 15)/16)
#define PB 54    // pool-zero blocks: 128*432/1024
#define WB4 128  // W4 pack blocks: 32768/256
#define WB3 16   // W3 pack blocks: 4096/256

typedef unsigned short u16;
typedef unsigned int u32;
typedef float f32x4 __attribute__((ext_vector_type(4)));
typedef short s16x8 __attribute__((ext_vector_type(8)));

__device__ __forceinline__ float lrelu(float x){ return x > 0.f ? x : 0.2f*x; }
__device__ __forceinline__ u16 f2bf(float f){
    __hip_bfloat16 h = __float2bfloat16(f);
    return *(u16*)&h;
}
// unpack 8 bf16 (as uint4) -> 8 floats
__device__ __forceinline__ void unpack8(uint4 t, float* f){
    f[0]=__uint_as_float(t.x<<16); f[1]=__uint_as_float(t.x&0xffff0000u);
    f[2]=__uint_as_float(t.y<<16); f[3]=__uint_as_float(t.y&0xffff0000u);
    f[4]=__uint_as_float(t.z<<16); f[5]=__uint_as_float(t.z&0xffff0000u);
    f[6]=__uint_as_float(t.w<<16); f[7]=__uint_as_float(t.w&0xffff0000u);
}

// ---- fused: edge count + mm1 (x@W1 -> bf16 h1) + pool zero + W4/W3 bf16 pack ----
__global__ void k_cm(const int* __restrict__ dstE, int* __restrict__ degi,
                     const float* __restrict__ x, const float* __restrict__ W1,
                     const float* __restrict__ W3, const float* __restrict__ W4,
                     u16* __restrict__ h1, float* __restrict__ pool,
                     u16* __restrict__ W3p, u16* __restrict__ W4p){
    if (blockIdx.x < EB){
        int e = blockIdx.x*256 + threadIdx.x;
        if (e < NE) atomicAdd(&degi[dstE[e]], 1);
        return;
    }
    if (blockIdx.x >= EB + MB1){
        int b2 = blockIdx.x - EB - MB1;
        if (b2 < PB){
            int idx = b2*1024 + threadIdx.x*4;
            if (idx < NG*432) *(float4*)(pool + idx) = make_float4(0.f,0.f,0.f,0.f);
        } else if (b2 < PB + WB4){
            int e = (b2 - PB)*256 + threadIdx.x;     // e = k*256 + n
            int k = e >> 8, n = e & 255;
            W4p[(k>>3)*2048 + n*8 + (k&7)] = f2bf(W4[e]);
        } else {
            int e = (b2 - PB - WB4)*256 + threadIdx.x; // e = k*128 + n
            if (e < 4096){
                int k = e >> 7, n = e & 127;
                W3p[(k>>3)*1024 + n*8 + (k&7)] = f2bf(W3[e]);
            }
        }
        return;
    }
    __shared__ float wl[128*16];
    for (int i = threadIdx.x; i < 128*16; i += 256) wl[i] = W1[i];
    __syncthreads();
    int m  = threadIdx.x & 15;
    int nl = threadIdx.x >> 4;
    int node = (blockIdx.x - EB) * 16 + nl;
    if (node >= NN) return;
    const float* row = x + (size_t)node * 128;
    float acc = 0.f;
#pragma unroll 8
    for (int k = 0; k < 128; k++) acc += row[k] * wl[k*16 + m];
    h1[(size_t)node*16 + m] = f2bf(acc);
}

// scan stage A + dinv + cursor zero
__global__ void k_scan_a(const int* __restrict__ deg, int* __restrict__ rowptr,
                         float* __restrict__ dinv, int* __restrict__ cursor,
                         int* __restrict__ bsum, int n){
    __shared__ int lds[256];
    int base = blockIdx.x*1024 + threadIdx.x*4;
    int v[4]; int s = 0;
#pragma unroll
    for (int k=0;k<4;k++){ v[k] = (base+k < n) ? deg[base+k] : 0; s += v[k]; }
    lds[threadIdx.x] = s;
    __syncthreads();
    for (int off=1; off<256; off<<=1){
        int t = (threadIdx.x>=off) ? lds[threadIdx.x-off] : 0;
        __syncthreads(); lds[threadIdx.x] += t; __syncthreads();
    }
    int run = lds[threadIdx.x] - s;
#pragma unroll
    for (int k=0;k<4;k++){
        if (base+k < n){
            rowptr[base+k] = run;
            dinv[base+k] = rsqrtf((float)(v[k] + 1));
            cursor[base+k] = 0;
        }
        run += v[k];
    }
    if (threadIdx.x == 255) bsum[blockIdx.x] = lds[255];
}

__global__ void k_scan_c(int* __restrict__ rowptr, const int* __restrict__ bsum,
                         int nb, int n){
    __shared__ int off_s;
    if (threadIdx.x < 64){
        int v = ((int)threadIdx.x < nb && (int)threadIdx.x < (int)blockIdx.x)
                ? bsum[threadIdx.x] : 0;
        for (int m=1; m<64; m<<=1) v += __shfl_xor(v, m, 64);
        if (threadIdx.x == 0) off_s = v;
    }
    __syncthreads();
    int o = off_s;
    int idx = blockIdx.x*1024 + threadIdx.x*4;
#pragma unroll
    for (int k=0;k<4;k++) if (idx+k < n) rowptr[idx+k] += o;
    if ((int)blockIdx.x == nb-1 && threadIdx.x == 0) rowptr[n] = o + bsum[nb-1];
}

__global__ void k_scatter(const int* __restrict__ src, const int* __restrict__ dst,
                          const int* __restrict__ rowptr, int* __restrict__ cursor,
                          int* __restrict__ csr_src, int E){
    int e = blockIdx.x*blockDim.x + threadIdx.x;
    if (e < E){
        int d = dst[e];
        int pos = rowptr[d] + atomicAdd(&cursor[d], 1);
        csr_src[pos] = src[e];
    }
}

// ---- fused GCN1 agg (bf16 h1) + relu + mm2 -> bf16 h2; pools x1 (chans 0..15) ----
// grid NN/16 exact; no early returns (barrier safety)
__global__ void k_gcn_agg16_mm2(const u16* __restrict__ h1, const float* __restrict__ dinv,
                                const int* __restrict__ rowptr, const int* __restrict__ csr_src,
                                const float* __restrict__ b1, const float* __restrict__ W2,
                                const int* __restrict__ batch, float* __restrict__ pool,
                                u16* __restrict__ h2, int n){
    __shared__ float w2s[16*32];
    __shared__ float x1s[16][17];
    __shared__ int gbuf[16];
    for (int i = threadIdx.x; i < 512; i += 256) w2s[i] = W2[i];
    int lin = threadIdx.x & 15;
    int nl  = threadIdx.x >> 4;
    int i = blockIdx.x*16 + nl;
    int ll = lin & 1, slot = lin >> 1;
    float di = dinv[i];
    float acc[8] = {0.f,0.f,0.f,0.f,0.f,0.f,0.f,0.f};
    if (slot == 0){
        uint4 t = *(const uint4*)(h1 + (size_t)i*16 + ll*8);
        float f[8]; unpack8(t, f);
#pragma unroll
        for (int k=0;k<8;k++) acc[k] = di*f[k];
    }
    int e0 = rowptr[i], e1 = rowptr[i+1];
    int e = e0 + slot;
    for (; e + 8 < e1; e += 16){
        int j0 = csr_src[e], j1 = csr_src[e+8];
        float d0 = dinv[j0], d1 = dinv[j1];
        uint4 t0 = *(const uint4*)(h1 + (size_t)j0*16 + ll*8);
        uint4 t1 = *(const uint4*)(h1 + (size_t)j1*16 + ll*8);
        float f0[8], f1[8]; unpack8(t0, f0); unpack8(t1, f1);
#pragma unroll
        for (int k=0;k<8;k++) acc[k] += d0*f0[k] + d1*f1[k];
    }
    if (e < e1){
        int j = csr_src[e];
        float dj = dinv[j];
        uint4 t = *(const uint4*)(h1 + (size_t)j*16 + ll*8);
        float f[8]; unpack8(t, f);
#pragma unroll
        for (int k=0;k<8;k++) acc[k] += dj*f[k];
    }
#pragma unroll
    for (int m = 2; m < 16; m <<= 1){
#pragma unroll
        for (int k=0;k<8;k++) acc[k] += __shfl_xor(acc[k], m, 64);
    }
    if (slot == 0){
#pragma unroll
        for (int k=0;k<8;k++)
            x1s[nl][ll*8+k] = fmaxf(di*acc[k] + b1[ll*8+k], 0.f);
        if (lin == 0) gbuf[nl] = batch[i];
    }
    __syncthreads();
    // mm2: each lane computes 2 chans of h2
    {
        float a0 = 0.f, a1 = 0.f;
        int m0 = lin*2;
#pragma unroll
        for (int k=0;k<16;k++){
            float xv = x1s[nl][k];
            a0 += xv * w2s[k*32 + m0];
            a1 += xv * w2s[k*32 + m0 + 1];
        }
        u32 pk = (u32)f2bf(a0) | ((u32)f2bf(a1) << 16);
        *(u32*)(h2 + (size_t)i*32 + m0) = pk;
    }
    // pool x1: threads 0..15 each own chan c, walk 16 sorted nodes
    if (threadIdx.x < 16){
        int c = threadIdx.x;
        int curg = gbuf[0];
        float a = 0.f;
        for (int nd = 0; nd < 16; nd++){
            int g = gbuf[nd];
            if (g != curg){ atomicAdd(&pool[curg*432 + c], a); a = 0.f; curg = g; }
            a += x1s[nd][c];
        }
        atomicAdd(&pool[curg*432 + c], a);
    }
}

// ---- GCN2 agg (bf16 h2) -> x2 bf16 copy; pools x2 (chans 16..47) ----
// grid NN/16 exact; no early returns
__global__ void k_gcn_agg32(const u16* __restrict__ h2, const float* __restrict__ dinv,
                            const int* __restrict__ rowptr, const int* __restrict__ csr_src,
                            const float* __restrict__ b2, const int* __restrict__ batch,
                            float* __restrict__ pool, u16* __restrict__ x2b, int n){
    __shared__ float x2s[16][33];
    __shared__ int gbuf[16];
    int lin = threadIdx.x & 15;
    int nl  = threadIdx.x >> 4;
    int i = blockIdx.x*16 + nl;
    int ll = lin & 3, slot = lin >> 2;
    float di = dinv[i];
    float acc[8] = {0.f,0.f,0.f,0.f,0.f,0.f,0.f,0.f};
    if (slot == 0){
        uint4 t = *(const uint4*)(h2 + (size_t)i*32 + ll*8);
        float f[8]; unpack8(t, f);
#pragma unroll
        for (int k=0;k<8;k++) acc[k] = di*f[k];
    }
    int e0 = rowptr[i], e1 = rowptr[i+1];
    int e = e0 + slot;
    for (; e + 12 < e1; e += 16){
        int j0 = csr_src[e], j1 = csr_src[e+4], j2 = csr_src[e+8], j3 = csr_src[e+12];
        float d0 = dinv[j0], d1 = dinv[j1], d2 = dinv[j2], d3 = dinv[j3];
        uint4 t0 = *(const uint4*)(h2 + (size_t)j0*32 + ll*8);
        uint4 t1 = *(const uint4*)(h2 + (size_t)j1*32 + ll*8);
        uint4 t2 = *(const uint4*)(h2 + (size_t)j2*32 + ll*8);
        uint4 t3 = *(const uint4*)(h2 + (size_t)j3*32 + ll*8);
        float f0[8], f1[8], f2[8], f3[8];
        unpack8(t0, f0); unpack8(t1, f1); unpack8(t2, f2); unpack8(t3, f3);
#pragma unroll
        for (int k=0;k<8;k++) acc[k] += d0*f0[k] + d1*f1[k] + d2*f2[k] + d3*f3[k];
    }
    for (; e < e1; e += 4){
        int j = csr_src[e];
        float dj = dinv[j];
        uint4 t = *(const uint4*)(h2 + (size_t)j*32 + ll*8);
        float f[8]; unpack8(t, f);
#pragma unroll
        for (int k=0;k<8;k++) acc[k] += dj*f[k];
    }
#pragma unroll
    for (int m = 4; m < 16; m <<= 1){
#pragma unroll
        for (int k=0;k<8;k++) acc[k] += __shfl_xor(acc[k], m, 64);
    }
    if (slot == 0){
        float o[8];
#pragma unroll
        for (int k=0;k<8;k++){
            o[k] = fmaxf(di*acc[k] + b2[ll*8+k], 0.f);
            x2s[nl][ll*8+k] = o[k];
        }
        uint4 pk;
        pk.x = (u32)f2bf(o[0]) | ((u32)f2bf(o[1])<<16);
        pk.y = (u32)f2bf(o[2]) | ((u32)f2bf(o[3])<<16);
        pk.z = (u32)f2bf(o[4]) | ((u32)f2bf(o[5])<<16);
        pk.w = (u32)f2bf(o[6]) | ((u32)f2bf(o[7])<<16);
        *(uint4*)(x2b + (size_t)i*32 + ll*8) = pk;
        if (lin == 0) gbuf[nl] = batch[i];
    }
    __syncthreads();
    if (threadIdx.x < 32){
        int c = threadIdx.x;
        int curg = gbuf[0];
        float a = 0.f;
        for (int nd = 0; nd < 16; nd++){
            int g = gbuf[nd];
            if (g != curg){ atomicAdd(&pool[curg*432 + 16 + c], a); a = 0.f; curg = g; }
            a += x2s[nd][c];
        }
        atomicAdd(&pool[curg*432 + 16 + c], a);
    }
}

// ---- mm3 via bf16 MFMA (bf16 A from x2b, packed bf16 B) ----
__global__ void k_mm3_mfma(const u16* __restrict__ x2b, const u16* __restrict__ W3p,
                           const float* __restrict__ as, const float* __restrict__ adt,
                           u16* __restrict__ hb, float* __restrict__ asrc,
                           float* __restrict__ adst){
    __shared__ u16 outS[64][136];
    __shared__ float asS[128], adS[128];
    int tid = threadIdx.x;
    int lane = tid & 63, w = tid >> 6;
    int nbase = blockIdx.x * 64;
    if (tid < 128){ asS[tid] = as[tid]; adS[tid] = adt[tid]; }
    int q = lane >> 4, r16 = lane & 15;
    int m = nbase + w*16 + r16;
    f32x4 acc[8] = {};
    s16x8 af = (s16x8){0,0,0,0,0,0,0,0};
    if (m < NN) af = *(const s16x8*)(x2b + (size_t)m*32 + q*8);
#pragma unroll
    for (int t = 0; t < 8; t++){
        s16x8 bf = *(const s16x8*)(W3p + q*1024 + (t*16 + r16)*8);
        acc[t] = __builtin_amdgcn_mfma_f32_16x16x32_bf16(af, bf, acc[t], 0, 0, 0);
    }
#pragma unroll
    for (int t = 0; t < 8; t++){
#pragma unroll
        for (int r = 0; r < 4; r++){
            outS[w*16 + q*4 + r][t*16 + r16] = f2bf(acc[t][r]);
        }
    }
    __syncthreads();
    {
        int row = w*16 + r16;
        int node = nbase + row;
        float ps = 0.f, pd = 0.f;
        const u16* orow = &outS[row][q*32];
#pragma unroll
        for (int c = 0; c < 32; c++){
            float f = __uint_as_float(((u32)orow[c]) << 16);
            ps += f * asS[q*32 + c];
            pd += f * adS[q*32 + c];
        }
        if (node < NN){
            asrc[(size_t)node*4 + q] = ps;
            adst[(size_t)node*4 + q] = pd;
        }
    }
    for (int idx = tid; idx < 1024; idx += 256){
        int row = idx >> 4, seg = idx & 15;
        int node = nbase + row;
        if (node < NN){
            uint4 v = *(const uint4*)&outS[row][seg*8];
            *(uint4*)(hb + (size_t)node*128 + seg*8) = v;
        }
    }
}

// ---- mm4 via bf16 MFMA (bf16 A from x3b, packed bf16 B) ----
__global__ void k_mm4_mfma(const u16* __restrict__ x3b, const u16* __restrict__ W4p,
                           const float* __restrict__ as, const float* __restrict__ adt,
                           u16* __restrict__ hb, float* __restrict__ asrc,
                           float* __restrict__ adst){
    __shared__ u16 outS[64][136];
    __shared__ float asS[128], adS[128];
    int tid = threadIdx.x;
    int lane = tid & 63, w = tid >> 6;
    int cbase = blockIdx.x * 128;
    int nbase = blockIdx.y * 64;
    if (tid < 128){ asS[tid] = as[cbase + tid]; adS[tid] = adt[cbase + tid]; }
    int q = lane >> 4, r16 = lane & 15;
    int m = nbase + w*16 + r16;
    f32x4 acc[8] = {};
    for (int s = 0; s < 4; s++){
        s16x8 af = (s16x8){0,0,0,0,0,0,0,0};
        if (m < NN) af = *(const s16x8*)(x3b + (size_t)m*128 + s*32 + q*8);
        int kb = s*4 + q;
#pragma unroll
        for (int t = 0; t < 8; t++){
            s16x8 bf = *(const s16x8*)(W4p + (size_t)kb*2048 + (cbase + t*16 + r16)*8);
            acc[t] = __builtin_amdgcn_mfma_f32_16x16x32_bf16(af, bf, acc[t], 0, 0, 0);
        }
    }
#pragma unroll
    for (int t = 0; t < 8; t++){
#pragma unroll
        for (int r = 0; r < 4; r++){
            outS[w*16 + q*4 + r][t*16 + r16] = f2bf(acc[t][r]);
        }
    }
    __syncthreads();
    {
        int row = w*16 + r16;
        int node = nbase + row;
        float ps = 0.f, pd = 0.f;
        const u16* orow = &outS[row][q*32];
#pragma unroll
        for (int c = 0; c < 32; c++){
            float f = __uint_as_float(((u32)orow[c]) << 16);
            ps += f * asS[q*32 + c];
            pd += f * adS[q*32 + c];
        }
        if (node < NN){
            int hg = (cbase >> 5) + q;
            asrc[(size_t)node*8 + hg] = ps;
            adst[(size_t)node*8 + hg] = pd;
        }
    }
    for (int idx = tid; idx < 1024; idx += 256){
        int row = idx >> 4, seg = idx & 15;
        int node = nbase + row;
        if (node < NN){
            uint4 v = *(const uint4*)&outS[row][seg*8];
            *(uint4*)(hb + (size_t)node*256 + cbase + seg*8) = v;
        }
    }
}

// ---- GAT agg layer 3 -> x3 bf16 (for mm4); pools x3 (chans 48..175) ----
// grid NN/4 exact; no early returns
__global__ void k_gat_agg3(const u16* __restrict__ h, const float* __restrict__ asrc,
                           const float* __restrict__ adst, const int* __restrict__ rowptr,
                           const int* __restrict__ csr_src, const float* __restrict__ b,
                           const int* __restrict__ batch, float* __restrict__ pool,
                           u16* __restrict__ x3b, int n){
    constexpr int HC = 128, CL = 16, S = 4;
    __shared__ float x3s[4][128];
    __shared__ int gbuf[4];
    int lane = threadIdx.x & 63;
    int wid  = threadIdx.x >> 6;
    int i = blockIdx.x*4 + wid;
    int ll   = lane % CL;
    int slot = lane / CL;
    int head = (ll*8)/32;
    float ad = adst[(size_t)i*4 + head];
    float acc[8] = {0.f,0.f,0.f,0.f,0.f,0.f,0.f,0.f};
    float s = 0.f;
    if (slot == 0){
        float wself = __expf(lrelu(asrc[(size_t)i*4 + head] + ad));
        uint4 t = ((const uint4*)(h + (size_t)i*HC))[ll];
        float f[8]; unpack8(t, f);
#pragma unroll
        for (int k=0;k<8;k++) acc[k] = wself*f[k];
        s = wself;
    }
    int e0 = rowptr[i], e1 = rowptr[i+1];
    int e = e0 + slot;
    for (; e + 3*S < e1; e += 4*S){
        int j0 = csr_src[e], j1 = csr_src[e+S], j2 = csr_src[e+2*S], j3 = csr_src[e+3*S];
        float w0 = __expf(lrelu(asrc[(size_t)j0*4 + head] + ad));
        float w1 = __expf(lrelu(asrc[(size_t)j1*4 + head] + ad));
        float w2 = __expf(lrelu(asrc[(size_t)j2*4 + head] + ad));
        float w3 = __expf(lrelu(asrc[(size_t)j3*4 + head] + ad));
        uint4 t0 = ((const uint4*)(h + (size_t)j0*HC))[ll];
        uint4 t1 = ((const uint4*)(h + (size_t)j1*HC))[ll];
        uint4 t2 = ((const uint4*)(h + (size_t)j2*HC))[ll];
        uint4 t3 = ((const uint4*)(h + (size_t)j3*HC))[ll];
        float f0[8], f1[8], f2[8], f3[8];
        unpack8(t0, f0); unpack8(t1, f1); unpack8(t2, f2); unpack8(t3, f3);
#pragma unroll
        for (int k=0;k<8;k++) acc[k] += w0*f0[k] + w1*f1[k] + w2*f2[k] + w3*f3[k];
        s += w0 + w1 + w2 + w3;
    }
    for (; e < e1; e += S){
        int j = csr_src[e];
        float w = __expf(lrelu(asrc[(size_t)j*4 + head] + ad));
        uint4 t = ((const uint4*)(h + (size_t)j*HC))[ll];
        float f[8]; unpack8(t, f);
#pragma unroll
        for (int k=0;k<8;k++) acc[k] += w*f[k];
        s += w;
    }
#pragma unroll
    for (int m = CL; m < 64; m <<= 1){
        s += __shfl_xor(s, m, 64);
#pragma unroll
        for (int k=0;k<8;k++) acc[k] += __shfl_xor(acc[k], m, 64);
    }
    if (slot == 0){
        float inv = 1.f / s;
        float o[8];
#pragma unroll
        for (int k=0;k<8;k++){
            o[k] = fmaxf(acc[k]*inv + b[ll*8+k], 0.f);
            x3s[wid][ll*8+k] = o[k];
        }
        uint4 pk;
        pk.x = (u32)f2bf(o[0]) | ((u32)f2bf(o[1])<<16);
        pk.y = (u32)f2bf(o[2]) | ((u32)f2bf(o[3])<<16);
        pk.z = (u32)f2bf(o[4]) | ((u32)f2bf(o[5])<<16);
        pk.w = (u32)f2bf(o[6]) | ((u32)f2bf(o[7])<<16);
        *(uint4*)(x3b + (size_t)i*128 + ll*8) = pk;
        if (ll == 0) gbuf[wid] = batch[i];
    }
    __syncthreads();
    if (threadIdx.x < 128){
        int c = threadIdx.x;
        int g0 = gbuf[0];
        float sum = 0.f;
#pragma unroll
        for (int wd = 0; wd < 4; wd++){
            float v = x3s[wd][c];
            int gw = gbuf[wd];
            if (gw == g0) sum += v;
            else atomicAdd(&pool[gw*432 + 48 + c], v);
        }
        atomicAdd(&pool[g0*432 + 48 + c], sum);
    }
}

// ---- GAT agg layer 4: pools x4 (chans 176..431) ----
// grid NN/4 exact; no early returns
__global__ void k_gat_agg4(const u16* __restrict__ h, const float* __restrict__ asrc,
                           const float* __restrict__ adst, const int* __restrict__ rowptr,
                           const int* __restrict__ csr_src, const float* __restrict__ b,
                           const int* __restrict__ batch, float* __restrict__ pool){
    constexpr int HC = 256, CL = 32, S = 2;
    __shared__ float x4buf[4][256];
    __shared__ int gbuf[4];
    int lane = threadIdx.x & 63;
    int wid  = threadIdx.x >> 6;
    int i = blockIdx.x*4 + wid;
    int ll   = lane % CL;
    int slot = lane / CL;
    int head = ll >> 2;
    float ad = adst[(size_t)i*8 + head];
    float acc[8] = {0.f,0.f,0.f,0.f,0.f,0.f,0.f,0.f};
    float s = 0.f;
    if (slot == 0){
        float wself = __expf(lrelu(asrc[(size_t)i*8 + head] + ad));
        uint4 t = ((const uint4*)(h + (size_t)i*HC))[ll];
        float f[8]; unpack8(t, f);
#pragma unroll
        for (int k=0;k<8;k++) acc[k] = wself*f[k];
        s = wself;
    }
    int e0 = rowptr[i], e1 = rowptr[i+1];
    int e = e0 + slot;
    for (; e + 3*S < e1; e += 4*S){
        int j0 = csr_src[e], j1 = csr_src[e+S], j2 = csr_src[e+2*S], j3 = csr_src[e+3*S];
        float w0 = __expf(lrelu(asrc[(size_t)j0*8 + head] + ad));
        float w1 = __expf(lrelu(asrc[(size_t)j1*8 + head] + ad));
        float w2 = __expf(lrelu(asrc[(size_t)j2*8 + head] + ad));
        float w3 = __expf(lrelu(asrc[(size_t)j3*8 + head] + ad));
        uint4 t0 = ((const uint4*)(h + (size_t)j0*HC))[ll];
        uint4 t1 = ((const uint4*)(h + (size_t)j1*HC))[ll];
        uint4 t2 = ((const uint4*)(h + (size_t)j2*HC))[ll];
        uint4 t3 = ((const uint4*)(h + (size_t)j3*HC))[ll];
        float f0[8], f1[8], f2[8], f3[8];
        unpack8(t0, f0); unpack8(t1, f1); unpack8(t2, f2); unpack8(t3, f3);
#pragma unroll
        for (int k=0;k<8;k++) acc[k] += w0*f0[k] + w1*f1[k] + w2*f2[k] + w3*f3[k];
        s += w0 + w1 + w2 + w3;
    }
    for (; e < e1; e += S){
        int j = csr_src[e];
        float w = __expf(lrelu(asrc[(size_t)j*8 + head] + ad));
        uint4 t = ((const uint4*)(h + (size_t)j*HC))[ll];
        float f[8]; unpack8(t, f);
#pragma unroll
        for (int k=0;k<8;k++) acc[k] += w*f[k];
        s += w;
    }
    s += __shfl_xor(s, 32, 64);
#pragma unroll
    for (int k=0;k<8;k++) acc[k] += __shfl_xor(acc[k], 32, 64);
    if (slot == 0){
        float inv = 1.f / s;
#pragma unroll
        for (int k=0;k<8;k++)
            x4buf[wid][ll*8+k] = fmaxf(acc[k]*inv + b[ll*8+k], 0.f);
        if (ll == 0) gbuf[wid] = batch[i];
    }
    __syncthreads();
    {
        int c = threadIdx.x;
        int g0 = gbuf[0];
        float sum = 0.f;
#pragma unroll
        for (int wd = 0; wd < 4; wd++){
            float v = x4buf[wd][c];
            int gw = gbuf[wd];
            if (gw == g0) sum += v;
            else atomicAdd(&pool[gw*432 + 176 + c], v);
        }
        atomicAdd(&pool[g0*432 + 176 + c], sum);
    }
}

// fused fc1 + fc2
__global__ void k_fc(const float* __restrict__ pool, const int* __restrict__ batch,
                     const float* __restrict__ Wf1, const float* __restrict__ bf1,
                     const float* __restrict__ Wf2, const float* __restrict__ bf2,
                     float* __restrict__ out){
    int g = blockIdx.x, j = threadIdx.x;
    int lo = 0, hi = NN;
    while (lo < hi){ int mid = (lo+hi) >> 1; if (batch[mid] < g) lo = mid+1; else hi = mid; }
    int s0 = lo;
    lo = 0; hi = NN;
    while (lo < hi){ int mid = (lo+hi) >> 1; if (batch[mid] < g+1) lo = mid+1; else hi = mid; }
    int cnt = lo - s0;
    float invc = 1.f / (float)max(cnt, 1);
    float acc = 0.f;
    for (int k = 0; k < 432; k++) acc += pool[g*432 + k] * Wf1[k*128 + j];
    float hv = fmaxf(acc * invc + bf1[j], 0.f);
    float p = hv * Wf2[j];
    for (int off = 32; off > 0; off >>= 1) p += __shfl_down(p, off, 64);
    __shared__ float part[2];
    if ((j & 63) == 0) part[j >> 6] = p;
    __syncthreads();
    if (j == 0) out[g] = part[0] + part[1] + bf2[0];
}

extern "C" void kernel_launch(void* const* d_in, const int* in_sizes, int n_in,
                              void* d_out, int out_size, void* d_ws, size_t ws_size,
                              hipStream_t stream){
    const float* x     = (const float*)d_in[0];
    const int*   ei    = (const int*)  d_in[1];
    const int*   batch = (const int*)  d_in[2];
    const float* W1 = (const float*)d_in[3];  const float* b1 = (const float*)d_in[4];
    const float* W2 = (const float*)d_in[5];  const float* b2 = (const float*)d_in[6];
    const float* W3 = (const float*)d_in[7];
    const float* as3 = (const float*)d_in[8]; const float* ad3 = (const float*)d_in[9];
    const float* b3 = (const float*)d_in[10];
    const float* W4 = (const float*)d_in[11];
    const float* as4 = (const float*)d_in[12]; const float* ad4 = (const float*)d_in[13];
    const float* b4 = (const float*)d_in[14];
    const float* Wf1 = (const float*)d_in[15]; const float* bf1 = (const float*)d_in[16];
    const float* Wf2 = (const float*)d_in[17]; const float* bf2 = (const float*)d_in[18];
    float* out = (float*)d_out;

    const int* srcE = ei;
    const int* dstE = ei + NE;

    char* base = (char*)d_ws; size_t off = 0;
    auto alloc = [&](size_t bytes)->void*{
        void* p = base + off;
        off += (bytes + 255) & ~(size_t)255;
        return p;
    };
    int*   degi    = (int*)  alloc((size_t)NN*4);
    int*   cursor  = (int*)  alloc((size_t)NN*4);
    float* dinv    = (float*)alloc((size_t)NN*4);
    int*   rowptr  = (int*)  alloc((size_t)(NN+1)*4);
    int*   bsum    = (int*)  alloc(64*4);
    int*   csr_src = (int*)  alloc((size_t)NE*4);
    u16*   h1b     = (u16*)  alloc((size_t)NN*16*2);
    u16*   h2b     = (u16*)  alloc((size_t)NN*32*2);
    u16*   hb3     = (u16*)  alloc((size_t)NN*128*2);
    u16*   hb4     = (u16*)  alloc((size_t)NN*256*2);
    u16*   x2b     = (u16*)  alloc((size_t)NN*32*2);
    u16*   x3b     = (u16*)  alloc((size_t)NN*128*2);
    u16*   W3p     = (u16*)  alloc((size_t)4096*2);
    u16*   W4p     = (u16*)  alloc((size_t)32768*2);
    float* a_src   = (float*)alloc((size_t)NN*8*4);
    float* a_dst   = (float*)alloc((size_t)NN*8*4);
    float* pool    = (float*)alloc((size_t)NG*432*4);

    hipMemsetAsync(degi, 0, (size_t)NN*4, stream);

    const int SB = (NN + 1023)/1024;

    k_cm     <<<EB + MB1 + PB + WB4 + WB3, 256, 0, stream>>>(dstE, degi, x, W1, W3, W4,
                                                             h1b, pool, W3p, W4p);
    k_scan_a <<<SB, 256, 0, stream>>>(degi, rowptr, dinv, cursor, bsum, NN);
    k_scan_c <<<SB, 256, 0, stream>>>(rowptr, bsum, SB, NN);
    k_scatter<<<EB, 256, 0, stream>>>(srcE, dstE, rowptr, cursor, csr_src, NE);

    // GCN layer 1 agg + relu + mm2 fused; pools x1
    k_gcn_agg16_mm2<<<NN/16, 256, 0, stream>>>(h1b, dinv, rowptr, csr_src, b1, W2,
                                               batch, pool, h2b, NN);

    // GCN layer 2 agg -> x2 bf16; pools x2
    k_gcn_agg32<<<NN/16, 256, 0, stream>>>(h2b, dinv, rowptr, csr_src, b2, batch,
                                           pool, x2b, NN);

    // GAT layer 3: MFMA mm3 + fused logits; agg3 pools x3
    k_mm3_mfma<<<(NN+63)/64, 256, 0, stream>>>(x2b, W3p, as3, ad3, hb3, a_src, a_dst);
    k_gat_agg3<<<NN/4, 256, 0, stream>>>(hb3, a_src, a_dst, rowptr, csr_src, b3,
                                         batch, pool, x3b, NN);

    // GAT layer 4: MFMA mm4 + fused logits; agg4 pools x4
    {
        dim3 grid(2, (NN + 63)/64);
        k_mm4_mfma<<<grid, 256, 0, stream>>>(x3b, W4p, as4, ad4, hb4, a_src, a_dst);
    }
    k_gat_agg4<<<NN/4, 256, 0, stream>>>(hb4, a_src, a_dst, rowptr, csr_src, b4, batch, pool);

    // fused FC
    k_fc<<<NG, 128, 0, stream>>>(pool, batch, Wf1, bf1, Wf2, bf2, out);
}